// Round 7
// baseline (912.221 us; speedup 1.0000x reference)
//
#include <hip/hip_runtime.h>

#define N_NODES 32000
typedef unsigned short u16;
typedef unsigned int u32;
typedef unsigned char u8;
typedef __attribute__((ext_vector_type(8))) short bf16x8;
typedef __attribute__((ext_vector_type(4))) float f32x4;
typedef __attribute__((ext_vector_type(2))) float f32x2;

__device__ __forceinline__ float leakyf(float v) { return v >= 0.f ? v : 0.1f * v; }
__device__ __forceinline__ u16 f2bf(float f) {
    u32 u = __float_as_uint(f);
    return (u16)((u + 0x7FFFu + ((u >> 16) & 1u)) >> 16);
}
__device__ __forceinline__ float bf2f(u16 h) { return __uint_as_float(((u32)h) << 16); }
__device__ __forceinline__ float bf_lo(u32 u) { return __uint_as_float(u << 16); }
__device__ __forceinline__ float bf_hi(u32 u) { return __uint_as_float(u & 0xFFFF0000u); }
__device__ __forceinline__ u32 pack2(float a, float b) { return (u32)f2bf(a) | ((u32)f2bf(b) << 16); }

// fp8 e4m3 (OCP on gfx950) decode: 4 floats from one u32
__device__ __forceinline__ void dec4(float* acc, u32 w) {
    f32x2 lo = __builtin_amdgcn_cvt_pk_f32_fp8(w, false);
    f32x2 hi = __builtin_amdgcn_cvt_pk_f32_fp8(w, true);
    acc[0] += lo[0]; acc[1] += lo[1]; acc[2] += hi[0]; acc[3] += hi[1];
}
__device__ __forceinline__ void dec16(float* acc, uint4 v) {
    dec4(acc + 0, v.x); dec4(acc + 4, v.y); dec4(acc + 8, v.z); dec4(acc + 12, v.w);
}
__device__ __forceinline__ u8 f2fp8(float v) {
    return (u8)__builtin_amdgcn_cvt_pk_fp8_f32(v, v, 0, false);
}

__device__ __forceinline__ void gload16(const u16* g, u16* l) {
    __builtin_amdgcn_global_load_lds((const __attribute__((address_space(1))) void*)g,
                                     (__attribute__((address_space(3))) void*)l, 16, 0, 0);
}

// ---------------- CSR build ----------------
__global__ __launch_bounds__(256) void k_count(const int* __restrict__ dst, int* __restrict__ cnt, int E)
{
    int e = blockIdx.x * 256 + threadIdx.x;
    if (e < E) atomicAdd(&cnt[dst[e]], 1);
}

// phase 1: per-block scan of 256 counts -> block-local exclusive prefix + block total
__global__ __launch_bounds__(256) void k_scan_blk(const int* __restrict__ cnt, int* __restrict__ rp,
                                                  int* __restrict__ bsum)
{
    __shared__ int sh[256];
    const int b = blockIdx.x, t = threadIdx.x;
    int v = cnt[b * 256 + t];
    sh[t] = v;
    __syncthreads();
    for (int off = 1; off < 256; off <<= 1) {
        int u = (t >= off) ? sh[t - off] : 0;
        __syncthreads();
        sh[t] += u;
        __syncthreads();
    }
    rp[b * 256 + t] = sh[t] - v;          // exclusive within block
    if (t == 255) bsum[b] = sh[255];      // block total
}

// phase 2: scan the 125 block totals (one small block)
__global__ __launch_bounds__(128) void k_scan_top(int* __restrict__ bsum, int nb)
{
    __shared__ int sh[128];
    const int t = threadIdx.x;
    int v = (t < nb) ? bsum[t] : 0;
    sh[t] = v;
    __syncthreads();
    for (int off = 1; off < 128; off <<= 1) {
        int u = (t >= off) ? sh[t - off] : 0;
        __syncthreads();
        sh[t] += u;
        __syncthreads();
    }
    if (t < nb) bsum[t] = sh[t] - v;      // exclusive block offsets
}

// phase 3: add block offsets; set rp[n]=E
__global__ __launch_bounds__(256) void k_scan_add(int* __restrict__ rp, const int* __restrict__ bsum,
                                                  int n, int E)
{
    int i = blockIdx.x * 256 + threadIdx.x;
    rp[i] += bsum[blockIdx.x];
    if (i == 0) rp[n] = E;
}

__global__ __launch_bounds__(256) void k_place(const int* __restrict__ src, const int* __restrict__ dst,
                                               const int* __restrict__ rp, int* __restrict__ cur,
                                               int* __restrict__ cs, int E)
{
    int e = blockIdx.x * 256 + threadIdx.x;
    if (e < E) {
        int d = dst[e];
        int p = rp[d] + atomicAdd(&cur[d], 1);
        cs[p] = src[e];
    }
}

// ---------------- conversions ----------------
__global__ __launch_bounds__(256) void k_cvt(const float* __restrict__ in, u16* __restrict__ out)
{
    int i = blockIdx.x * 256 + threadIdx.x;
    float4 v = ((const float4*)in)[i];
    ushort4 o;
    o.x = f2bf(v.x); o.y = f2bf(v.y); o.z = f2bf(v.z); o.w = f2bf(v.w);
    ((ushort4*)out)[i] = o;
}

__global__ __launch_bounds__(256) void k_cvt8(const float* __restrict__ in, u32* __restrict__ out)
{
    int i = blockIdx.x * 256 + threadIdx.x;
    float4 v = ((const float4*)in)[i];
    int p = __builtin_amdgcn_cvt_pk_fp8_f32(v.x, v.y, 0, false);
    p = __builtin_amdgcn_cvt_pk_fp8_f32(v.z, v.w, p, true);
    out[i] = (u32)p;
}

// ---------------- bf16 MFMA GEMM (m97 structure) ----------------
// C[m][o] = sum_k A[m][k]*W[o][k] + biasmul*bias[o]; biasmul=(deg+1) if DEGB; out bf16 or fp8.
template <bool RELU, bool DEGB, bool F8OUT>
__global__ __launch_bounds__(256) void k_gemm_mfma(const u16* __restrict__ A, const u16* __restrict__ W,
                                                   const float* __restrict__ bias, const int* __restrict__ rp,
                                                   void* __restrict__ Cv, int K, int OD)
{
    __shared__ u16 As[128 * 32];
    __shared__ u16 Bs[128 * 32];
    const int t = threadIdx.x;
    const int lane = t & 63;
    const int w = t >> 6;
    const int wr = w >> 1, wc = w & 1;
    const int bm = blockIdx.x * 128;
    const int bn = blockIdx.y * 128;

    const int c0 = w * 64 + lane;
    const int r0 = c0 >> 2, kc0 = (c0 & 3) * 8;
    const int c1 = c0 + 256;
    const int r1 = c1 >> 2, kc1 = (c1 & 3) * 8;
    const u16* gA0 = A + (size_t)(bm + r0) * K + kc0;
    const u16* gA1 = A + (size_t)(bm + r1) * K + kc1;
    const u16* gB0 = W + (size_t)(bn + r0) * K + kc0;
    const u16* gB1 = W + (size_t)(bn + r1) * K + kc1;
    u16* lA0 = As + w * 512;
    u16* lA1 = As + 2048 + w * 512;
    u16* lB0 = Bs + w * 512;
    u16* lB1 = Bs + 2048 + w * 512;

    f32x4 acc[4][4];
#pragma unroll
    for (int i = 0; i < 4; ++i)
#pragma unroll
        for (int j = 0; j < 4; ++j)
            acc[i][j] = (f32x4){0.f, 0.f, 0.f, 0.f};

    const int fr = lane & 15;
    const int ko = (lane >> 4) * 8;

    for (int k0 = 0; k0 < K; k0 += 32) {
        __syncthreads();
        gload16(gA0 + k0, lA0);
        gload16(gA1 + k0, lA1);
        gload16(gB0 + k0, lB0);
        gload16(gB1 + k0, lB1);
        asm volatile("s_waitcnt vmcnt(0)" ::: "memory");
        __syncthreads();
        bf16x8 af[4], bfv[4];
#pragma unroll
        for (int i = 0; i < 4; ++i)
            af[i] = *(const bf16x8*)&As[(wr * 64 + i * 16 + fr) * 32 + ko];
#pragma unroll
        for (int j = 0; j < 4; ++j)
            bfv[j] = *(const bf16x8*)&Bs[(wc * 64 + j * 16 + fr) * 32 + ko];
#pragma unroll
        for (int i = 0; i < 4; ++i)
#pragma unroll
            for (int j = 0; j < 4; ++j)
                acc[i][j] = __builtin_amdgcn_mfma_f32_16x16x32_bf16(af[i], bfv[j], acc[i][j], 0, 0, 0);
    }

    u16* C16 = (u16*)Cv;
    u8*  C8  = (u8*)Cv;
    const int qr = (lane >> 4) * 4;
    float bcol[4];
#pragma unroll
    for (int j = 0; j < 4; ++j) bcol[j] = bias[bn + wc * 64 + j * 16 + fr];
#pragma unroll
    for (int i = 0; i < 4; ++i) {
#pragma unroll
        for (int r = 0; r < 4; ++r) {
            int row = bm + wr * 64 + i * 16 + qr + r;
            float bm_ = 1.f;
            if (DEGB) bm_ = (float)(rp[row + 1] - rp[row]) + 1.f;
#pragma unroll
            for (int j = 0; j < 4; ++j) {
                int col = bn + wc * 64 + j * 16 + fr;
                float o = acc[i][j][r] + bm_ * bcol[j];
                if (RELU) o = fmaxf(o, 0.f);
                if (F8OUT) C8[(size_t)row * OD + col] = f2fp8(o);
                else       C16[(size_t)row * OD + col] = f2bf(o);
            }
        }
    }
}

// ---------------- fp8 gather+self(+relu), D=256: quarter-wave rows (16B = 16 fp8/lane) ----------------
template <bool RELU>
__global__ __launch_bounds__(256) void k_agg256_f8(const u8* __restrict__ h8, const int* __restrict__ rp,
                                                   const int* __restrict__ cs, u16* __restrict__ out)
{
    const int lane = threadIdx.x & 63;
    const int n = blockIdx.x * 4 + (threadIdx.x >> 6);
    const int g = lane >> 4;        // edge group 0..3
    const int c = lane & 15;        // 16B slot in 256B row
    const uint4* hb = (const uint4*)h8 + c;

    float acc[16];
#pragma unroll
    for (int i = 0; i < 16; ++i) acc[i] = 0.f;
    if (g == 0) dec16(acc, hb[(size_t)n * 16]);

    const int beg = rp[n], end = rp[n + 1];
    int e = beg;
    for (; e + 16 <= end; e += 16) {
        uint4 v0 = hb[(size_t)cs[e + g] * 16];
        uint4 v1 = hb[(size_t)cs[e + 4 + g] * 16];
        uint4 v2 = hb[(size_t)cs[e + 8 + g] * 16];
        uint4 v3 = hb[(size_t)cs[e + 12 + g] * 16];
        dec16(acc, v0); dec16(acc, v1); dec16(acc, v2); dec16(acc, v3);
    }
    for (; e + 4 <= end; e += 4) {
        uint4 v = hb[(size_t)cs[e + g] * 16];
        dec16(acc, v);
    }
    if (e + g < end) {
        uint4 v = hb[(size_t)cs[e + g] * 16];
        dec16(acc, v);
    }
#pragma unroll
    for (int i = 0; i < 16; ++i) acc[i] += __shfl_xor(acc[i], 16);
#pragma unroll
    for (int i = 0; i < 16; ++i) acc[i] += __shfl_xor(acc[i], 32);
    if (g == 0) {
        if (RELU) {
#pragma unroll
            for (int i = 0; i < 16; ++i) acc[i] = fmaxf(acc[i], 0.f);
        }
        uint4 o0, o1;
        o0.x = pack2(acc[0], acc[1]);  o0.y = pack2(acc[2], acc[3]);
        o0.z = pack2(acc[4], acc[5]);  o0.w = pack2(acc[6], acc[7]);
        o1.x = pack2(acc[8], acc[9]);  o1.y = pack2(acc[10], acc[11]);
        o1.z = pack2(acc[12], acc[13]); o1.w = pack2(acc[14], acc[15]);
        uint4* op = (uint4*)((u32*)out + (size_t)n * 128 + c * 8);
        op[0] = o0; op[1] = o1;
    }
}

// ---------------- fp8 gather+self(+relu), D=512: half-wave rows ----------------
template <bool RELU>
__global__ __launch_bounds__(256) void k_agg512_f8(const u8* __restrict__ h8, const int* __restrict__ rp,
                                                   const int* __restrict__ cs, u16* __restrict__ out)
{
    const int lane = threadIdx.x & 63;
    const int n = blockIdx.x * 4 + (threadIdx.x >> 6);
    const int g = lane >> 5;        // edge parity
    const int c = lane & 31;        // 16B slot in 512B row
    const uint4* hb = (const uint4*)h8 + c;

    float acc[16];
#pragma unroll
    for (int i = 0; i < 16; ++i) acc[i] = 0.f;
    if (g == 0) dec16(acc, hb[(size_t)n * 32]);

    const int beg = rp[n], end = rp[n + 1];
    int e = beg;
    for (; e + 8 <= end; e += 8) {
        uint4 v0 = hb[(size_t)cs[e + g] * 32];
        uint4 v1 = hb[(size_t)cs[e + 2 + g] * 32];
        uint4 v2 = hb[(size_t)cs[e + 4 + g] * 32];
        uint4 v3 = hb[(size_t)cs[e + 6 + g] * 32];
        dec16(acc, v0); dec16(acc, v1); dec16(acc, v2); dec16(acc, v3);
    }
    for (; e + 2 <= end; e += 2) {
        uint4 v = hb[(size_t)cs[e + g] * 32];
        dec16(acc, v);
    }
    if (e + g < end) {
        uint4 v = hb[(size_t)cs[e + g] * 32];
        dec16(acc, v);
    }
#pragma unroll
    for (int i = 0; i < 16; ++i) acc[i] += __shfl_xor(acc[i], 32);
    if (g == 0) {
        if (RELU) {
#pragma unroll
            for (int i = 0; i < 16; ++i) acc[i] = fmaxf(acc[i], 0.f);
        }
        uint4 o0, o1;
        o0.x = pack2(acc[0], acc[1]);  o0.y = pack2(acc[2], acc[3]);
        o0.z = pack2(acc[4], acc[5]);  o0.w = pack2(acc[6], acc[7]);
        o1.x = pack2(acc[8], acc[9]);  o1.y = pack2(acc[10], acc[11]);
        o1.z = pack2(acc[12], acc[13]); o1.w = pack2(acc[14], acc[15]);
        uint4* op = (uint4*)((u32*)out + (size_t)n * 256 + c * 8);
        op[0] = o0; op[1] = o1;
    }
}

// ---------------- batchnorm stats: 1000 blocks x 32 rows, uint4 loads, LDS reduce ----------------
template <int D>
__global__ __launch_bounds__(256) void k_bn_stats(const u16* __restrict__ h, float* __restrict__ sums)
{
    constexpr int SLOT = D / 8;        // uint4 slots per row: 64 (D=512) or 32 (D=256)
    constexpr int NS = 256 / SLOT;     // row substreams: 4 or 8
    constexpr int ROWS = 32;
    const int t = threadIdx.x;
    const int s = t % SLOT, j = t / SLOT;
    const int r0 = blockIdx.x * ROWS;
    float a[8] = {}, q[8] = {};
    for (int r = j; r < ROWS; r += NS) {
        uint4 v = *((const uint4*)(h + (size_t)(r0 + r) * D) + s);
        u32 wv[4] = {v.x, v.y, v.z, v.w};
#pragma unroll
        for (int k = 0; k < 4; ++k) {
            float lo = bf_lo(wv[k]), hi = bf_hi(wv[k]);
            a[2 * k]     += lo; q[2 * k]     = fmaf(lo, lo, q[2 * k]);
            a[2 * k + 1] += hi; q[2 * k + 1] = fmaf(hi, hi, q[2 * k + 1]);
        }
    }
    __shared__ float red[256 * 16];
#pragma unroll
    for (int i = 0; i < 8; ++i) { red[t * 16 + i] = a[i]; red[t * 16 + 8 + i] = q[i]; }
    __syncthreads();
    if (j == 0) {
#pragma unroll 1
        for (int k = 1; k < NS; ++k) {
            const float* rr = &red[(k * SLOT + s) * 16];
#pragma unroll
            for (int i = 0; i < 8; ++i) { a[i] += rr[i]; q[i] += rr[8 + i]; }
        }
#pragma unroll
        for (int i = 0; i < 8; ++i) {
            atomicAdd(&sums[8 * s + i], a[i]);
            atomicAdd(&sums[D + 8 * s + i], q[i]);
        }
    }
}

__global__ __launch_bounds__(512) void k_bn_finalize(const float* __restrict__ sums, const float* __restrict__ gam,
                                                     const float* __restrict__ bet, float* __restrict__ ss, int D)
{
    int t = threadIdx.x;
    if (t < D) {
        const float invN = 1.f / (float)N_NODES;
        float mu  = sums[t] * invN;
        float var = sums[D + t] * invN - mu * mu;
        float rs  = rsqrtf(var + 1e-5f);
        float sc  = gam[t] * rs;
        ss[t]     = sc;
        ss[D + t] = bet[t] - mu * sc;
    }
}

__global__ __launch_bounds__(256) void k_bn_apply(u16* __restrict__ h, const float* __restrict__ ss, int D)
{
    int i = blockIdx.x * 256 + threadIdx.x;
    uint4 v = ((uint4*)h)[i];
    int c = (i * 8) & (D - 1);
    const float* sc = &ss[c];
    const float* sh = &ss[D + c];
    u32 r[4];
    u32 vv[4] = {v.x, v.y, v.z, v.w};
#pragma unroll
    for (int k = 0; k < 4; ++k) {
        float a = leakyf(fmaf(bf_lo(vv[k]), sc[2 * k], sh[2 * k]));
        float b = leakyf(fmaf(bf_hi(vv[k]), sc[2 * k + 1], sh[2 * k + 1]));
        r[k] = pack2(a, b);
    }
    ((uint4*)h)[i] = make_uint4(r[0], r[1], r[2], r[3]);
}

// ---------------- pool + head ----------------
__global__ __launch_bounds__(256) void k_pool(const u16* __restrict__ h, float* __restrict__ gp)
{
    int b = blockIdx.x, ch = blockIdx.y, t = threadIdx.x;
    int s = t & 63, j = t >> 6;
    int r0 = b * 2000 + ch * 80;
    float a0 = 0.f, a1 = 0.f, a2 = 0.f, a3 = 0.f;
    for (int r = j; r < 80; r += 4) {
        uint2 v = *((const uint2*)(h + (size_t)(r0 + r) * 256) + s);
        a0 += bf_lo(v.x); a1 += bf_hi(v.x); a2 += bf_lo(v.y); a3 += bf_hi(v.y);
    }
    atomicAdd(&gp[b * 256 + s * 4 + 0], a0);
    atomicAdd(&gp[b * 256 + s * 4 + 1], a1);
    atomicAdd(&gp[b * 256 + s * 4 + 2], a2);
    atomicAdd(&gp[b * 256 + s * 4 + 3], a3);
}

__global__ __launch_bounds__(64) void k_final(const float* __restrict__ gp, const float* __restrict__ Wp,
                                              const float* __restrict__ bp, float* __restrict__ out)
{
    __shared__ float lg[32];
    int t = threadIdx.x;
    if (t < 32) {
        int b = t >> 1, c = t & 1;
        float s = 0.f;
        for (int k = 0; k < 256; ++k) s = fmaf(gp[b * 256 + k], Wp[c * 256 + k], s);
        float o = s * (1.f / 2000.f) + bp[c];
        out[b * 2 + c] = o;
        lg[t] = o;
    }
    __syncthreads();
    if (t < 16) out[32 + t] = (lg[t * 2 + 1] > lg[t * 2]) ? 1.f : 0.f;
}

extern "C" void kernel_launch(void* const* d_in, const int* in_sizes, int n_in,
                              void* d_out, int out_size, void* d_ws, size_t ws_size,
                              hipStream_t stream)
{
    const float* x   = (const float*)d_in[0];
    const int*   ei  = (const int*)d_in[1];
    const float* W1  = (const float*)d_in[2];
    const float* b1  = (const float*)d_in[3];
    const float* W2  = (const float*)d_in[4];
    const float* b2  = (const float*)d_in[5];
    const float* W3  = (const float*)d_in[6];
    const float* b3  = (const float*)d_in[7];
    const float* g1  = (const float*)d_in[8];
    const float* be1 = (const float*)d_in[9];
    const float* g2  = (const float*)d_in[10];
    const float* be2 = (const float*)d_in[11];
    const float* g3  = (const float*)d_in[12];
    const float* be3 = (const float*)d_in[13];
    const float* Wp  = (const float*)d_in[14];
    const float* bp  = (const float*)d_in[15];
    float* out = (float*)d_out;

    const int E = in_sizes[1] / 2;
    const int* src = ei;
    const int* dst = ei + E;

    char* ws = (char*)d_ws;
    size_t off = 0;
    auto alloc = [&](size_t bytes) -> void* {
        void* p = ws + off;
        off = (off + bytes + 255) & ~(size_t)255;
        return p;
    };
    u16*   bufA = (u16*)alloc((size_t)N_NODES * 512 * 2);
    u16*   bufB = (u16*)alloc((size_t)N_NODES * 512 * 2);
    u8*    buf8 = (u8*)alloc((size_t)N_NODES * 512);
    u8*    x8   = (u8*)alloc((size_t)N_NODES * 256);
    u16*   w1b  = (u16*)alloc(512 * 256 * 2);
    u16*   w2b  = (u16*)alloc(512 * 512 * 2);
    u16*   w3b  = (u16*)alloc(256 * 512 * 2);
    int*   cs   = (int*)alloc((size_t)E * 4);
    int*   rp   = (int*)alloc((size_t)(N_NODES + 1) * 4);
    int*   cnt  = (int*)alloc((size_t)N_NODES * 4);
    int*   cur  = (int*)alloc((size_t)N_NODES * 4);
    int*   bsum = (int*)alloc(256 * 4);
    float* sums = (float*)alloc(1024 * 4);
    float* ss   = (float*)alloc(1024 * 4);
    float* gp   = (float*)alloc(16 * 256 * 4);

    // CSR build (parallel 3-phase scan)
    hipMemsetAsync(cnt, 0, (size_t)N_NODES * 4, stream);
    hipMemsetAsync(cur, 0, (size_t)N_NODES * 4, stream);
    const int eb = (E + 255) / 256;
    const int nb = N_NODES / 256;   // 125
    k_count<<<eb, 256, 0, stream>>>(dst, cnt, E);
    k_scan_blk<<<nb, 256, 0, stream>>>(cnt, rp, bsum);
    k_scan_top<<<1, 128, 0, stream>>>(bsum, nb);
    k_scan_add<<<nb, 256, 0, stream>>>(rp, bsum, N_NODES, E);
    k_place<<<eb, 256, 0, stream>>>(src, dst, rp, cur, cs, E);

    // conversions: x -> fp8 gather table; weights -> bf16
    k_cvt8<<<N_NODES * 256 / 4 / 256, 256, 0, stream>>>(x, (u32*)x8);
    k_cvt<<<512 * 256 / 4 / 256, 256, 0, stream>>>(W1, w1b);
    k_cvt<<<512 * 512 / 4 / 256, 256, 0, stream>>>(W2, w2b);
    k_cvt<<<256 * 512 / 4 / 256, 256, 0, stream>>>(W3, w3b);

    // ---- layer 1 (linearity): s = x + sum_src x (fp8 gather, bf16 out);
    //      h1 = relu(s@W1' + (deg+1)*b1) fused in GEMM ----
    k_agg256_f8<false><<<N_NODES / 4, 256, 0, stream>>>(x8, rp, cs, bufA);
    k_gemm_mfma<true, true, false><<<dim3(250, 4), 256, 0, stream>>>(bufA, w1b, b1, rp, bufB, 256, 512);
    hipMemsetAsync(sums, 0, 1024 * 4, stream);
    k_bn_stats<512><<<N_NODES / 32, 256, 0, stream>>>(bufB, sums);
    k_bn_finalize<<<1, 512, 0, stream>>>(sums, g1, be1, ss, 512);
    k_bn_apply<<<N_NODES * 512 / 8 / 256, 256, 0, stream>>>(bufB, ss, 512);

    // ---- layer 2: GEMM (bf16 in, fp8 out) then 512-wide fp8 gather + relu ----
    k_gemm_mfma<false, false, true><<<dim3(250, 4), 256, 0, stream>>>(bufB, w2b, b2, rp, buf8, 512, 512);
    k_agg512_f8<true><<<N_NODES / 4, 256, 0, stream>>>(buf8, rp, cs, bufA);
    hipMemsetAsync(sums, 0, 1024 * 4, stream);
    k_bn_stats<512><<<N_NODES / 32, 256, 0, stream>>>(bufA, sums);
    k_bn_finalize<<<1, 512, 0, stream>>>(sums, g2, be2, ss, 512);
    k_bn_apply<<<N_NODES * 512 / 8 / 256, 256, 0, stream>>>(bufA, ss, 512);

    // ---- layer 3: GEMM (512->256, fp8 out) then 256-wide fp8 gather + relu ----
    k_gemm_mfma<false, false, true><<<dim3(250, 2), 256, 0, stream>>>(bufA, w3b, b3, rp, buf8, 512, 256);
    k_agg256_f8<true><<<N_NODES / 4, 256, 0, stream>>>(buf8, rp, cs, bufB);
    hipMemsetAsync(sums, 0, 1024 * 4, stream);
    k_bn_stats<256><<<N_NODES / 32, 256, 0, stream>>>(bufB, sums);
    k_bn_finalize<<<1, 512, 0, stream>>>(sums, g3, be3, ss, 256);
    k_bn_apply<<<N_NODES * 256 / 8 / 256, 256, 0, stream>>>(bufB, ss, 256);

    // ---- pool + head ----
    hipMemsetAsync(gp, 0, 16 * 256 * 4, stream);
    k_pool<<<dim3(16, 25), 256, 0, stream>>>(bufB, gp);
    k_final<<<1, 64, 0, stream>>>(gp, Wp, bp, out);
}

// Round 8
// 441.148 us; speedup vs baseline: 2.0678x; 2.0678x over previous
//
#include <hip/hip_runtime.h>

#define N_NODES 32000
typedef unsigned short u16;
typedef unsigned int u32;
typedef unsigned char u8;
typedef __attribute__((ext_vector_type(8))) short bf16x8;
typedef __attribute__((ext_vector_type(4))) float f32x4;
typedef __attribute__((ext_vector_type(2))) float f32x2;

__device__ __forceinline__ float leakyf(float v) { return v >= 0.f ? v : 0.1f * v; }
__device__ __forceinline__ u16 f2bf(float f) {
    u32 u = __float_as_uint(f);
    return (u16)((u + 0x7FFFu + ((u >> 16) & 1u)) >> 16);
}
__device__ __forceinline__ float bf2f(u16 h) { return __uint_as_float(((u32)h) << 16); }
__device__ __forceinline__ float bf_lo(u32 u) { return __uint_as_float(u << 16); }
__device__ __forceinline__ float bf_hi(u32 u) { return __uint_as_float(u & 0xFFFF0000u); }
__device__ __forceinline__ u32 pack2(float a, float b) { return (u32)f2bf(a) | ((u32)f2bf(b) << 16); }

// fp8 e4m3 (OCP on gfx950) decode: 4 floats from one u32
__device__ __forceinline__ void dec4(float* acc, u32 w) {
    f32x2 lo = __builtin_amdgcn_cvt_pk_f32_fp8(w, false);
    f32x2 hi = __builtin_amdgcn_cvt_pk_f32_fp8(w, true);
    acc[0] += lo[0]; acc[1] += lo[1]; acc[2] += hi[0]; acc[3] += hi[1];
}
__device__ __forceinline__ void dec16(float* acc, uint4 v) {
    dec4(acc + 0, v.x); dec4(acc + 4, v.y); dec4(acc + 8, v.z); dec4(acc + 12, v.w);
}
__device__ __forceinline__ u8 f2fp8(float v) {
    return (u8)__builtin_amdgcn_cvt_pk_fp8_f32(v, v, 0, false);
}

__device__ __forceinline__ void gload16(const u16* g, u16* l) {
    __builtin_amdgcn_global_load_lds((const __attribute__((address_space(1))) void*)g,
                                     (__attribute__((address_space(3))) void*)l, 16, 0, 0);
}

// ---------------- CSR build ----------------
__global__ __launch_bounds__(256) void k_count(const int* __restrict__ dst, int* __restrict__ cnt, int E)
{
    int e = blockIdx.x * 256 + threadIdx.x;
    if (e < E) atomicAdd(&cnt[dst[e]], 1);
}

__global__ __launch_bounds__(256) void k_scan_blk(const int* __restrict__ cnt, int* __restrict__ rp,
                                                  int* __restrict__ bsum)
{
    __shared__ int sh[256];
    const int b = blockIdx.x, t = threadIdx.x;
    int v = cnt[b * 256 + t];
    sh[t] = v;
    __syncthreads();
    for (int off = 1; off < 256; off <<= 1) {
        int u = (t >= off) ? sh[t - off] : 0;
        __syncthreads();
        sh[t] += u;
        __syncthreads();
    }
    rp[b * 256 + t] = sh[t] - v;
    if (t == 255) bsum[b] = sh[255];
}

__global__ __launch_bounds__(128) void k_scan_top(int* __restrict__ bsum, int nb)
{
    __shared__ int sh[128];
    const int t = threadIdx.x;
    int v = (t < nb) ? bsum[t] : 0;
    sh[t] = v;
    __syncthreads();
    for (int off = 1; off < 128; off <<= 1) {
        int u = (t >= off) ? sh[t - off] : 0;
        __syncthreads();
        sh[t] += u;
        __syncthreads();
    }
    if (t < nb) bsum[t] = sh[t] - v;
}

__global__ __launch_bounds__(256) void k_scan_add(int* __restrict__ rp, const int* __restrict__ bsum,
                                                  int n, int E)
{
    int i = blockIdx.x * 256 + threadIdx.x;
    rp[i] += bsum[blockIdx.x];
    if (i == 0) rp[n] = E;
}

__global__ __launch_bounds__(256) void k_place(const int* __restrict__ src, const int* __restrict__ dst,
                                               const int* __restrict__ rp, int* __restrict__ cur,
                                               int* __restrict__ cs, int E)
{
    int e = blockIdx.x * 256 + threadIdx.x;
    if (e < E) {
        int d = dst[e];
        int p = rp[d] + atomicAdd(&cur[d], 1);
        cs[p] = src[e];
    }
}

// ---------------- conversions ----------------
__global__ __launch_bounds__(256) void k_cvt(const float* __restrict__ in, u16* __restrict__ out)
{
    int i = blockIdx.x * 256 + threadIdx.x;
    float4 v = ((const float4*)in)[i];
    ushort4 o;
    o.x = f2bf(v.x); o.y = f2bf(v.y); o.z = f2bf(v.z); o.w = f2bf(v.w);
    ((ushort4*)out)[i] = o;
}

__global__ __launch_bounds__(256) void k_cvt8(const float* __restrict__ in, u32* __restrict__ out)
{
    int i = blockIdx.x * 256 + threadIdx.x;
    float4 v = ((const float4*)in)[i];
    int p = __builtin_amdgcn_cvt_pk_fp8_f32(v.x, v.y, 0, false);
    p = __builtin_amdgcn_cvt_pk_fp8_f32(v.z, v.w, p, true);
    out[i] = (u32)p;
}

// ---------------- bf16 MFMA GEMM (m97 structure) ----------------
template <bool RELU, bool DEGB, bool F8OUT>
__global__ __launch_bounds__(256) void k_gemm_mfma(const u16* __restrict__ A, const u16* __restrict__ W,
                                                   const float* __restrict__ bias, const int* __restrict__ rp,
                                                   void* __restrict__ Cv, int K, int OD)
{
    __shared__ u16 As[128 * 32];
    __shared__ u16 Bs[128 * 32];
    const int t = threadIdx.x;
    const int lane = t & 63;
    const int w = t >> 6;
    const int wr = w >> 1, wc = w & 1;
    const int bm = blockIdx.x * 128;
    const int bn = blockIdx.y * 128;

    const int c0 = w * 64 + lane;
    const int r0 = c0 >> 2, kc0 = (c0 & 3) * 8;
    const int c1 = c0 + 256;
    const int r1 = c1 >> 2, kc1 = (c1 & 3) * 8;
    const u16* gA0 = A + (size_t)(bm + r0) * K + kc0;
    const u16* gA1 = A + (size_t)(bm + r1) * K + kc1;
    const u16* gB0 = W + (size_t)(bn + r0) * K + kc0;
    const u16* gB1 = W + (size_t)(bn + r1) * K + kc1;
    u16* lA0 = As + w * 512;
    u16* lA1 = As + 2048 + w * 512;
    u16* lB0 = Bs + w * 512;
    u16* lB1 = Bs + 2048 + w * 512;

    f32x4 acc[4][4];
#pragma unroll
    for (int i = 0; i < 4; ++i)
#pragma unroll
        for (int j = 0; j < 4; ++j)
            acc[i][j] = (f32x4){0.f, 0.f, 0.f, 0.f};

    const int fr = lane & 15;
    const int ko = (lane >> 4) * 8;

    for (int k0 = 0; k0 < K; k0 += 32) {
        __syncthreads();
        gload16(gA0 + k0, lA0);
        gload16(gA1 + k0, lA1);
        gload16(gB0 + k0, lB0);
        gload16(gB1 + k0, lB1);
        asm volatile("s_waitcnt vmcnt(0)" ::: "memory");
        __syncthreads();
        bf16x8 af[4], bfv[4];
#pragma unroll
        for (int i = 0; i < 4; ++i)
            af[i] = *(const bf16x8*)&As[(wr * 64 + i * 16 + fr) * 32 + ko];
#pragma unroll
        for (int j = 0; j < 4; ++j)
            bfv[j] = *(const bf16x8*)&Bs[(wc * 64 + j * 16 + fr) * 32 + ko];
#pragma unroll
        for (int i = 0; i < 4; ++i)
#pragma unroll
            for (int j = 0; j < 4; ++j)
                acc[i][j] = __builtin_amdgcn_mfma_f32_16x16x32_bf16(af[i], bfv[j], acc[i][j], 0, 0, 0);
    }

    u16* C16 = (u16*)Cv;
    u8*  C8  = (u8*)Cv;
    const int qr = (lane >> 4) * 4;
    float bcol[4];
#pragma unroll
    for (int j = 0; j < 4; ++j) bcol[j] = bias[bn + wc * 64 + j * 16 + fr];
#pragma unroll
    for (int i = 0; i < 4; ++i) {
#pragma unroll
        for (int r = 0; r < 4; ++r) {
            int row = bm + wr * 64 + i * 16 + qr + r;
            float bm_ = 1.f;
            if (DEGB) bm_ = (float)(rp[row + 1] - rp[row]) + 1.f;
#pragma unroll
            for (int j = 0; j < 4; ++j) {
                int col = bn + wc * 64 + j * 16 + fr;
                float o = acc[i][j][r] + bm_ * bcol[j];
                if (RELU) o = fmaxf(o, 0.f);
                if (F8OUT) C8[(size_t)row * OD + col] = f2fp8(o);
                else       C16[(size_t)row * OD + col] = f2bf(o);
            }
        }
    }
}

// ---------------- fp8 gather+self(+relu), D=256 ----------------
template <bool RELU>
__global__ __launch_bounds__(256) void k_agg256_f8(const u8* __restrict__ h8, const int* __restrict__ rp,
                                                   const int* __restrict__ cs, u16* __restrict__ out)
{
    const int lane = threadIdx.x & 63;
    const int n = blockIdx.x * 4 + (threadIdx.x >> 6);
    const int g = lane >> 4;
    const int c = lane & 15;
    const uint4* hb = (const uint4*)h8 + c;

    float acc[16];
#pragma unroll
    for (int i = 0; i < 16; ++i) acc[i] = 0.f;
    if (g == 0) dec16(acc, hb[(size_t)n * 16]);

    const int beg = rp[n], end = rp[n + 1];
    int e = beg;
    for (; e + 16 <= end; e += 16) {
        uint4 v0 = hb[(size_t)cs[e + g] * 16];
        uint4 v1 = hb[(size_t)cs[e + 4 + g] * 16];
        uint4 v2 = hb[(size_t)cs[e + 8 + g] * 16];
        uint4 v3 = hb[(size_t)cs[e + 12 + g] * 16];
        dec16(acc, v0); dec16(acc, v1); dec16(acc, v2); dec16(acc, v3);
    }
    for (; e + 4 <= end; e += 4) {
        uint4 v = hb[(size_t)cs[e + g] * 16];
        dec16(acc, v);
    }
    if (e + g < end) {
        uint4 v = hb[(size_t)cs[e + g] * 16];
        dec16(acc, v);
    }
#pragma unroll
    for (int i = 0; i < 16; ++i) acc[i] += __shfl_xor(acc[i], 16);
#pragma unroll
    for (int i = 0; i < 16; ++i) acc[i] += __shfl_xor(acc[i], 32);
    if (g == 0) {
        if (RELU) {
#pragma unroll
            for (int i = 0; i < 16; ++i) acc[i] = fmaxf(acc[i], 0.f);
        }
        uint4 o0, o1;
        o0.x = pack2(acc[0], acc[1]);  o0.y = pack2(acc[2], acc[3]);
        o0.z = pack2(acc[4], acc[5]);  o0.w = pack2(acc[6], acc[7]);
        o1.x = pack2(acc[8], acc[9]);  o1.y = pack2(acc[10], acc[11]);
        o1.z = pack2(acc[12], acc[13]); o1.w = pack2(acc[14], acc[15]);
        uint4* op = (uint4*)((u32*)out + (size_t)n * 128 + c * 8);
        op[0] = o0; op[1] = o1;
    }
}

// ---------------- fp8 gather+self(+relu), D=512 ----------------
template <bool RELU>
__global__ __launch_bounds__(256) void k_agg512_f8(const u8* __restrict__ h8, const int* __restrict__ rp,
                                                   const int* __restrict__ cs, u16* __restrict__ out)
{
    const int lane = threadIdx.x & 63;
    const int n = blockIdx.x * 4 + (threadIdx.x >> 6);
    const int g = lane >> 5;
    const int c = lane & 31;
    const uint4* hb = (const uint4*)h8 + c;

    float acc[16];
#pragma unroll
    for (int i = 0; i < 16; ++i) acc[i] = 0.f;
    if (g == 0) dec16(acc, hb[(size_t)n * 32]);

    const int beg = rp[n], end = rp[n + 1];
    int e = beg;
    for (; e + 8 <= end; e += 8) {
        uint4 v0 = hb[(size_t)cs[e + g] * 32];
        uint4 v1 = hb[(size_t)cs[e + 2 + g] * 32];
        uint4 v2 = hb[(size_t)cs[e + 4 + g] * 32];
        uint4 v3 = hb[(size_t)cs[e + 6 + g] * 32];
        dec16(acc, v0); dec16(acc, v1); dec16(acc, v2); dec16(acc, v3);
    }
    for (; e + 2 <= end; e += 2) {
        uint4 v = hb[(size_t)cs[e + g] * 32];
        dec16(acc, v);
    }
    if (e + g < end) {
        uint4 v = hb[(size_t)cs[e + g] * 32];
        dec16(acc, v);
    }
#pragma unroll
    for (int i = 0; i < 16; ++i) acc[i] += __shfl_xor(acc[i], 32);
    if (g == 0) {
        if (RELU) {
#pragma unroll
            for (int i = 0; i < 16; ++i) acc[i] = fmaxf(acc[i], 0.f);
        }
        uint4 o0, o1;
        o0.x = pack2(acc[0], acc[1]);  o0.y = pack2(acc[2], acc[3]);
        o0.z = pack2(acc[4], acc[5]);  o0.w = pack2(acc[6], acc[7]);
        o1.x = pack2(acc[8], acc[9]);  o1.y = pack2(acc[10], acc[11]);
        o1.z = pack2(acc[12], acc[13]); o1.w = pack2(acc[14], acc[15]);
        uint4* op = (uint4*)((u32*)out + (size_t)n * 256 + c * 8);
        op[0] = o0; op[1] = o1;
    }
}

// ---------------- BN stats, stage A: per-block partials, NO atomics ----------------
// 2000 blocks x 16 rows; wave-per-row coalesced uint4 loads; LDS reduce [16][256] (conflict-free);
// block writes 2D partial sums (sum | sumsq) as float4 stores.
template <int D>
__global__ __launch_bounds__(256) void k_bn_part(const u16* __restrict__ h, float* __restrict__ partial)
{
    constexpr int SLOT = D / 8;        // uint4 per row: 64 (512) / 32 (256)
    constexpr int NS = 256 / SLOT;     // 4 / 8
    constexpr int ROWS = 16;
    const int t = threadIdx.x;
    const int s = t % SLOT, j = t / SLOT;
    const int r0 = blockIdx.x * ROWS;
    float a[8] = {}, q[8] = {};
#pragma unroll
    for (int rr = 0; rr < ROWS / NS; ++rr) {
        int r = j + rr * NS;
        uint4 v = *((const uint4*)(h + (size_t)(r0 + r) * D) + s);
        u32 wv[4] = {v.x, v.y, v.z, v.w};
#pragma unroll
        for (int k = 0; k < 4; ++k) {
            float lo = bf_lo(wv[k]), hi = bf_hi(wv[k]);
            a[2 * k]     += lo; q[2 * k]     = fmaf(lo, lo, q[2 * k]);
            a[2 * k + 1] += hi; q[2 * k + 1] = fmaf(hi, hi, q[2 * k + 1]);
        }
    }
    __shared__ float red[16][256];
#pragma unroll
    for (int i = 0; i < 8; ++i) { red[i][t] = a[i]; red[8 + i][t] = q[i]; }
    __syncthreads();
    if (j == 0) {
        for (int k = 1; k < NS; ++k) {
            int o = k * SLOT + s;
#pragma unroll
            for (int i = 0; i < 8; ++i) { a[i] += red[i][o]; q[i] += red[8 + i][o]; }
        }
        float* pb = partial + (size_t)blockIdx.x * (2 * D);
        float4* p0 = (float4*)(pb + 8 * s);
        p0[0] = make_float4(a[0], a[1], a[2], a[3]);
        p0[1] = make_float4(a[4], a[5], a[6], a[7]);
        float4* p1 = (float4*)(pb + D + 8 * s);
        p1[0] = make_float4(q[0], q[1], q[2], q[3]);
        p1[1] = make_float4(q[4], q[5], q[6], q[7]);
    }
}

// ---------------- BN stats, stage B: reduce partials (coalesced; 8K atomics total) ----------------
template <int D, int P, int SEG>
__global__ __launch_bounds__(256) void k_bn_red(const float* __restrict__ partial, float* __restrict__ sums)
{
    const int g = blockIdx.x * 256 + threadIdx.x;
    const int col = g & (2 * D - 1);
    const int seg = g / (2 * D);
    constexpr int CHUNK = P / SEG;
    const float* p = partial + (size_t)seg * CHUNK * (2 * D) + col;
    float acc = 0.f;
#pragma unroll 4
    for (int i = 0; i < CHUNK; ++i) acc += p[(size_t)i * (2 * D)];
    atomicAdd(&sums[col], acc);
}

__global__ __launch_bounds__(512) void k_bn_finalize(const float* __restrict__ sums, const float* __restrict__ gam,
                                                     const float* __restrict__ bet, float* __restrict__ ss, int D)
{
    int t = threadIdx.x;
    if (t < D) {
        const float invN = 1.f / (float)N_NODES;
        float mu  = sums[t] * invN;
        float var = sums[D + t] * invN - mu * mu;
        float rs  = rsqrtf(var + 1e-5f);
        float sc  = gam[t] * rs;
        ss[t]     = sc;
        ss[D + t] = bet[t] - mu * sc;
    }
}

__global__ __launch_bounds__(256) void k_bn_apply(u16* __restrict__ h, const float* __restrict__ ss, int D)
{
    int i = blockIdx.x * 256 + threadIdx.x;
    uint4 v = ((uint4*)h)[i];
    int c = (i * 8) & (D - 1);
    const float* sc = &ss[c];
    const float* sh = &ss[D + c];
    u32 r[4];
    u32 vv[4] = {v.x, v.y, v.z, v.w};
#pragma unroll
    for (int k = 0; k < 4; ++k) {
        float a = leakyf(fmaf(bf_lo(vv[k]), sc[2 * k], sh[2 * k]));
        float b = leakyf(fmaf(bf_hi(vv[k]), sc[2 * k + 1], sh[2 * k + 1]));
        r[k] = pack2(a, b);
    }
    ((uint4*)h)[i] = make_uint4(r[0], r[1], r[2], r[3]);
}

// ---------------- pool + head ----------------
__global__ __launch_bounds__(256) void k_pool(const u16* __restrict__ h, float* __restrict__ gp)
{
    int b = blockIdx.x, ch = blockIdx.y, t = threadIdx.x;
    int s = t & 63, j = t >> 6;
    int r0 = b * 2000 + ch * 80;
    float a0 = 0.f, a1 = 0.f, a2 = 0.f, a3 = 0.f;
    for (int r = j; r < 80; r += 4) {
        uint2 v = *((const uint2*)(h + (size_t)(r0 + r) * 256) + s);
        a0 += bf_lo(v.x); a1 += bf_hi(v.x); a2 += bf_lo(v.y); a3 += bf_hi(v.y);
    }
    atomicAdd(&gp[b * 256 + s * 4 + 0], a0);
    atomicAdd(&gp[b * 256 + s * 4 + 1], a1);
    atomicAdd(&gp[b * 256 + s * 4 + 2], a2);
    atomicAdd(&gp[b * 256 + s * 4 + 3], a3);
}

__global__ __launch_bounds__(64) void k_final(const float* __restrict__ gp, const float* __restrict__ Wp,
                                              const float* __restrict__ bp, float* __restrict__ out)
{
    __shared__ float lg[32];
    int t = threadIdx.x;
    if (t < 32) {
        int b = t >> 1, c = t & 1;
        float s = 0.f;
        for (int k = 0; k < 256; ++k) s = fmaf(gp[b * 256 + k], Wp[c * 256 + k], s);
        float o = s * (1.f / 2000.f) + bp[c];
        out[b * 2 + c] = o;
        lg[t] = o;
    }
    __syncthreads();
    if (t < 16) out[32 + t] = (lg[t * 2 + 1] > lg[t * 2]) ? 1.f : 0.f;
}

extern "C" void kernel_launch(void* const* d_in, const int* in_sizes, int n_in,
                              void* d_out, int out_size, void* d_ws, size_t ws_size,
                              hipStream_t stream)
{
    const float* x   = (const float*)d_in[0];
    const int*   ei  = (const int*)d_in[1];
    const float* W1  = (const float*)d_in[2];
    const float* b1  = (const float*)d_in[3];
    const float* W2  = (const float*)d_in[4];
    const float* b2  = (const float*)d_in[5];
    const float* W3  = (const float*)d_in[6];
    const float* b3  = (const float*)d_in[7];
    const float* g1  = (const float*)d_in[8];
    const float* be1 = (const float*)d_in[9];
    const float* g2  = (const float*)d_in[10];
    const float* be2 = (const float*)d_in[11];
    const float* g3  = (const float*)d_in[12];
    const float* be3 = (const float*)d_in[13];
    const float* Wp  = (const float*)d_in[14];
    const float* bp  = (const float*)d_in[15];
    float* out = (float*)d_out;

    const int E = in_sizes[1] / 2;
    const int* src = ei;
    const int* dst = ei + E;

    char* ws = (char*)d_ws;
    size_t off = 0;
    auto alloc = [&](size_t bytes) -> void* {
        void* p = ws + off;
        off = (off + bytes + 255) & ~(size_t)255;
        return p;
    };
    u16*   bufA = (u16*)alloc((size_t)N_NODES * 512 * 2);
    u16*   bufB = (u16*)alloc((size_t)N_NODES * 512 * 2);
    u8*    buf8 = (u8*)alloc((size_t)N_NODES * 512);
    u8*    x8   = (u8*)alloc((size_t)N_NODES * 256);
    u16*   w1b  = (u16*)alloc(512 * 256 * 2);
    u16*   w2b  = (u16*)alloc(512 * 512 * 2);
    u16*   w3b  = (u16*)alloc(256 * 512 * 2);
    int*   cs   = (int*)alloc((size_t)E * 4);
    int*   rp   = (int*)alloc((size_t)(N_NODES + 1) * 4);
    int*   cnt  = (int*)alloc((size_t)N_NODES * 4);
    int*   cur  = (int*)alloc((size_t)N_NODES * 4);
    int*   bsum = (int*)alloc(256 * 4);
    float* part = (float*)alloc((size_t)2000 * 1024 * 4);   // BN stage-A partials (max 8MB)
    float* sums = (float*)alloc(1024 * 4);
    float* ss   = (float*)alloc(1024 * 4);
    float* gp   = (float*)alloc(16 * 256 * 4);

    // CSR build (parallel 3-phase scan)
    hipMemsetAsync(cnt, 0, (size_t)N_NODES * 4, stream);
    hipMemsetAsync(cur, 0, (size_t)N_NODES * 4, stream);
    const int eb = (E + 255) / 256;
    const int nb = N_NODES / 256;   // 125
    k_count<<<eb, 256, 0, stream>>>(dst, cnt, E);
    k_scan_blk<<<nb, 256, 0, stream>>>(cnt, rp, bsum);
    k_scan_top<<<1, 128, 0, stream>>>(bsum, nb);
    k_scan_add<<<nb, 256, 0, stream>>>(rp, bsum, N_NODES, E);
    k_place<<<eb, 256, 0, stream>>>(src, dst, rp, cur, cs, E);

    // conversions: x -> fp8 gather table; weights -> bf16
    k_cvt8<<<N_NODES * 256 / 4 / 256, 256, 0, stream>>>(x, (u32*)x8);
    k_cvt<<<512 * 256 / 4 / 256, 256, 0, stream>>>(W1, w1b);
    k_cvt<<<512 * 512 / 4 / 256, 256, 0, stream>>>(W2, w2b);
    k_cvt<<<256 * 512 / 4 / 256, 256, 0, stream>>>(W3, w3b);

    const int PB = N_NODES / 16;    // 2000 stage-A blocks

    // ---- layer 1 (linearity): s = x + sum_src x (fp8 gather); h1 = relu(s@W1' + (deg+1)*b1) ----
    k_agg256_f8<false><<<N_NODES / 4, 256, 0, stream>>>(x8, rp, cs, bufA);
    k_gemm_mfma<true, true, false><<<dim3(250, 4), 256, 0, stream>>>(bufA, w1b, b1, rp, bufB, 256, 512);
    hipMemsetAsync(sums, 0, 1024 * 4, stream);
    k_bn_part<512><<<PB, 256, 0, stream>>>(bufB, part);
    k_bn_red<512, 2000, 8><<<32, 256, 0, stream>>>(part, sums);
    k_bn_finalize<<<1, 512, 0, stream>>>(sums, g1, be1, ss, 512);
    k_bn_apply<<<N_NODES * 512 / 8 / 256, 256, 0, stream>>>(bufB, ss, 512);

    // ---- layer 2: GEMM (bf16 in, fp8 out) then 512-wide fp8 gather + relu ----
    k_gemm_mfma<false, false, true><<<dim3(250, 4), 256, 0, stream>>>(bufB, w2b, b2, rp, buf8, 512, 512);
    k_agg512_f8<true><<<N_NODES / 4, 256, 0, stream>>>(buf8, rp, cs, bufA);
    hipMemsetAsync(sums, 0, 1024 * 4, stream);
    k_bn_part<512><<<PB, 256, 0, stream>>>(bufA, part);
    k_bn_red<512, 2000, 8><<<32, 256, 0, stream>>>(part, sums);
    k_bn_finalize<<<1, 512, 0, stream>>>(sums, g2, be2, ss, 512);
    k_bn_apply<<<N_NODES * 512 / 8 / 256, 256, 0, stream>>>(bufA, ss, 512);

    // ---- layer 3: GEMM (512->256, fp8 out) then 256-wide fp8 gather + relu ----
    k_gemm_mfma<false, false, true><<<dim3(250, 2), 256, 0, stream>>>(bufA, w3b, b3, rp, buf8, 512, 256);
    k_agg256_f8<true><<<N_NODES / 4, 256, 0, stream>>>(buf8, rp, cs, bufB);
    hipMemsetAsync(sums, 0, 1024 * 4, stream);
    k_bn_part<256><<<PB, 256, 0, stream>>>(bufB, part);
    k_bn_red<256, 2000, 8><<<16, 256, 0, stream>>>(part, sums);
    k_bn_finalize<<<1, 512, 0, stream>>>(sums, g3, be3, ss, 256);
    k_bn_apply<<<N_NODES * 256 / 8 / 256, 256, 0, stream>>>(bufB, ss, 256);

    // ---- pool + head ----
    hipMemsetAsync(gp, 0, 16 * 256 * 4, stream);
    k_pool<<<dim3(16, 25), 256, 0, stream>>>(bufB, gp);
    k_final<<<1, 64, 0, stream>>>(gp, Wp, bp, out);
}

// Round 9
// 439.336 us; speedup vs baseline: 2.0764x; 1.0041x over previous
//
#include <hip/hip_runtime.h>

#define N_NODES 32000
typedef unsigned short u16;
typedef unsigned int u32;
typedef unsigned char u8;
typedef __attribute__((ext_vector_type(8))) short bf16x8;
typedef __attribute__((ext_vector_type(4))) float f32x4;
typedef __attribute__((ext_vector_type(2))) float f32x2;

__device__ __forceinline__ float leakyf(float v) { return v >= 0.f ? v : 0.1f * v; }
__device__ __forceinline__ u16 f2bf(float f) {
    u32 u = __float_as_uint(f);
    return (u16)((u + 0x7FFFu + ((u >> 16) & 1u)) >> 16);
}
__device__ __forceinline__ float bf2f(u16 h) { return __uint_as_float(((u32)h) << 16); }
__device__ __forceinline__ float bf_lo(u32 u) { return __uint_as_float(u << 16); }
__device__ __forceinline__ float bf_hi(u32 u) { return __uint_as_float(u & 0xFFFF0000u); }
__device__ __forceinline__ u32 pack2(float a, float b) { return (u32)f2bf(a) | ((u32)f2bf(b) << 16); }

// fp8 e4m3 (OCP on gfx950) decode: 4 floats from one u32
__device__ __forceinline__ void dec4(float* acc, u32 w) {
    f32x2 lo = __builtin_amdgcn_cvt_pk_f32_fp8(w, false);
    f32x2 hi = __builtin_amdgcn_cvt_pk_f32_fp8(w, true);
    acc[0] += lo[0]; acc[1] += lo[1]; acc[2] += hi[0]; acc[3] += hi[1];
}
__device__ __forceinline__ void dec16(float* acc, uint4 v) {
    dec4(acc + 0, v.x); dec4(acc + 4, v.y); dec4(acc + 8, v.z); dec4(acc + 12, v.w);
}
__device__ __forceinline__ u8 f2fp8(float v) {
    return (u8)__builtin_amdgcn_cvt_pk_fp8_f32(v, v, 0, false);
}

__device__ __forceinline__ void gload16(const u16* g, u16* l) {
    __builtin_amdgcn_global_load_lds((const __attribute__((address_space(1))) void*)g,
                                     (__attribute__((address_space(3))) void*)l, 16, 0, 0);
}

// ---------------- CSR build ----------------
__global__ __launch_bounds__(256) void k_count(const int* __restrict__ dst, int* __restrict__ cnt, int E)
{
    int e = blockIdx.x * 256 + threadIdx.x;
    if (e < E) atomicAdd(&cnt[dst[e]], 1);
}

__global__ __launch_bounds__(256) void k_scan_blk(const int* __restrict__ cnt, int* __restrict__ rp,
                                                  int* __restrict__ bsum)
{
    __shared__ int sh[256];
    const int b = blockIdx.x, t = threadIdx.x;
    int v = cnt[b * 256 + t];
    sh[t] = v;
    __syncthreads();
    for (int off = 1; off < 256; off <<= 1) {
        int u = (t >= off) ? sh[t - off] : 0;
        __syncthreads();
        sh[t] += u;
        __syncthreads();
    }
    rp[b * 256 + t] = sh[t] - v;
    if (t == 255) bsum[b] = sh[255];
}

__global__ __launch_bounds__(128) void k_scan_top(int* __restrict__ bsum, int nb)
{
    __shared__ int sh[128];
    const int t = threadIdx.x;
    int v = (t < nb) ? bsum[t] : 0;
    sh[t] = v;
    __syncthreads();
    for (int off = 1; off < 128; off <<= 1) {
        int u = (t >= off) ? sh[t - off] : 0;
        __syncthreads();
        sh[t] += u;
        __syncthreads();
    }
    if (t < nb) bsum[t] = sh[t] - v;
}

__global__ __launch_bounds__(256) void k_scan_add(int* __restrict__ rp, const int* __restrict__ bsum,
                                                  int n, int E)
{
    int i = blockIdx.x * 256 + threadIdx.x;
    rp[i] += bsum[blockIdx.x];
    if (i == 0) rp[n] = E;
}

__global__ __launch_bounds__(256) void k_place(const int* __restrict__ src, const int* __restrict__ dst,
                                               const int* __restrict__ rp, int* __restrict__ cur,
                                               int* __restrict__ cs, int E)
{
    int e = blockIdx.x * 256 + threadIdx.x;
    if (e < E) {
        int d = dst[e];
        int p = rp[d] + atomicAdd(&cur[d], 1);
        cs[p] = src[e];
    }
}

// ---------------- conversions ----------------
__global__ __launch_bounds__(256) void k_cvt8(const float* __restrict__ in, u32* __restrict__ out)
{
    int i = blockIdx.x * 256 + threadIdx.x;
    float4 v = ((const float4*)in)[i];
    int p = __builtin_amdgcn_cvt_pk_fp8_f32(v.x, v.y, 0, false);
    p = __builtin_amdgcn_cvt_pk_fp8_f32(v.z, v.w, p, true);
    out[i] = (u32)p;
}

// fused: all 3 weight matrices -> bf16 in one launch (128+256+128 blocks)
__global__ __launch_bounds__(256) void k_cvtw(const float* __restrict__ W1, const float* __restrict__ W2,
                                              const float* __restrict__ W3, u16* __restrict__ o1,
                                              u16* __restrict__ o2, u16* __restrict__ o3)
{
    int b = blockIdx.x;
    const float* in; u16* out; int i;
    if (b < 128)      { in = W1; out = o1; i = b * 256 + threadIdx.x; }
    else if (b < 384) { in = W2; out = o2; i = (b - 128) * 256 + threadIdx.x; }
    else              { in = W3; out = o3; i = (b - 384) * 256 + threadIdx.x; }
    float4 v = ((const float4*)in)[i];
    ushort4 o;
    o.x = f2bf(v.x); o.y = f2bf(v.y); o.z = f2bf(v.z); o.w = f2bf(v.w);
    ((ushort4*)out)[i] = o;
}

// ---------------- bf16 MFMA GEMM, 2-phase double-buffered ----------------
// C[m][o] = sum_k A[m][k]*W[o][k] + biasmul*bias[o]; biasmul=(deg+1) if DEGB; out bf16 or fp8.
template <bool RELU, bool DEGB, bool F8OUT>
__global__ __launch_bounds__(256) void k_gemm_mfma(const u16* __restrict__ A, const u16* __restrict__ W,
                                                   const float* __restrict__ bias, const int* __restrict__ rp,
                                                   void* __restrict__ Cv, int K, int OD)
{
    __shared__ u16 As[2][128 * 32];
    __shared__ u16 Bs[2][128 * 32];
    const int t = threadIdx.x;
    const int lane = t & 63;
    const int w = t >> 6;
    const int wr = w >> 1, wc = w & 1;
    const int bm = blockIdx.x * 128;
    const int bn = blockIdx.y * 128;

    const int c0 = w * 64 + lane;
    const int r0 = c0 >> 2, kc0 = (c0 & 3) * 8;
    const int c1 = c0 + 256;
    const int r1 = c1 >> 2, kc1 = (c1 & 3) * 8;
    const u16* gA0 = A + (size_t)(bm + r0) * K + kc0;
    const u16* gA1 = A + (size_t)(bm + r1) * K + kc1;
    const u16* gB0 = W + (size_t)(bn + r0) * K + kc0;
    const u16* gB1 = W + (size_t)(bn + r1) * K + kc1;

    f32x4 acc[4][4];
#pragma unroll
    for (int i = 0; i < 4; ++i)
#pragma unroll
        for (int j = 0; j < 4; ++j)
            acc[i][j] = (f32x4){0.f, 0.f, 0.f, 0.f};

    const int fr = lane & 15;
    const int ko = (lane >> 4) * 8;

    auto STAGE = [&](int b, int k0) {
        gload16(gA0 + k0, &As[b][0] + w * 512);
        gload16(gA1 + k0, &As[b][0] + 2048 + w * 512);
        gload16(gB0 + k0, &Bs[b][0] + w * 512);
        gload16(gB1 + k0, &Bs[b][0] + 2048 + w * 512);
    };

    // prologue: fill buffer 0
    STAGE(0, 0);
    asm volatile("s_waitcnt vmcnt(0)" ::: "memory");
    __syncthreads();

    int cur = 0;
    for (int k0 = 0; k0 < K; k0 += 32) {
        if (k0 + 32 < K) STAGE(cur ^ 1, k0 + 32);   // prefetch next tile (overlaps compute)
        bf16x8 af[4], bfv[4];
#pragma unroll
        for (int i = 0; i < 4; ++i)
            af[i] = *(const bf16x8*)&As[cur][(wr * 64 + i * 16 + fr) * 32 + ko];
#pragma unroll
        for (int j = 0; j < 4; ++j)
            bfv[j] = *(const bf16x8*)&Bs[cur][(wc * 64 + j * 16 + fr) * 32 + ko];
#pragma unroll
        for (int i = 0; i < 4; ++i)
#pragma unroll
            for (int j = 0; j < 4; ++j)
                acc[i][j] = __builtin_amdgcn_mfma_f32_16x16x32_bf16(af[i], bfv[j], acc[i][j], 0, 0, 0);
        asm volatile("s_waitcnt vmcnt(0)" ::: "memory");   // prefetched tile landed
        __syncthreads();                                    // all waves done reading cur
        cur ^= 1;
    }

    u16* C16 = (u16*)Cv;
    u8*  C8  = (u8*)Cv;
    const int qr = (lane >> 4) * 4;
    float bcol[4];
#pragma unroll
    for (int j = 0; j < 4; ++j) bcol[j] = bias[bn + wc * 64 + j * 16 + fr];
#pragma unroll
    for (int i = 0; i < 4; ++i) {
#pragma unroll
        for (int r = 0; r < 4; ++r) {
            int row = bm + wr * 64 + i * 16 + qr + r;
            float bm_ = 1.f;
            if (DEGB) bm_ = (float)(rp[row + 1] - rp[row]) + 1.f;
#pragma unroll
            for (int j = 0; j < 4; ++j) {
                int col = bn + wc * 64 + j * 16 + fr;
                float o = acc[i][j][r] + bm_ * bcol[j];
                if (RELU) o = fmaxf(o, 0.f);
                if (F8OUT) C8[(size_t)row * OD + col] = f2fp8(o);
                else       C16[(size_t)row * OD + col] = f2bf(o);
            }
        }
    }
}

// ---------------- fp8 gather+self(+relu), D=256 ----------------
template <bool RELU>
__global__ __launch_bounds__(256) void k_agg256_f8(const u8* __restrict__ h8, const int* __restrict__ rp,
                                                   const int* __restrict__ cs, u16* __restrict__ out)
{
    const int lane = threadIdx.x & 63;
    const int n = blockIdx.x * 4 + (threadIdx.x >> 6);
    const int g = lane >> 4;
    const int c = lane & 15;
    const uint4* hb = (const uint4*)h8 + c;

    float acc[16];
#pragma unroll
    for (int i = 0; i < 16; ++i) acc[i] = 0.f;
    if (g == 0) dec16(acc, hb[(size_t)n * 16]);

    const int beg = rp[n], end = rp[n + 1];
    int e = beg;
    for (; e + 16 <= end; e += 16) {
        uint4 v0 = hb[(size_t)cs[e + g] * 16];
        uint4 v1 = hb[(size_t)cs[e + 4 + g] * 16];
        uint4 v2 = hb[(size_t)cs[e + 8 + g] * 16];
        uint4 v3 = hb[(size_t)cs[e + 12 + g] * 16];
        dec16(acc, v0); dec16(acc, v1); dec16(acc, v2); dec16(acc, v3);
    }
    for (; e + 4 <= end; e += 4) {
        uint4 v = hb[(size_t)cs[e + g] * 16];
        dec16(acc, v);
    }
    if (e + g < end) {
        uint4 v = hb[(size_t)cs[e + g] * 16];
        dec16(acc, v);
    }
#pragma unroll
    for (int i = 0; i < 16; ++i) acc[i] += __shfl_xor(acc[i], 16);
#pragma unroll
    for (int i = 0; i < 16; ++i) acc[i] += __shfl_xor(acc[i], 32);
    if (g == 0) {
        if (RELU) {
#pragma unroll
            for (int i = 0; i < 16; ++i) acc[i] = fmaxf(acc[i], 0.f);
        }
        uint4 o0, o1;
        o0.x = pack2(acc[0], acc[1]);  o0.y = pack2(acc[2], acc[3]);
        o0.z = pack2(acc[4], acc[5]);  o0.w = pack2(acc[6], acc[7]);
        o1.x = pack2(acc[8], acc[9]);  o1.y = pack2(acc[10], acc[11]);
        o1.z = pack2(acc[12], acc[13]); o1.w = pack2(acc[14], acc[15]);
        uint4* op = (uint4*)((u32*)out + (size_t)n * 128 + c * 8);
        op[0] = o0; op[1] = o1;
    }
}

// ---------------- fp8 gather+self(+relu), D=512: half-wave rows, 8 loads in flight ----------------
template <bool RELU>
__global__ __launch_bounds__(256) void k_agg512_f8(const u8* __restrict__ h8, const int* __restrict__ rp,
                                                   const int* __restrict__ cs, u16* __restrict__ out)
{
    const int lane = threadIdx.x & 63;
    const int n = blockIdx.x * 4 + (threadIdx.x >> 6);
    const int g = lane >> 5;
    const int c = lane & 31;
    const uint4* hb = (const uint4*)h8 + c;

    float acc[16];
#pragma unroll
    for (int i = 0; i < 16; ++i) acc[i] = 0.f;
    if (g == 0) dec16(acc, hb[(size_t)n * 32]);

    const int beg = rp[n], end = rp[n + 1];
    int e = beg;
    for (; e + 16 <= end; e += 16) {
        uint4 v[8];
#pragma unroll
        for (int u = 0; u < 8; ++u) v[u] = hb[(size_t)cs[e + 2 * u + g] * 32];
#pragma unroll
        for (int u = 0; u < 8; ++u) dec16(acc, v[u]);
    }
    for (; e + 8 <= end; e += 8) {
        uint4 v[4];
#pragma unroll
        for (int u = 0; u < 4; ++u) v[u] = hb[(size_t)cs[e + 2 * u + g] * 32];
#pragma unroll
        for (int u = 0; u < 4; ++u) dec16(acc, v[u]);
    }
    for (; e + 2 <= end; e += 2) {
        uint4 v = hb[(size_t)cs[e + g] * 32];
        dec16(acc, v);
    }
    if (e + g < end) {
        uint4 v = hb[(size_t)cs[e + g] * 32];
        dec16(acc, v);
    }
#pragma unroll
    for (int i = 0; i < 16; ++i) acc[i] += __shfl_xor(acc[i], 32);
    if (g == 0) {
        if (RELU) {
#pragma unroll
            for (int i = 0; i < 16; ++i) acc[i] = fmaxf(acc[i], 0.f);
        }
        uint4 o0, o1;
        o0.x = pack2(acc[0], acc[1]);  o0.y = pack2(acc[2], acc[3]);
        o0.z = pack2(acc[4], acc[5]);  o0.w = pack2(acc[6], acc[7]);
        o1.x = pack2(acc[8], acc[9]);  o1.y = pack2(acc[10], acc[11]);
        o1.z = pack2(acc[12], acc[13]); o1.w = pack2(acc[14], acc[15]);
        uint4* op = (uint4*)((u32*)out + (size_t)n * 256 + c * 8);
        op[0] = o0; op[1] = o1;
    }
}

// ---------------- BN stats, stage A: per-block partials, NO atomics ----------------
template <int D>
__global__ __launch_bounds__(256) void k_bn_part(const u16* __restrict__ h, float* __restrict__ partial)
{
    constexpr int SLOT = D / 8;
    constexpr int NS = 256 / SLOT;
    constexpr int ROWS = 16;
    const int t = threadIdx.x;
    const int s = t % SLOT, j = t / SLOT;
    const int r0 = blockIdx.x * ROWS;
    float a[8] = {}, q[8] = {};
#pragma unroll
    for (int rr = 0; rr < ROWS / NS; ++rr) {
        int r = j + rr * NS;
        uint4 v = *((const uint4*)(h + (size_t)(r0 + r) * D) + s);
        u32 wv[4] = {v.x, v.y, v.z, v.w};
#pragma unroll
        for (int k = 0; k < 4; ++k) {
            float lo = bf_lo(wv[k]), hi = bf_hi(wv[k]);
            a[2 * k]     += lo; q[2 * k]     = fmaf(lo, lo, q[2 * k]);
            a[2 * k + 1] += hi; q[2 * k + 1] = fmaf(hi, hi, q[2 * k + 1]);
        }
    }
    __shared__ float red[16][256];
#pragma unroll
    for (int i = 0; i < 8; ++i) { red[i][t] = a[i]; red[8 + i][t] = q[i]; }
    __syncthreads();
    if (j == 0) {
        for (int k = 1; k < NS; ++k) {
            int o = k * SLOT + s;
#pragma unroll
            for (int i = 0; i < 8; ++i) { a[i] += red[i][o]; q[i] += red[8 + i][o]; }
        }
        float* pb = partial + (size_t)blockIdx.x * (2 * D);
        float4* p0 = (float4*)(pb + 8 * s);
        p0[0] = make_float4(a[0], a[1], a[2], a[3]);
        p0[1] = make_float4(a[4], a[5], a[6], a[7]);
        float4* p1 = (float4*)(pb + D + 8 * s);
        p1[0] = make_float4(q[0], q[1], q[2], q[3]);
        p1[1] = make_float4(q[4], q[5], q[6], q[7]);
    }
}

// ---------------- BN stats, stage B: reduce partials (coalesced; few atomics) ----------------
template <int D, int P, int SEG>
__global__ __launch_bounds__(256) void k_bn_red(const float* __restrict__ partial, float* __restrict__ sums)
{
    const int g = blockIdx.x * 256 + threadIdx.x;
    const int col = g & (2 * D - 1);
    const int seg = g / (2 * D);
    constexpr int CHUNK = P / SEG;
    const float* p = partial + (size_t)seg * CHUNK * (2 * D) + col;
    float acc = 0.f;
#pragma unroll 4
    for (int i = 0; i < CHUNK; ++i) acc += p[(size_t)i * (2 * D)];
    atomicAdd(&sums[col], acc);
}

__global__ __launch_bounds__(512) void k_bn_finalize(const float* __restrict__ sums, const float* __restrict__ gam,
                                                     const float* __restrict__ bet, float* __restrict__ ss, int D)
{
    int t = threadIdx.x;
    if (t < D) {
        const float invN = 1.f / (float)N_NODES;
        float mu  = sums[t] * invN;
        float var = sums[D + t] * invN - mu * mu;
        float rs  = rsqrtf(var + 1e-5f);
        float sc  = gam[t] * rs;
        ss[t]     = sc;
        ss[D + t] = bet[t] - mu * sc;
    }
}

__global__ __launch_bounds__(256) void k_bn_apply(u16* __restrict__ h, const float* __restrict__ ss, int D)
{
    int i = blockIdx.x * 256 + threadIdx.x;
    uint4 v = ((uint4*)h)[i];
    int c = (i * 8) & (D - 1);
    const float* sc = &ss[c];
    const float* sh = &ss[D + c];
    u32 r[4];
    u32 vv[4] = {v.x, v.y, v.z, v.w};
#pragma unroll
    for (int k = 0; k < 4; ++k) {
        float a = leakyf(fmaf(bf_lo(vv[k]), sc[2 * k], sh[2 * k]));
        float b = leakyf(fmaf(bf_hi(vv[k]), sc[2 * k + 1], sh[2 * k + 1]));
        r[k] = pack2(a, b);
    }
    ((uint4*)h)[i] = make_uint4(r[0], r[1], r[2], r[3]);
}

// ---------------- pool + head ----------------
__global__ __launch_bounds__(256) void k_pool(const u16* __restrict__ h, float* __restrict__ gp)
{
    int b = blockIdx.x, ch = blockIdx.y, t = threadIdx.x;
    int s = t & 63, j = t >> 6;
    int r0 = b * 2000 + ch * 80;
    float a0 = 0.f, a1 = 0.f, a2 = 0.f, a3 = 0.f;
    for (int r = j; r < 80; r += 4) {
        uint2 v = *((const uint2*)(h + (size_t)(r0 + r) * 256) + s);
        a0 += bf_lo(v.x); a1 += bf_hi(v.x); a2 += bf_lo(v.y); a3 += bf_hi(v.y);
    }
    atomicAdd(&gp[b * 256 + s * 4 + 0], a0);
    atomicAdd(&gp[b * 256 + s * 4 + 1], a1);
    atomicAdd(&gp[b * 256 + s * 4 + 2], a2);
    atomicAdd(&gp[b * 256 + s * 4 + 3], a3);
}

__global__ __launch_bounds__(64) void k_final(const float* __restrict__ gp, const float* __restrict__ Wp,
                                              const float* __restrict__ bp, float* __restrict__ out)
{
    __shared__ float lg[32];
    int t = threadIdx.x;
    if (t < 32) {
        int b = t >> 1, c = t & 1;
        float s = 0.f;
        for (int k = 0; k < 256; ++k) s = fmaf(gp[b * 256 + k], Wp[c * 256 + k], s);
        float o = s * (1.f / 2000.f) + bp[c];
        out[b * 2 + c] = o;
        lg[t] = o;
    }
    __syncthreads();
    if (t < 16) out[32 + t] = (lg[t * 2 + 1] > lg[t * 2]) ? 1.f : 0.f;
}

extern "C" void kernel_launch(void* const* d_in, const int* in_sizes, int n_in,
                              void* d_out, int out_size, void* d_ws, size_t ws_size,
                              hipStream_t stream)
{
    const float* x   = (const float*)d_in[0];
    const int*   ei  = (const int*)d_in[1];
    const float* W1  = (const float*)d_in[2];
    const float* b1  = (const float*)d_in[3];
    const float* W2  = (const float*)d_in[4];
    const float* b2  = (const float*)d_in[5];
    const float* W3  = (const float*)d_in[6];
    const float* b3  = (const float*)d_in[7];
    const float* g1  = (const float*)d_in[8];
    const float* be1 = (const float*)d_in[9];
    const float* g2  = (const float*)d_in[10];
    const float* be2 = (const float*)d_in[11];
    const float* g3  = (const float*)d_in[12];
    const float* be3 = (const float*)d_in[13];
    const float* Wp  = (const float*)d_in[14];
    const float* bp  = (const float*)d_in[15];
    float* out = (float*)d_out;

    const int E = in_sizes[1] / 2;
    const int* src = ei;
    const int* dst = ei + E;

    char* ws = (char*)d_ws;
    size_t off = 0;
    auto alloc = [&](size_t bytes) -> void* {
        void* p = ws + off;
        off = (off + bytes + 255) & ~(size_t)255;
        return p;
    };
    u16*   bufA = (u16*)alloc((size_t)N_NODES * 512 * 2);
    u16*   bufB = (u16*)alloc((size_t)N_NODES * 512 * 2);
    u8*    buf8 = (u8*)alloc((size_t)N_NODES * 512);
    u8*    x8   = (u8*)alloc((size_t)N_NODES * 256);
    u16*   w1b  = (u16*)alloc(512 * 256 * 2);
    u16*   w2b  = (u16*)alloc(512 * 512 * 2);
    u16*   w3b  = (u16*)alloc(256 * 512 * 2);
    int*   cs   = (int*)alloc((size_t)E * 4);
    int*   rp   = (int*)alloc((size_t)(N_NODES + 1) * 4);
    int*   cnt  = (int*)alloc((size_t)N_NODES * 4 * 2);   // cnt | cur (one memset)
    int*   cur  = cnt + N_NODES;
    int*   bsum = (int*)alloc(256 * 4);
    float* part = (float*)alloc((size_t)2000 * 1024 * 4);
    float* zz   = (float*)alloc((3 * 1024 + 16 * 256) * 4); // sums x3 | gp (one memset)
    float* sums1 = zz, *sums2 = zz + 1024, *sums3 = zz + 2048;
    float* gp   = zz + 3072;
    float* ss   = (float*)alloc(1024 * 4);

    // CSR build (parallel 3-phase scan)
    hipMemsetAsync(cnt, 0, (size_t)N_NODES * 4 * 2, stream);
    hipMemsetAsync(zz, 0, (3 * 1024 + 16 * 256) * 4, stream);
    const int eb = (E + 255) / 256;
    const int nb = N_NODES / 256;   // 125
    k_count<<<eb, 256, 0, stream>>>(dst, cnt, E);
    k_scan_blk<<<nb, 256, 0, stream>>>(cnt, rp, bsum);
    k_scan_top<<<1, 128, 0, stream>>>(bsum, nb);
    k_scan_add<<<nb, 256, 0, stream>>>(rp, bsum, N_NODES, E);
    k_place<<<eb, 256, 0, stream>>>(src, dst, rp, cur, cs, E);

    // conversions: x -> fp8 gather table; weights -> bf16 (fused)
    k_cvt8<<<N_NODES * 256 / 4 / 256, 256, 0, stream>>>(x, (u32*)x8);
    k_cvtw<<<512, 256, 0, stream>>>(W1, W2, W3, w1b, w2b, w3b);

    const int PB = N_NODES / 16;    // 2000 stage-A blocks

    // ---- layer 1 (linearity): s = x + sum_src x (fp8 gather); h1 = relu(s@W1' + (deg+1)*b1) ----
    k_agg256_f8<false><<<N_NODES / 4, 256, 0, stream>>>(x8, rp, cs, bufA);
    k_gemm_mfma<true, true, false><<<dim3(250, 4), 256, 0, stream>>>(bufA, w1b, b1, rp, bufB, 256, 512);
    k_bn_part<512><<<PB, 256, 0, stream>>>(bufB, part);
    k_bn_red<512, 2000, 8><<<32, 256, 0, stream>>>(part, sums1);
    k_bn_finalize<<<1, 512, 0, stream>>>(sums1, g1, be1, ss, 512);
    k_bn_apply<<<N_NODES * 512 / 8 / 256, 256, 0, stream>>>(bufB, ss, 512);

    // ---- layer 2: GEMM (bf16 in, fp8 out) then 512-wide fp8 gather + relu ----
    k_gemm_mfma<false, false, true><<<dim3(250, 4), 256, 0, stream>>>(bufB, w2b, b2, rp, buf8, 512, 512);
    k_agg512_f8<true><<<N_NODES / 4, 256, 0, stream>>>(buf8, rp, cs, bufA);
    k_bn_part<512><<<PB, 256, 0, stream>>>(bufA, part);
    k_bn_red<512, 2000, 8><<<32, 256, 0, stream>>>(part, sums2);
    k_bn_finalize<<<1, 512, 0, stream>>>(sums2, g2, be2, ss, 512);
    k_bn_apply<<<N_NODES * 512 / 8 / 256, 256, 0, stream>>>(bufA, ss, 512);

    // ---- layer 3: GEMM (512->256, fp8 out) then 256-wide fp8 gather + relu ----
    k_gemm_mfma<false, false, true><<<dim3(250, 2), 256, 0, stream>>>(bufA, w3b, b3, rp, buf8, 512, 256);
    k_agg256_f8<true><<<N_NODES / 4, 256, 0, stream>>>(buf8, rp, cs, bufB);
    k_bn_part<256><<<PB, 256, 0, stream>>>(bufB, part);
    k_bn_red<256, 2000, 8><<<16, 256, 0, stream>>>(part, sums3);
    k_bn_finalize<<<1, 512, 0, stream>>>(sums3, g3, be3, ss, 256);
    k_bn_apply<<<N_NODES * 256 / 8 / 256, 256, 0, stream>>>(bufB, ss, 256);

    // ---- pool + head ----
    k_pool<<<dim3(16, 25), 256, 0, stream>>>(bufB, gp);
    k_final<<<1, 64, 0, stream>>>(gp, Wp, bp, out);
}

// Round 10
// 417.589 us; speedup vs baseline: 2.1845x; 1.0521x over previous
//
#include <hip/hip_runtime.h>

#define N_NODES 32000
typedef unsigned short u16;
typedef unsigned int u32;
typedef unsigned char u8;
typedef __attribute__((ext_vector_type(8))) short bf16x8;
typedef __attribute__((ext_vector_type(4))) float f32x4;
typedef __attribute__((ext_vector_type(2))) float f32x2;

__device__ __forceinline__ float leakyf(float v) { return v >= 0.f ? v : 0.1f * v; }
__device__ __forceinline__ u16 f2bf(float f) {
    u32 u = __float_as_uint(f);
    return (u16)((u + 0x7FFFu + ((u >> 16) & 1u)) >> 16);
}
__device__ __forceinline__ float bf2f(u16 h) { return __uint_as_float(((u32)h) << 16); }
__device__ __forceinline__ float bf_lo(u32 u) { return __uint_as_float(u << 16); }
__device__ __forceinline__ float bf_hi(u32 u) { return __uint_as_float(u & 0xFFFF0000u); }
__device__ __forceinline__ u32 pack2(float a, float b) { return (u32)f2bf(a) | ((u32)f2bf(b) << 16); }

// fp8 e4m3 (OCP on gfx950) decode: 4 floats from one u32
__device__ __forceinline__ void dec4(float* acc, u32 w) {
    f32x2 lo = __builtin_amdgcn_cvt_pk_f32_fp8(w, false);
    f32x2 hi = __builtin_amdgcn_cvt_pk_f32_fp8(w, true);
    acc[0] += lo[0]; acc[1] += lo[1]; acc[2] += hi[0]; acc[3] += hi[1];
}
__device__ __forceinline__ void dec16(float* acc, uint4 v) {
    dec4(acc + 0, v.x); dec4(acc + 4, v.y); dec4(acc + 8, v.z); dec4(acc + 12, v.w);
}
__device__ __forceinline__ u8 f2fp8(float v) {
    return (u8)__builtin_amdgcn_cvt_pk_fp8_f32(v, v, 0, false);
}

__device__ __forceinline__ void gload16(const u16* g, u16* l) {
    __builtin_amdgcn_global_load_lds((const __attribute__((address_space(1))) void*)g,
                                     (__attribute__((address_space(3))) void*)l, 16, 0, 0);
}

// ---------------- CSR build ----------------
__global__ __launch_bounds__(256) void k_count(const int* __restrict__ dst, int* __restrict__ cnt, int E)
{
    int e = blockIdx.x * 256 + threadIdx.x;
    if (e < E) atomicAdd(&cnt[dst[e]], 1);
}

__global__ __launch_bounds__(256) void k_scan_blk(const int* __restrict__ cnt, int* __restrict__ rp,
                                                  int* __restrict__ bsum)
{
    __shared__ int sh[256];
    const int b = blockIdx.x, t = threadIdx.x;
    int v = cnt[b * 256 + t];
    sh[t] = v;
    __syncthreads();
    for (int off = 1; off < 256; off <<= 1) {
        int u = (t >= off) ? sh[t - off] : 0;
        __syncthreads();
        sh[t] += u;
        __syncthreads();
    }
    rp[b * 256 + t] = sh[t] - v;
    if (t == 255) bsum[b] = sh[255];
}

// fused: add sum(bsum[0..b)) to this block's rp entries; set rp[n]=E
__global__ __launch_bounds__(256) void k_scan_add(int* __restrict__ rp, const int* __restrict__ bsum,
                                                  int nb, int n, int E)
{
    __shared__ int sh[256];
    const int b = blockIdx.x, t = threadIdx.x;
    int v = (t < b && t < nb) ? bsum[t] : 0;
    sh[t] = v;
    __syncthreads();
    for (int off = 128; off > 0; off >>= 1) {
        if (t < off) sh[t] += sh[t + off];
        __syncthreads();
    }
    int i = b * 256 + t;
    rp[i] += sh[0];
    if (i == 0) rp[n] = E;
}

__global__ __launch_bounds__(256) void k_place(const int* __restrict__ src, const int* __restrict__ dst,
                                               const int* __restrict__ rp, int* __restrict__ cur,
                                               int* __restrict__ cs, int E)
{
    int e = blockIdx.x * 256 + threadIdx.x;
    if (e < E) {
        int d = dst[e];
        int p = rp[d] + atomicAdd(&cur[d], 1);
        cs[p] = src[e];
    }
}

// ---------------- conversions ----------------
__global__ __launch_bounds__(256) void k_cvt8(const float* __restrict__ in, u32* __restrict__ out)
{
    int i = blockIdx.x * 256 + threadIdx.x;
    float4 v = ((const float4*)in)[i];
    int p = __builtin_amdgcn_cvt_pk_fp8_f32(v.x, v.y, 0, false);
    p = __builtin_amdgcn_cvt_pk_fp8_f32(v.z, v.w, p, true);
    out[i] = (u32)p;
}

// fused: all 3 weight matrices -> bf16 in one launch
__global__ __launch_bounds__(256) void k_cvtw(const float* __restrict__ W1, const float* __restrict__ W2,
                                              const float* __restrict__ W3, u16* __restrict__ o1,
                                              u16* __restrict__ o2, u16* __restrict__ o3)
{
    int b = blockIdx.x;
    const float* in; u16* out; int i;
    if (b < 128)      { in = W1; out = o1; i = b * 256 + threadIdx.x; }
    else if (b < 384) { in = W2; out = o2; i = (b - 128) * 256 + threadIdx.x; }
    else              { in = W3; out = o3; i = (b - 384) * 256 + threadIdx.x; }
    float4 v = ((const float4*)in)[i];
    ushort4 o;
    o.x = f2bf(v.x); o.y = f2bf(v.y); o.z = f2bf(v.z); o.w = f2bf(v.w);
    ((ushort4*)out)[i] = o;
}

// ---------------- bf16 MFMA GEMM, 2-phase double-buffered ----------------
template <bool RELU, bool DEGB, bool F8OUT>
__global__ __launch_bounds__(256) void k_gemm_mfma(const u16* __restrict__ A, const u16* __restrict__ W,
                                                   const float* __restrict__ bias, const int* __restrict__ rp,
                                                   void* __restrict__ Cv, int K, int OD)
{
    __shared__ u16 As[2][128 * 32];
    __shared__ u16 Bs[2][128 * 32];
    const int t = threadIdx.x;
    const int lane = t & 63;
    const int w = t >> 6;
    const int wr = w >> 1, wc = w & 1;
    const int bm = blockIdx.x * 128;
    const int bn = blockIdx.y * 128;

    const int c0 = w * 64 + lane;
    const int r0 = c0 >> 2, kc0 = (c0 & 3) * 8;
    const int c1 = c0 + 256;
    const int r1 = c1 >> 2, kc1 = (c1 & 3) * 8;
    const u16* gA0 = A + (size_t)(bm + r0) * K + kc0;
    const u16* gA1 = A + (size_t)(bm + r1) * K + kc1;
    const u16* gB0 = W + (size_t)(bn + r0) * K + kc0;
    const u16* gB1 = W + (size_t)(bn + r1) * K + kc1;

    f32x4 acc[4][4];
#pragma unroll
    for (int i = 0; i < 4; ++i)
#pragma unroll
        for (int j = 0; j < 4; ++j)
            acc[i][j] = (f32x4){0.f, 0.f, 0.f, 0.f};

    const int fr = lane & 15;
    const int ko = (lane >> 4) * 8;

    auto STAGE = [&](int b, int k0) {
        gload16(gA0 + k0, &As[b][0] + w * 512);
        gload16(gA1 + k0, &As[b][0] + 2048 + w * 512);
        gload16(gB0 + k0, &Bs[b][0] + w * 512);
        gload16(gB1 + k0, &Bs[b][0] + 2048 + w * 512);
    };

    STAGE(0, 0);
    asm volatile("s_waitcnt vmcnt(0)" ::: "memory");
    __syncthreads();

    int cur = 0;
    for (int k0 = 0; k0 < K; k0 += 32) {
        if (k0 + 32 < K) STAGE(cur ^ 1, k0 + 32);   // prefetch next tile
        bf16x8 af[4], bfv[4];
#pragma unroll
        for (int i = 0; i < 4; ++i)
            af[i] = *(const bf16x8*)&As[cur][(wr * 64 + i * 16 + fr) * 32 + ko];
#pragma unroll
        for (int j = 0; j < 4; ++j)
            bfv[j] = *(const bf16x8*)&Bs[cur][(wc * 64 + j * 16 + fr) * 32 + ko];
#pragma unroll
        for (int i = 0; i < 4; ++i)
#pragma unroll
            for (int j = 0; j < 4; ++j)
                acc[i][j] = __builtin_amdgcn_mfma_f32_16x16x32_bf16(af[i], bfv[j], acc[i][j], 0, 0, 0);
        asm volatile("s_waitcnt vmcnt(0)" ::: "memory");
        __syncthreads();
        cur ^= 1;
    }

    u16* C16 = (u16*)Cv;
    u8*  C8  = (u8*)Cv;
    const int qr = (lane >> 4) * 4;
    float bcol[4];
#pragma unroll
    for (int j = 0; j < 4; ++j) bcol[j] = bias[bn + wc * 64 + j * 16 + fr];
#pragma unroll
    for (int i = 0; i < 4; ++i) {
#pragma unroll
        for (int r = 0; r < 4; ++r) {
            int row = bm + wr * 64 + i * 16 + qr + r;
            float bm_ = 1.f;
            if (DEGB) bm_ = (float)(rp[row + 1] - rp[row]) + 1.f;
#pragma unroll
            for (int j = 0; j < 4; ++j) {
                int col = bn + wc * 64 + j * 16 + fr;
                float o = acc[i][j][r] + bm_ * bcol[j];
                if (RELU) o = fmaxf(o, 0.f);
                if (F8OUT) C8[(size_t)row * OD + col] = f2fp8(o);
                else       C16[(size_t)row * OD + col] = f2bf(o);
            }
        }
    }
}

// ---------------- fp8 gather+self(+relu), D=256 ----------------
template <bool RELU>
__global__ __launch_bounds__(256) void k_agg256_f8(const u8* __restrict__ h8, const int* __restrict__ rp,
                                                   const int* __restrict__ cs, u16* __restrict__ out)
{
    const int lane = threadIdx.x & 63;
    const int n = blockIdx.x * 4 + (threadIdx.x >> 6);
    const int g = lane >> 4;
    const int c = lane & 15;
    const uint4* hb = (const uint4*)h8 + c;

    float acc[16];
#pragma unroll
    for (int i = 0; i < 16; ++i) acc[i] = 0.f;
    if (g == 0) dec16(acc, hb[(size_t)n * 16]);

    const int beg = rp[n], end = rp[n + 1];
    int e = beg;
    for (; e + 16 <= end; e += 16) {
        uint4 v0 = hb[(size_t)cs[e + g] * 16];
        uint4 v1 = hb[(size_t)cs[e + 4 + g] * 16];
        uint4 v2 = hb[(size_t)cs[e + 8 + g] * 16];
        uint4 v3 = hb[(size_t)cs[e + 12 + g] * 16];
        dec16(acc, v0); dec16(acc, v1); dec16(acc, v2); dec16(acc, v3);
    }
    for (; e + 4 <= end; e += 4) {
        uint4 v = hb[(size_t)cs[e + g] * 16];
        dec16(acc, v);
    }
    if (e + g < end) {
        uint4 v = hb[(size_t)cs[e + g] * 16];
        dec16(acc, v);
    }
#pragma unroll
    for (int i = 0; i < 16; ++i) acc[i] += __shfl_xor(acc[i], 16);
#pragma unroll
    for (int i = 0; i < 16; ++i) acc[i] += __shfl_xor(acc[i], 32);
    if (g == 0) {
        if (RELU) {
#pragma unroll
            for (int i = 0; i < 16; ++i) acc[i] = fmaxf(acc[i], 0.f);
        }
        uint4 o0, o1;
        o0.x = pack2(acc[0], acc[1]);  o0.y = pack2(acc[2], acc[3]);
        o0.z = pack2(acc[4], acc[5]);  o0.w = pack2(acc[6], acc[7]);
        o1.x = pack2(acc[8], acc[9]);  o1.y = pack2(acc[10], acc[11]);
        o1.z = pack2(acc[12], acc[13]); o1.w = pack2(acc[14], acc[15]);
        uint4* op = (uint4*)((u32*)out + (size_t)n * 128 + c * 8);
        op[0] = o0; op[1] = o1;
    }
}

// ---------------- fp8 gather+self(+relu), D=512: half-wave rows, 4 loads in flight ----------------
template <bool RELU>
__global__ __launch_bounds__(256) void k_agg512_f8(const u8* __restrict__ h8, const int* __restrict__ rp,
                                                   const int* __restrict__ cs, u16* __restrict__ out)
{
    const int lane = threadIdx.x & 63;
    const int n = blockIdx.x * 4 + (threadIdx.x >> 6);
    const int g = lane >> 5;
    const int c = lane & 31;
    const uint4* hb = (const uint4*)h8 + c;

    float acc[16];
#pragma unroll
    for (int i = 0; i < 16; ++i) acc[i] = 0.f;
    if (g == 0) dec16(acc, hb[(size_t)n * 32]);

    const int beg = rp[n], end = rp[n + 1];
    int e = beg;
    for (; e + 8 <= end; e += 8) {
        uint4 v0 = hb[(size_t)cs[e + g] * 32];
        uint4 v1 = hb[(size_t)cs[e + 2 + g] * 32];
        uint4 v2 = hb[(size_t)cs[e + 4 + g] * 32];
        uint4 v3 = hb[(size_t)cs[e + 6 + g] * 32];
        dec16(acc, v0); dec16(acc, v1); dec16(acc, v2); dec16(acc, v3);
    }
    for (; e + 2 <= end; e += 2) {
        uint4 v = hb[(size_t)cs[e + g] * 32];
        dec16(acc, v);
    }
    if (e + g < end) {
        uint4 v = hb[(size_t)cs[e + g] * 32];
        dec16(acc, v);
    }
#pragma unroll
    for (int i = 0; i < 16; ++i) acc[i] += __shfl_xor(acc[i], 32);
    if (g == 0) {
        if (RELU) {
#pragma unroll
            for (int i = 0; i < 16; ++i) acc[i] = fmaxf(acc[i], 0.f);
        }
        uint4 o0, o1;
        o0.x = pack2(acc[0], acc[1]);  o0.y = pack2(acc[2], acc[3]);
        o0.z = pack2(acc[4], acc[5]);  o0.w = pack2(acc[6], acc[7]);
        o1.x = pack2(acc[8], acc[9]);  o1.y = pack2(acc[10], acc[11]);
        o1.z = pack2(acc[12], acc[13]); o1.w = pack2(acc[14], acc[15]);
        uint4* op = (uint4*)((u32*)out + (size_t)n * 256 + c * 8);
        op[0] = o0; op[1] = o1;
    }
}

// ---------------- BN stats, stage A: per-block partials, NO atomics ----------------
template <int D>
__global__ __launch_bounds__(256) void k_bn_part(const u16* __restrict__ h, float* __restrict__ partial)
{
    constexpr int SLOT = D / 8;
    constexpr int NS = 256 / SLOT;
    constexpr int ROWS = 16;
    const int t = threadIdx.x;
    const int s = t % SLOT, j = t / SLOT;
    const int r0 = blockIdx.x * ROWS;
    float a[8] = {}, q[8] = {};
#pragma unroll
    for (int rr = 0; rr < ROWS / NS; ++rr) {
        int r = j + rr * NS;
        uint4 v = *((const uint4*)(h + (size_t)(r0 + r) * D) + s);
        u32 wv[4] = {v.x, v.y, v.z, v.w};
#pragma unroll
        for (int k = 0; k < 4; ++k) {
            float lo = bf_lo(wv[k]), hi = bf_hi(wv[k]);
            a[2 * k]     += lo; q[2 * k]     = fmaf(lo, lo, q[2 * k]);
            a[2 * k + 1] += hi; q[2 * k + 1] = fmaf(hi, hi, q[2 * k + 1]);
        }
    }
    __shared__ float red[16][256];
#pragma unroll
    for (int i = 0; i < 8; ++i) { red[i][t] = a[i]; red[8 + i][t] = q[i]; }
    __syncthreads();
    if (j == 0) {
        for (int k = 1; k < NS; ++k) {
            int o = k * SLOT + s;
#pragma unroll
            for (int i = 0; i < 8; ++i) { a[i] += red[i][o]; q[i] += red[8 + i][o]; }
        }
        float* pb = partial + (size_t)blockIdx.x * (2 * D);
        float4* p0 = (float4*)(pb + 8 * s);
        p0[0] = make_float4(a[0], a[1], a[2], a[3]);
        p0[1] = make_float4(a[4], a[5], a[6], a[7]);
        float4* p1 = (float4*)(pb + D + 8 * s);
        p1[0] = make_float4(q[0], q[1], q[2], q[3]);
        p1[1] = make_float4(q[4], q[5], q[6], q[7]);
    }
}

// ---------------- BN stats, stage B: reduce partials ----------------
template <int D, int P, int SEG>
__global__ __launch_bounds__(256) void k_bn_red(const float* __restrict__ partial, float* __restrict__ sums)
{
    const int g = blockIdx.x * 256 + threadIdx.x;
    const int col = g & (2 * D - 1);
    const int seg = g / (2 * D);
    constexpr int CHUNK = P / SEG;
    const float* p = partial + (size_t)seg * CHUNK * (2 * D) + col;
    float acc = 0.f;
#pragma unroll 4
    for (int i = 0; i < CHUNK; ++i) acc += p[(size_t)i * (2 * D)];
    atomicAdd(&sums[col], acc);
}

// ---------------- BN apply with inline finalize (mu/var/rsqrt from sums) ----------------
template <int D>
__global__ __launch_bounds__(256) void k_bn_apply(u16* __restrict__ h, const float* __restrict__ sums,
                                                  const float* __restrict__ gam, const float* __restrict__ bet)
{
    int i = blockIdx.x * 256 + threadIdx.x;
    int c = (i * 8) & (D - 1);
    const float invN = 1.f / (float)N_NODES;
    float sc[8], sh[8];
#pragma unroll
    for (int k = 0; k < 8; ++k) {
        float mu  = sums[c + k] * invN;
        float var = sums[D + c + k] * invN - mu * mu;
        float rs  = rsqrtf(var + 1e-5f);
        sc[k] = gam[c + k] * rs;
        sh[k] = bet[c + k] - mu * sc[k];
    }
    uint4 v = ((uint4*)h)[i];
    u32 vv[4] = {v.x, v.y, v.z, v.w};
    u32 r[4];
#pragma unroll
    for (int k = 0; k < 4; ++k) {
        float a = leakyf(fmaf(bf_lo(vv[k]), sc[2 * k], sh[2 * k]));
        float b = leakyf(fmaf(bf_hi(vv[k]), sc[2 * k + 1], sh[2 * k + 1]));
        r[k] = pack2(a, b);
    }
    ((uint4*)h)[i] = make_uint4(r[0], r[1], r[2], r[3]);
}

// ---------------- pool with fused BN3+leaky (layer-3 apply eliminated) ----------------
__global__ __launch_bounds__(256) void k_pool_bn(const u16* __restrict__ h, const float* __restrict__ sums,
                                                 const float* __restrict__ gam, const float* __restrict__ bet,
                                                 float* __restrict__ gp)
{
    int b = blockIdx.x, ch = blockIdx.y, t = threadIdx.x;
    int s = t & 63, j = t >> 6;          // s: uint2 slot (4 cols), j: row substream
    const float invN = 1.f / (float)N_NODES;
    float sc[4], sh[4];
#pragma unroll
    for (int k = 0; k < 4; ++k) {
        int c = 4 * s + k;
        float mu  = sums[c] * invN;
        float var = sums[256 + c] * invN - mu * mu;
        float rs  = rsqrtf(var + 1e-5f);
        sc[k] = gam[c] * rs;
        sh[k] = bet[c] - mu * sc[k];
    }
    int r0 = b * 2000 + ch * 80;
    float a0 = 0.f, a1 = 0.f, a2 = 0.f, a3 = 0.f;
    for (int r = j; r < 80; r += 4) {
        uint2 v = *((const uint2*)(h + (size_t)(r0 + r) * 256) + s);
        a0 += leakyf(fmaf(bf_lo(v.x), sc[0], sh[0]));
        a1 += leakyf(fmaf(bf_hi(v.x), sc[1], sh[1]));
        a2 += leakyf(fmaf(bf_lo(v.y), sc[2], sh[2]));
        a3 += leakyf(fmaf(bf_hi(v.y), sc[3], sh[3]));
    }
    atomicAdd(&gp[b * 256 + s * 4 + 0], a0);
    atomicAdd(&gp[b * 256 + s * 4 + 1], a1);
    atomicAdd(&gp[b * 256 + s * 4 + 2], a2);
    atomicAdd(&gp[b * 256 + s * 4 + 3], a3);
}

__global__ __launch_bounds__(64) void k_final(const float* __restrict__ gp, const float* __restrict__ Wp,
                                              const float* __restrict__ bp, float* __restrict__ out)
{
    __shared__ float lg[32];
    int t = threadIdx.x;
    if (t < 32) {
        int b = t >> 1, c = t & 1;
        float s = 0.f;
        for (int k = 0; k < 256; ++k) s = fmaf(gp[b * 256 + k], Wp[c * 256 + k], s);
        float o = s * (1.f / 2000.f) + bp[c];
        out[b * 2 + c] = o;
        lg[t] = o;
    }
    __syncthreads();
    if (t < 16) out[32 + t] = (lg[t * 2 + 1] > lg[t * 2]) ? 1.f : 0.f;
}

extern "C" void kernel_launch(void* const* d_in, const int* in_sizes, int n_in,
                              void* d_out, int out_size, void* d_ws, size_t ws_size,
                              hipStream_t stream)
{
    const float* x   = (const float*)d_in[0];
    const int*   ei  = (const int*)d_in[1];
    const float* W1  = (const float*)d_in[2];
    const float* b1  = (const float*)d_in[3];
    const float* W2  = (const float*)d_in[4];
    const float* b2  = (const float*)d_in[5];
    const float* W3  = (const float*)d_in[6];
    const float* b3  = (const float*)d_in[7];
    const float* g1  = (const float*)d_in[8];
    const float* be1 = (const float*)d_in[9];
    const float* g2  = (const float*)d_in[10];
    const float* be2 = (const float*)d_in[11];
    const float* g3  = (const float*)d_in[12];
    const float* be3 = (const float*)d_in[13];
    const float* Wp  = (const float*)d_in[14];
    const float* bp  = (const float*)d_in[15];
    float* out = (float*)d_out;

    const int E = in_sizes[1] / 2;
    const int* src = ei;
    const int* dst = ei + E;

    char* ws = (char*)d_ws;
    size_t off = 0;
    auto alloc = [&](size_t bytes) -> void* {
        void* p = ws + off;
        off = (off + bytes + 255) & ~(size_t)255;
        return p;
    };
    u16*   bufA = (u16*)alloc((size_t)N_NODES * 512 * 2);
    u16*   bufB = (u16*)alloc((size_t)N_NODES * 512 * 2);
    u8*    buf8 = (u8*)alloc((size_t)N_NODES * 512);
    u8*    x8   = (u8*)alloc((size_t)N_NODES * 256);
    u16*   w1b  = (u16*)alloc(512 * 256 * 2);
    u16*   w2b  = (u16*)alloc(512 * 512 * 2);
    u16*   w3b  = (u16*)alloc(256 * 512 * 2);
    int*   cs   = (int*)alloc((size_t)E * 4);
    int*   rp   = (int*)alloc((size_t)(N_NODES + 1) * 4);
    int*   cnt  = (int*)alloc((size_t)N_NODES * 4 * 2);   // cnt | cur (one memset)
    int*   cur  = cnt + N_NODES;
    int*   bsum = (int*)alloc(256 * 4);
    float* part = (float*)alloc((size_t)2000 * 1024 * 4);
    float* zz   = (float*)alloc((3 * 1024 + 16 * 256) * 4); // sums x3 | gp (one memset)
    float* sums1 = zz, *sums2 = zz + 1024, *sums3 = zz + 2048;
    float* gp   = zz + 3072;

    // CSR build
    hipMemsetAsync(cnt, 0, (size_t)N_NODES * 4 * 2, stream);
    hipMemsetAsync(zz, 0, (3 * 1024 + 16 * 256) * 4, stream);
    const int eb = (E + 255) / 256;
    const int nb = N_NODES / 256;   // 125
    k_count<<<eb, 256, 0, stream>>>(dst, cnt, E);
    k_scan_blk<<<nb, 256, 0, stream>>>(cnt, rp, bsum);
    k_scan_add<<<nb, 256, 0, stream>>>(rp, bsum, nb, N_NODES, E);
    k_place<<<eb, 256, 0, stream>>>(src, dst, rp, cur, cs, E);

    // conversions
    k_cvt8<<<N_NODES * 256 / 4 / 256, 256, 0, stream>>>(x, (u32*)x8);
    k_cvtw<<<512, 256, 0, stream>>>(W1, W2, W3, w1b, w2b, w3b);

    const int PB = N_NODES / 16;    // 2000 stage-A blocks

    // ---- layer 1 (linearity): s = x + sum_src x (fp8 gather); h1 = relu(s@W1' + (deg+1)*b1) ----
    k_agg256_f8<false><<<N_NODES / 4, 256, 0, stream>>>(x8, rp, cs, bufA);
    k_gemm_mfma<true, true, false><<<dim3(250, 4), 256, 0, stream>>>(bufA, w1b, b1, rp, bufB, 256, 512);
    k_bn_part<512><<<PB, 256, 0, stream>>>(bufB, part);
    k_bn_red<512, 2000, 8><<<32, 256, 0, stream>>>(part, sums1);
    k_bn_apply<512><<<N_NODES * 512 / 8 / 256, 256, 0, stream>>>(bufB, sums1, g1, be1);

    // ---- layer 2: GEMM (bf16 in, fp8 out) then 512-wide fp8 gather + relu ----
    k_gemm_mfma<false, false, true><<<dim3(250, 4), 256, 0, stream>>>(bufB, w2b, b2, rp, buf8, 512, 512);
    k_agg512_f8<true><<<N_NODES / 4, 256, 0, stream>>>(buf8, rp, cs, bufA);
    k_bn_part<512><<<PB, 256, 0, stream>>>(bufA, part);
    k_bn_red<512, 2000, 8><<<32, 256, 0, stream>>>(part, sums2);
    k_bn_apply<512><<<N_NODES * 512 / 8 / 256, 256, 0, stream>>>(bufA, sums2, g2, be2);

    // ---- layer 3: GEMM (512->256, fp8 out) then 256-wide fp8 gather + relu ----
    k_gemm_mfma<false, false, true><<<dim3(250, 2), 256, 0, stream>>>(bufA, w3b, b3, rp, buf8, 512, 256);
    k_agg256_f8<true><<<N_NODES / 4, 256, 0, stream>>>(buf8, rp, cs, bufB);
    k_bn_part<256><<<PB, 256, 0, stream>>>(bufB, part);
    k_bn_red<256, 2000, 8><<<16, 256, 0, stream>>>(part, sums3);

    // ---- pool (fused BN3+leaky) + head ----
    k_pool_bn<<<dim3(16, 25), 256, 0, stream>>>(bufB, sums3, g3, be3, gp);
    k_final<<<1, 64, 0, stream>>>(gp, Wp, bp, out);
}

// Round 11
// 417.551 us; speedup vs baseline: 2.1847x; 1.0001x over previous
//
#include <hip/hip_runtime.h>

#define N_NODES 32000
typedef unsigned short u16;
typedef unsigned int u32;
typedef unsigned char u8;
typedef __attribute__((ext_vector_type(8))) short bf16x8;
typedef __attribute__((ext_vector_type(4))) float f32x4;
typedef __attribute__((ext_vector_type(2))) float f32x2;

__device__ __forceinline__ float leakyf(float v) { return v >= 0.f ? v : 0.1f * v; }
__device__ __forceinline__ u16 f2bf(float f) {
    u32 u = __float_as_uint(f);
    return (u16)((u + 0x7FFFu + ((u >> 16) & 1u)) >> 16);
}
__device__ __forceinline__ float bf2f(u16 h) { return __uint_as_float(((u32)h) << 16); }
__device__ __forceinline__ float bf_lo(u32 u) { return __uint_as_float(u << 16); }
__device__ __forceinline__ float bf_hi(u32 u) { return __uint_as_float(u & 0xFFFF0000u); }
__device__ __forceinline__ u32 pack2(float a, float b) { return (u32)f2bf(a) | ((u32)f2bf(b) << 16); }

// fp8 e4m3 (OCP on gfx950) decode: 4 floats from one u32
__device__ __forceinline__ void dec4(float* acc, u32 w) {
    f32x2 lo = __builtin_amdgcn_cvt_pk_f32_fp8(w, false);
    f32x2 hi = __builtin_amdgcn_cvt_pk_f32_fp8(w, true);
    acc[0] += lo[0]; acc[1] += lo[1]; acc[2] += hi[0]; acc[3] += hi[1];
}
__device__ __forceinline__ void dec16(float* acc, uint4 v) {
    dec4(acc + 0, v.x); dec4(acc + 4, v.y); dec4(acc + 8, v.z); dec4(acc + 12, v.w);
}
__device__ __forceinline__ u8 f2fp8(float v) {
    return (u8)__builtin_amdgcn_cvt_pk_fp8_f32(v, v, 0, false);
}

__device__ __forceinline__ void gload16(const u16* g, u16* l) {
    __builtin_amdgcn_global_load_lds((const __attribute__((address_space(1))) void*)g,
                                     (__attribute__((address_space(3))) void*)l, 16, 0, 0);
}

// ---------------- CSR build ----------------
__global__ __launch_bounds__(256) void k_count(const int* __restrict__ dst, int* __restrict__ cnt, int E)
{
    int e = blockIdx.x * 256 + threadIdx.x;
    if (e < E) atomicAdd(&cnt[dst[e]], 1);
}

__global__ __launch_bounds__(256) void k_scan_blk(const int* __restrict__ cnt, int* __restrict__ rp,
                                                  int* __restrict__ bsum)
{
    __shared__ int sh[256];
    const int b = blockIdx.x, t = threadIdx.x;
    int v = cnt[b * 256 + t];
    sh[t] = v;
    __syncthreads();
    for (int off = 1; off < 256; off <<= 1) {
        int u = (t >= off) ? sh[t - off] : 0;
        __syncthreads();
        sh[t] += u;
        __syncthreads();
    }
    rp[b * 256 + t] = sh[t] - v;
    if (t == 255) bsum[b] = sh[255];
}

// fused: add sum(bsum[0..b)) to this block's rp entries; set rp[n]=E
__global__ __launch_bounds__(256) void k_scan_add(int* __restrict__ rp, const int* __restrict__ bsum,
                                                  int nb, int n, int E)
{
    __shared__ int sh[256];
    const int b = blockIdx.x, t = threadIdx.x;
    int v = (t < b && t < nb) ? bsum[t] : 0;
    sh[t] = v;
    __syncthreads();
    for (int off = 128; off > 0; off >>= 1) {
        if (t < off) sh[t] += sh[t + off];
        __syncthreads();
    }
    int i = b * 256 + t;
    rp[i] += sh[0];
    if (i == 0) rp[n] = E;
}

__global__ __launch_bounds__(256) void k_place(const int* __restrict__ src, const int* __restrict__ dst,
                                               const int* __restrict__ rp, int* __restrict__ cur,
                                               int* __restrict__ cs, int E)
{
    int e = blockIdx.x * 256 + threadIdx.x;
    if (e < E) {
        int d = dst[e];
        int p = rp[d] + atomicAdd(&cur[d], 1);
        cs[p] = src[e];
    }
}

// ---------------- conversions ----------------
__global__ __launch_bounds__(256) void k_cvt8(const float* __restrict__ in, u32* __restrict__ out)
{
    int i = blockIdx.x * 256 + threadIdx.x;
    float4 v = ((const float4*)in)[i];
    int p = __builtin_amdgcn_cvt_pk_fp8_f32(v.x, v.y, 0, false);
    p = __builtin_amdgcn_cvt_pk_fp8_f32(v.z, v.w, p, true);
    out[i] = (u32)p;
}

// fused: all 3 weight matrices -> bf16 in one launch
__global__ __launch_bounds__(256) void k_cvtw(const float* __restrict__ W1, const float* __restrict__ W2,
                                              const float* __restrict__ W3, u16* __restrict__ o1,
                                              u16* __restrict__ o2, u16* __restrict__ o3)
{
    int b = blockIdx.x;
    const float* in; u16* out; int i;
    if (b < 128)      { in = W1; out = o1; i = b * 256 + threadIdx.x; }
    else if (b < 384) { in = W2; out = o2; i = (b - 128) * 256 + threadIdx.x; }
    else              { in = W3; out = o3; i = (b - 384) * 256 + threadIdx.x; }
    float4 v = ((const float4*)in)[i];
    ushort4 o;
    o.x = f2bf(v.x); o.y = f2bf(v.y); o.z = f2bf(v.z); o.w = f2bf(v.w);
    ((ushort4*)out)[i] = o;
}

// ---------------- bf16 MFMA GEMM, 2-phase double-buffered, counted vmcnt ----------------
template <bool RELU, bool DEGB, bool F8OUT>
__global__ __launch_bounds__(256) void k_gemm_mfma(const u16* __restrict__ A, const u16* __restrict__ W,
                                                   const float* __restrict__ bias, const int* __restrict__ rp,
                                                   void* __restrict__ Cv, int K, int OD)
{
    __shared__ u16 As[2][128 * 32];
    __shared__ u16 Bs[2][128 * 32];
    const int t = threadIdx.x;
    const int lane = t & 63;
    const int w = t >> 6;
    const int wr = w >> 1, wc = w & 1;
    const int bm = blockIdx.x * 128;
    const int bn = blockIdx.y * 128;

    const int c0 = w * 64 + lane;
    const int r0 = c0 >> 2, kc0 = (c0 & 3) * 8;
    const int c1 = c0 + 256;
    const int r1 = c1 >> 2, kc1 = (c1 & 3) * 8;
    const u16* gA0 = A + (size_t)(bm + r0) * K + kc0;
    const u16* gA1 = A + (size_t)(bm + r1) * K + kc1;
    const u16* gB0 = W + (size_t)(bn + r0) * K + kc0;
    const u16* gB1 = W + (size_t)(bn + r1) * K + kc1;

    f32x4 acc[4][4];
#pragma unroll
    for (int i = 0; i < 4; ++i)
#pragma unroll
        for (int j = 0; j < 4; ++j)
            acc[i][j] = (f32x4){0.f, 0.f, 0.f, 0.f};

    const int fr = lane & 15;
    const int ko = (lane >> 4) * 8;

    auto STAGE = [&](int b, int k0) {
        gload16(gA0 + k0, &As[b][0] + w * 512);
        gload16(gA1 + k0, &As[b][0] + 2048 + w * 512);
        gload16(gB0 + k0, &Bs[b][0] + w * 512);
        gload16(gB1 + k0, &Bs[b][0] + 2048 + w * 512);
    };

    // prologue: issue buffer-0 loads; DO NOT drain — first loop iteration waits.
    STAGE(0, 0);

    int cur = 0;
    for (int k0 = 0; k0 < K; k0 += 32) {
        if (k0 + 32 < K) {
            STAGE(cur ^ 1, k0 + 32);                         // prefetch next tile (4 loads in flight)
            asm volatile("s_waitcnt vmcnt(4)" ::: "memory"); // wait ONLY for cur's 4 loads
        } else {
            asm volatile("s_waitcnt vmcnt(0)" ::: "memory"); // last tile: nothing else in flight
        }
        __syncthreads();   // all waves' cur loads landed in LDS
        bf16x8 af[4], bfv[4];
#pragma unroll
        for (int i = 0; i < 4; ++i)
            af[i] = *(const bf16x8*)&As[cur][(wr * 64 + i * 16 + fr) * 32 + ko];
#pragma unroll
        for (int j = 0; j < 4; ++j)
            bfv[j] = *(const bf16x8*)&Bs[cur][(wc * 64 + j * 16 + fr) * 32 + ko];
#pragma unroll
        for (int i = 0; i < 4; ++i)
#pragma unroll
            for (int j = 0; j < 4; ++j)
                acc[i][j] = __builtin_amdgcn_mfma_f32_16x16x32_bf16(af[i], bfv[j], acc[i][j], 0, 0, 0);
        __syncthreads();   // all waves done reading cur -> next iter may STAGE into it
        cur ^= 1;
    }

    u16* C16 = (u16*)Cv;
    u8*  C8  = (u8*)Cv;
    const int qr = (lane >> 4) * 4;
    float bcol[4];
#pragma unroll
    for (int j = 0; j < 4; ++j) bcol[j] = bias[bn + wc * 64 + j * 16 + fr];
#pragma unroll
    for (int i = 0; i < 4; ++i) {
#pragma unroll
        for (int r = 0; r < 4; ++r) {
            int row = bm + wr * 64 + i * 16 + qr + r;
            float bm_ = 1.f;
            if (DEGB) bm_ = (float)(rp[row + 1] - rp[row]) + 1.f;
#pragma unroll
            for (int j = 0; j < 4; ++j) {
                int col = bn + wc * 64 + j * 16 + fr;
                float o = acc[i][j][r] + bm_ * bcol[j];
                if (RELU) o = fmaxf(o, 0.f);
                if (F8OUT) C8[(size_t)row * OD + col] = f2fp8(o);
                else       C16[(size_t)row * OD + col] = f2bf(o);
            }
        }
    }
}

// ---------------- fp8 gather+self(+relu), D=256 ----------------
template <bool RELU>
__global__ __launch_bounds__(256) void k_agg256_f8(const u8* __restrict__ h8, const int* __restrict__ rp,
                                                   const int* __restrict__ cs, u16* __restrict__ out)
{
    const int lane = threadIdx.x & 63;
    const int n = blockIdx.x * 4 + (threadIdx.x >> 6);
    const int g = lane >> 4;
    const int c = lane & 15;
    const uint4* hb = (const uint4*)h8 + c;

    float acc[16];
#pragma unroll
    for (int i = 0; i < 16; ++i) acc[i] = 0.f;
    if (g == 0) dec16(acc, hb[(size_t)n * 16]);

    const int beg = rp[n], end = rp[n + 1];
    int e = beg;
    for (; e + 16 <= end; e += 16) {
        uint4 v0 = hb[(size_t)cs[e + g] * 16];
        uint4 v1 = hb[(size_t)cs[e + 4 + g] * 16];
        uint4 v2 = hb[(size_t)cs[e + 8 + g] * 16];
        uint4 v3 = hb[(size_t)cs[e + 12 + g] * 16];
        dec16(acc, v0); dec16(acc, v1); dec16(acc, v2); dec16(acc, v3);
    }
    for (; e + 4 <= end; e += 4) {
        uint4 v = hb[(size_t)cs[e + g] * 16];
        dec16(acc, v);
    }
    if (e + g < end) {
        uint4 v = hb[(size_t)cs[e + g] * 16];
        dec16(acc, v);
    }
#pragma unroll
    for (int i = 0; i < 16; ++i) acc[i] += __shfl_xor(acc[i], 16);
#pragma unroll
    for (int i = 0; i < 16; ++i) acc[i] += __shfl_xor(acc[i], 32);
    if (g == 0) {
        if (RELU) {
#pragma unroll
            for (int i = 0; i < 16; ++i) acc[i] = fmaxf(acc[i], 0.f);
        }
        uint4 o0, o1;
        o0.x = pack2(acc[0], acc[1]);  o0.y = pack2(acc[2], acc[3]);
        o0.z = pack2(acc[4], acc[5]);  o0.w = pack2(acc[6], acc[7]);
        o1.x = pack2(acc[8], acc[9]);  o1.y = pack2(acc[10], acc[11]);
        o1.z = pack2(acc[12], acc[13]); o1.w = pack2(acc[14], acc[15]);
        uint4* op = (uint4*)((u32*)out + (size_t)n * 128 + c * 8);
        op[0] = o0; op[1] = o1;
    }
}

// ---------------- fp8 gather+self(+relu), D=512: half-wave rows, 4 loads in flight ----------------
template <bool RELU>
__global__ __launch_bounds__(256) void k_agg512_f8(const u8* __restrict__ h8, const int* __restrict__ rp,
                                                   const int* __restrict__ cs, u16* __restrict__ out)
{
    const int lane = threadIdx.x & 63;
    const int n = blockIdx.x * 4 + (threadIdx.x >> 6);
    const int g = lane >> 5;
    const int c = lane & 31;
    const uint4* hb = (const uint4*)h8 + c;

    float acc[16];
#pragma unroll
    for (int i = 0; i < 16; ++i) acc[i] = 0.f;
    if (g == 0) dec16(acc, hb[(size_t)n * 32]);

    const int beg = rp[n], end = rp[n + 1];
    int e = beg;
    for (; e + 8 <= end; e += 8) {
        uint4 v0 = hb[(size_t)cs[e + g] * 32];
        uint4 v1 = hb[(size_t)cs[e + 2 + g] * 32];
        uint4 v2 = hb[(size_t)cs[e + 4 + g] * 32];
        uint4 v3 = hb[(size_t)cs[e + 6 + g] * 32];
        dec16(acc, v0); dec16(acc, v1); dec16(acc, v2); dec16(acc, v3);
    }
    for (; e + 2 <= end; e += 2) {
        uint4 v = hb[(size_t)cs[e + g] * 32];
        dec16(acc, v);
    }
    if (e + g < end) {
        uint4 v = hb[(size_t)cs[e + g] * 32];
        dec16(acc, v);
    }
#pragma unroll
    for (int i = 0; i < 16; ++i) acc[i] += __shfl_xor(acc[i], 32);
    if (g == 0) {
        if (RELU) {
#pragma unroll
            for (int i = 0; i < 16; ++i) acc[i] = fmaxf(acc[i], 0.f);
        }
        uint4 o0, o1;
        o0.x = pack2(acc[0], acc[1]);  o0.y = pack2(acc[2], acc[3]);
        o0.z = pack2(acc[4], acc[5]);  o0.w = pack2(acc[6], acc[7]);
        o1.x = pack2(acc[8], acc[9]);  o1.y = pack2(acc[10], acc[11]);
        o1.z = pack2(acc[12], acc[13]); o1.w = pack2(acc[14], acc[15]);
        uint4* op = (uint4*)((u32*)out + (size_t)n * 256 + c * 8);
        op[0] = o0; op[1] = o1;
    }
}

// ---------------- BN stats, stage A: per-block partials, NO atomics ----------------
template <int D>
__global__ __launch_bounds__(256) void k_bn_part(const u16* __restrict__ h, float* __restrict__ partial)
{
    constexpr int SLOT = D / 8;
    constexpr int NS = 256 / SLOT;
    constexpr int ROWS = 16;
    const int t = threadIdx.x;
    const int s = t % SLOT, j = t / SLOT;
    const int r0 = blockIdx.x * ROWS;
    float a[8] = {}, q[8] = {};
#pragma unroll
    for (int rr = 0; rr < ROWS / NS; ++rr) {
        int r = j + rr * NS;
        uint4 v = *((const uint4*)(h + (size_t)(r0 + r) * D) + s);
        u32 wv[4] = {v.x, v.y, v.z, v.w};
#pragma unroll
        for (int k = 0; k < 4; ++k) {
            float lo = bf_lo(wv[k]), hi = bf_hi(wv[k]);
            a[2 * k]     += lo; q[2 * k]     = fmaf(lo, lo, q[2 * k]);
            a[2 * k + 1] += hi; q[2 * k + 1] = fmaf(hi, hi, q[2 * k + 1]);
        }
    }
    __shared__ float red[16][256];
#pragma unroll
    for (int i = 0; i < 8; ++i) { red[i][t] = a[i]; red[8 + i][t] = q[i]; }
    __syncthreads();
    if (j == 0) {
        for (int k = 1; k < NS; ++k) {
            int o = k * SLOT + s;
#pragma unroll
            for (int i = 0; i < 8; ++i) { a[i] += red[i][o]; q[i] += red[8 + i][o]; }
        }
        float* pb = partial + (size_t)blockIdx.x * (2 * D);
        float4* p0 = (float4*)(pb + 8 * s);
        p0[0] = make_float4(a[0], a[1], a[2], a[3]);
        p0[1] = make_float4(a[4], a[5], a[6], a[7]);
        float4* p1 = (float4*)(pb + D + 8 * s);
        p1[0] = make_float4(q[0], q[1], q[2], q[3]);
        p1[1] = make_float4(q[4], q[5], q[6], q[7]);
    }
}

// ---------------- BN stats, stage B: reduce partials ----------------
template <int D, int P, int SEG>
__global__ __launch_bounds__(256) void k_bn_red(const float* __restrict__ partial, float* __restrict__ sums)
{
    const int g = blockIdx.x * 256 + threadIdx.x;
    const int col = g & (2 * D - 1);
    const int seg = g / (2 * D);
    constexpr int CHUNK = P / SEG;
    const float* p = partial + (size_t)seg * CHUNK * (2 * D) + col;
    float acc = 0.f;
#pragma unroll 4
    for (int i = 0; i < CHUNK; ++i) acc += p[(size_t)i * (2 * D)];
    atomicAdd(&sums[col], acc);
}

// ---------------- BN apply with inline finalize ----------------
template <int D>
__global__ __launch_bounds__(256) void k_bn_apply(u16* __restrict__ h, const float* __restrict__ sums,
                                                  const float* __restrict__ gam, const float* __restrict__ bet)
{
    int i = blockIdx.x * 256 + threadIdx.x;
    int c = (i * 8) & (D - 1);
    const float invN = 1.f / (float)N_NODES;
    float sc[8], sh[8];
#pragma unroll
    for (int k = 0; k < 8; ++k) {
        float mu  = sums[c + k] * invN;
        float var = sums[D + c + k] * invN - mu * mu;
        float rs  = rsqrtf(var + 1e-5f);
        sc[k] = gam[c + k] * rs;
        sh[k] = bet[c + k] - mu * sc[k];
    }
    uint4 v = ((uint4*)h)[i];
    u32 vv[4] = {v.x, v.y, v.z, v.w};
    u32 r[4];
#pragma unroll
    for (int k = 0; k < 4; ++k) {
        float a = leakyf(fmaf(bf_lo(vv[k]), sc[2 * k], sh[2 * k]));
        float b = leakyf(fmaf(bf_hi(vv[k]), sc[2 * k + 1], sh[2 * k + 1]));
        r[k] = pack2(a, b);
    }
    ((uint4*)h)[i] = make_uint4(r[0], r[1], r[2], r[3]);
}

// ---------------- pool with fused BN3+leaky ----------------
__global__ __launch_bounds__(256) void k_pool_bn(const u16* __restrict__ h, const float* __restrict__ sums,
                                                 const float* __restrict__ gam, const float* __restrict__ bet,
                                                 float* __restrict__ gp)
{
    int b = blockIdx.x, ch = blockIdx.y, t = threadIdx.x;
    int s = t & 63, j = t >> 6;
    const float invN = 1.f / (float)N_NODES;
    float sc[4], sh[4];
#pragma unroll
    for (int k = 0; k < 4; ++k) {
        int c = 4 * s + k;
        float mu  = sums[c] * invN;
        float var = sums[256 + c] * invN - mu * mu;
        float rs  = rsqrtf(var + 1e-5f);
        sc[k] = gam[c] * rs;
        sh[k] = bet[c] - mu * sc[k];
    }
    int r0 = b * 2000 + ch * 80;
    float a0 = 0.f, a1 = 0.f, a2 = 0.f, a3 = 0.f;
    for (int r = j; r < 80; r += 4) {
        uint2 v = *((const uint2*)(h + (size_t)(r0 + r) * 256) + s);
        a0 += leakyf(fmaf(bf_lo(v.x), sc[0], sh[0]));
        a1 += leakyf(fmaf(bf_hi(v.x), sc[1], sh[1]));
        a2 += leakyf(fmaf(bf_lo(v.y), sc[2], sh[2]));
        a3 += leakyf(fmaf(bf_hi(v.y), sc[3], sh[3]));
    }
    atomicAdd(&gp[b * 256 + s * 4 + 0], a0);
    atomicAdd(&gp[b * 256 + s * 4 + 1], a1);
    atomicAdd(&gp[b * 256 + s * 4 + 2], a2);
    atomicAdd(&gp[b * 256 + s * 4 + 3], a3);
}

__global__ __launch_bounds__(64) void k_final(const float* __restrict__ gp, const float* __restrict__ Wp,
                                              const float* __restrict__ bp, float* __restrict__ out)
{
    __shared__ float lg[32];
    int t = threadIdx.x;
    if (t < 32) {
        int b = t >> 1, c = t & 1;
        float s = 0.f;
        for (int k = 0; k < 256; ++k) s = fmaf(gp[b * 256 + k], Wp[c * 256 + k], s);
        float o = s * (1.f / 2000.f) + bp[c];
        out[b * 2 + c] = o;
        lg[t] = o;
    }
    __syncthreads();
    if (t < 16) out[32 + t] = (lg[t * 2 + 1] > lg[t * 2]) ? 1.f : 0.f;
}

extern "C" void kernel_launch(void* const* d_in, const int* in_sizes, int n_in,
                              void* d_out, int out_size, void* d_ws, size_t ws_size,
                              hipStream_t stream)
{
    const float* x   = (const float*)d_in[0];
    const int*   ei  = (const int*)d_in[1];
    const float* W1  = (const float*)d_in[2];
    const float* b1  = (const float*)d_in[3];
    const float* W2  = (const float*)d_in[4];
    const float* b2  = (const float*)d_in[5];
    const float* W3  = (const float*)d_in[6];
    const float* b3  = (const float*)d_in[7];
    const float* g1  = (const float*)d_in[8];
    const float* be1 = (const float*)d_in[9];
    const float* g2  = (const float*)d_in[10];
    const float* be2 = (const float*)d_in[11];
    const float* g3  = (const float*)d_in[12];
    const float* be3 = (const float*)d_in[13];
    const float* Wp  = (const float*)d_in[14];
    const float* bp  = (const float*)d_in[15];
    float* out = (float*)d_out;

    const int E = in_sizes[1] / 2;
    const int* src = ei;
    const int* dst = ei + E;

    char* ws = (char*)d_ws;
    size_t off = 0;
    auto alloc = [&](size_t bytes) -> void* {
        void* p = ws + off;
        off = (off + bytes + 255) & ~(size_t)255;
        return p;
    };
    u16*   bufA = (u16*)alloc((size_t)N_NODES * 512 * 2);
    u16*   bufB = (u16*)alloc((size_t)N_NODES * 512 * 2);
    u8*    buf8 = (u8*)alloc((size_t)N_NODES * 512);
    u8*    x8   = (u8*)alloc((size_t)N_NODES * 256);
    u16*   w1b  = (u16*)alloc(512 * 256 * 2);
    u16*   w2b  = (u16*)alloc(512 * 512 * 2);
    u16*   w3b  = (u16*)alloc(256 * 512 * 2);
    int*   cs   = (int*)alloc((size_t)E * 4);
    int*   rp   = (int*)alloc((size_t)(N_NODES + 1) * 4);
    int*   cnt  = (int*)alloc((size_t)N_NODES * 4 * 2);   // cnt | cur (one memset)
    int*   cur  = cnt + N_NODES;
    int*   bsum = (int*)alloc(256 * 4);
    float* part = (float*)alloc((size_t)2000 * 1024 * 4);
    float* zz   = (float*)alloc((3 * 1024 + 16 * 256) * 4); // sums x3 | gp (one memset)
    float* sums1 = zz, *sums2 = zz + 1024, *sums3 = zz + 2048;
    float* gp   = zz + 3072;

    // CSR build
    hipMemsetAsync(cnt, 0, (size_t)N_NODES * 4 * 2, stream);
    hipMemsetAsync(zz, 0, (3 * 1024 + 16 * 256) * 4, stream);
    const int eb = (E + 255) / 256;
    const int nb = N_NODES / 256;   // 125
    k_count<<<eb, 256, 0, stream>>>(dst, cnt, E);
    k_scan_blk<<<nb, 256, 0, stream>>>(cnt, rp, bsum);
    k_scan_add<<<nb, 256, 0, stream>>>(rp, bsum, nb, N_NODES, E);
    k_place<<<eb, 256, 0, stream>>>(src, dst, rp, cur, cs, E);

    // conversions
    k_cvt8<<<N_NODES * 256 / 4 / 256, 256, 0, stream>>>(x, (u32*)x8);
    k_cvtw<<<512, 256, 0, stream>>>(W1, W2, W3, w1b, w2b, w3b);

    const int PB = N_NODES / 16;    // 2000 stage-A blocks

    // ---- layer 1 (linearity): s = x + sum_src x (fp8 gather); h1 = relu(s@W1' + (deg+1)*b1) ----
    k_agg256_f8<false><<<N_NODES / 4, 256, 0, stream>>>(x8, rp, cs, bufA);
    k_gemm_mfma<true, true, false><<<dim3(250, 4), 256, 0, stream>>>(bufA, w1b, b1, rp, bufB, 256, 512);
    k_bn_part<512><<<PB, 256, 0, stream>>>(bufB, part);
    k_bn_red<512, 2000, 8><<<32, 256, 0, stream>>>(part, sums1);
    k_bn_apply<512><<<N_NODES * 512 / 8 / 256, 256, 0, stream>>>(bufB, sums1, g1, be1);

    // ---- layer 2: GEMM (bf16 in, fp8 out) then 512-wide fp8 gather + relu ----
    k_gemm_mfma<false, false, true><<<dim3(250, 4), 256, 0, stream>>>(bufB, w2b, b2, rp, buf8, 512, 512);
    k_agg512_f8<true><<<N_NODES / 4, 256, 0, stream>>>(buf8, rp, cs, bufA);
    k_bn_part<512><<<PB, 256, 0, stream>>>(bufA, part);
    k_bn_red<512, 2000, 8><<<32, 256, 0, stream>>>(part, sums2);
    k_bn_apply<512><<<N_NODES * 512 / 8 / 256, 256, 0, stream>>>(bufA, sums2, g2, be2);

    // ---- layer 3: GEMM (512->256, fp8 out) then 256-wide fp8 gather + relu ----
    k_gemm_mfma<false, false, true><<<dim3(250, 2), 256, 0, stream>>>(bufA, w3b, b3, rp, buf8, 512, 256);
    k_agg256_f8<true><<<N_NODES / 4, 256, 0, stream>>>(buf8, rp, cs, bufB);
    k_bn_part<256><<<PB, 256, 0, stream>>>(bufB, part);
    k_bn_red<256, 2000, 8><<<16, 256, 0, stream>>>(part, sums3);

    // ---- pool (fused BN3+leaky) + head ----
    k_pool_bn<<<dim3(16, 25), 256, 0, stream>>>(bufB, sums3, g3, be3, gp);
    k_final<<<1, 64, 0, stream>>>(gp, Wp, bp, out);
}

// Round 12
// 412.433 us; speedup vs baseline: 2.2118x; 1.0124x over previous
//
#include <hip/hip_runtime.h>

#define N_NODES 32000
typedef unsigned short u16;
typedef unsigned int u32;
typedef unsigned char u8;
typedef __attribute__((ext_vector_type(8))) short bf16x8;
typedef __attribute__((ext_vector_type(4))) float f32x4;
typedef __attribute__((ext_vector_type(2))) float f32x2;

__device__ __forceinline__ float leakyf(float v) { return v >= 0.f ? v : 0.1f * v; }
__device__ __forceinline__ u16 f2bf(float f) {
    u32 u = __float_as_uint(f);
    return (u16)((u + 0x7FFFu + ((u >> 16) & 1u)) >> 16);
}
__device__ __forceinline__ float bf_lo(u32 u) { return __uint_as_float(u << 16); }
__device__ __forceinline__ float bf_hi(u32 u) { return __uint_as_float(u & 0xFFFF0000u); }
__device__ __forceinline__ u32 pack2(float a, float b) { return (u32)f2bf(a) | ((u32)f2bf(b) << 16); }

__device__ __forceinline__ void dec4(float* acc, u32 w) {
    f32x2 lo = __builtin_amdgcn_cvt_pk_f32_fp8(w, false);
    f32x2 hi = __builtin_amdgcn_cvt_pk_f32_fp8(w, true);
    acc[0] += lo[0]; acc[1] += lo[1]; acc[2] += hi[0]; acc[3] += hi[1];
}
__device__ __forceinline__ void dec16(float* acc, uint4 v) {
    dec4(acc + 0, v.x); dec4(acc + 4, v.y); dec4(acc + 8, v.z); dec4(acc + 12, v.w);
}
__device__ __forceinline__ u8 f2fp8(float v) {
    return (u8)__builtin_amdgcn_cvt_pk_fp8_f32(v, v, 0, false);
}

__device__ __forceinline__ void gload16(const u16* g, u16* l) {
    __builtin_amdgcn_global_load_lds((const __attribute__((address_space(1))) void*)g,
                                     (__attribute__((address_space(3))) void*)l, 16, 0, 0);
}

// ---------------- fused prep: edge-count | x->fp8 | weights->bf16 ----------------
__global__ __launch_bounds__(256) void k_prep(const int* __restrict__ dst, int* __restrict__ cnt, int E,
                                              const float* __restrict__ x, u32* __restrict__ x8,
                                              const float* __restrict__ W1, const float* __restrict__ W2,
                                              const float* __restrict__ W3, u16* __restrict__ o1,
                                              u16* __restrict__ o2, u16* __restrict__ o3)
{
    const int b = blockIdx.x, t = threadIdx.x;
    if (b < 2000) {                       // edge degree count
        int e = b * 256 + t;
        if (e < E) atomicAdd(&cnt[dst[e]], 1);
    } else if (b < 10000) {               // x -> fp8 table
        int i = (b - 2000) * 256 + t;
        float4 v = ((const float4*)x)[i];
        int p = __builtin_amdgcn_cvt_pk_fp8_f32(v.x, v.y, 0, false);
        p = __builtin_amdgcn_cvt_pk_fp8_f32(v.z, v.w, p, true);
        x8[i] = (u32)p;
    } else {                              // weights -> bf16
        int bb = b - 10000;
        const float* in; u16* out; int i;
        if (bb < 128)      { in = W1; out = o1; i = bb * 256 + t; }
        else if (bb < 384) { in = W2; out = o2; i = (bb - 128) * 256 + t; }
        else               { in = W3; out = o3; i = (bb - 384) * 256 + t; }
        float4 v = ((const float4*)in)[i];
        ushort4 o;
        o.x = f2bf(v.x); o.y = f2bf(v.y); o.z = f2bf(v.z); o.w = f2bf(v.w);
        ((ushort4*)out)[i] = o;
    }
}

// ---------------- CSR scan ----------------
__global__ __launch_bounds__(256) void k_scan_blk(const int* __restrict__ cnt, int* __restrict__ rp,
                                                  int* __restrict__ bsum)
{
    __shared__ int sh[256];
    const int b = blockIdx.x, t = threadIdx.x;
    int v = cnt[b * 256 + t];
    sh[t] = v;
    __syncthreads();
    for (int off = 1; off < 256; off <<= 1) {
        int u = (t >= off) ? sh[t - off] : 0;
        __syncthreads();
        sh[t] += u;
        __syncthreads();
    }
    rp[b * 256 + t] = sh[t] - v;
    if (t == 255) bsum[b] = sh[255];
}

__global__ __launch_bounds__(256) void k_scan_add(int* __restrict__ rp, const int* __restrict__ bsum,
                                                  int nb, int n, int E)
{
    __shared__ int sh[256];
    const int b = blockIdx.x, t = threadIdx.x;
    int v = (t < b && t < nb) ? bsum[t] : 0;
    sh[t] = v;
    __syncthreads();
    for (int off = 128; off > 0; off >>= 1) {
        if (t < off) sh[t] += sh[t + off];
        __syncthreads();
    }
    int i = b * 256 + t;
    rp[i] += sh[0];
    if (i == 0) rp[n] = E;
}

__global__ __launch_bounds__(256) void k_place(const int* __restrict__ src, const int* __restrict__ dst,
                                               const int* __restrict__ rp, int* __restrict__ cur,
                                               int* __restrict__ cs, int E)
{
    int e = blockIdx.x * 256 + threadIdx.x;
    if (e < E) {
        int d = dst[e];
        int p = rp[d] + atomicAdd(&cur[d], 1);
        cs[p] = src[e];
    }
}

// ---------------- bf16 MFMA GEMM, dbuf + counted vmcnt; optional fused column stats ----------------
template <bool RELU, bool DEGB, bool F8OUT, bool STATS>
__global__ __launch_bounds__(256) void k_gemm_mfma(const u16* __restrict__ A, const u16* __restrict__ W,
                                                   const float* __restrict__ bias, const int* __restrict__ rp,
                                                   void* __restrict__ Cv, float* __restrict__ partial,
                                                   int K, int OD)
{
    __shared__ u16 As[2][128 * 32];
    __shared__ u16 Bs[2][128 * 32];
    const int t = threadIdx.x;
    const int lane = t & 63;
    const int w = t >> 6;
    const int wr = w >> 1, wc = w & 1;
    const int bm = blockIdx.x * 128;
    const int bn = blockIdx.y * 128;

    const int c0 = w * 64 + lane;
    const int r0 = c0 >> 2, kc0 = (c0 & 3) * 8;
    const int c1 = c0 + 256;
    const int r1 = c1 >> 2, kc1 = (c1 & 3) * 8;
    const u16* gA0 = A + (size_t)(bm + r0) * K + kc0;
    const u16* gA1 = A + (size_t)(bm + r1) * K + kc1;
    const u16* gB0 = W + (size_t)(bn + r0) * K + kc0;
    const u16* gB1 = W + (size_t)(bn + r1) * K + kc1;

    f32x4 acc[4][4];
#pragma unroll
    for (int i = 0; i < 4; ++i)
#pragma unroll
        for (int j = 0; j < 4; ++j)
            acc[i][j] = (f32x4){0.f, 0.f, 0.f, 0.f};

    const int fr = lane & 15;
    const int ko = (lane >> 4) * 8;

    auto STAGE = [&](int b, int k0) {
        gload16(gA0 + k0, &As[b][0] + w * 512);
        gload16(gA1 + k0, &As[b][0] + 2048 + w * 512);
        gload16(gB0 + k0, &Bs[b][0] + w * 512);
        gload16(gB1 + k0, &Bs[b][0] + 2048 + w * 512);
    };

    STAGE(0, 0);

    int cur = 0;
    for (int k0 = 0; k0 < K; k0 += 32) {
        if (k0 + 32 < K) {
            STAGE(cur ^ 1, k0 + 32);
            asm volatile("s_waitcnt vmcnt(4)" ::: "memory");
        } else {
            asm volatile("s_waitcnt vmcnt(0)" ::: "memory");
        }
        __syncthreads();
        bf16x8 af[4], bfv[4];
#pragma unroll
        for (int i = 0; i < 4; ++i)
            af[i] = *(const bf16x8*)&As[cur][(wr * 64 + i * 16 + fr) * 32 + ko];
#pragma unroll
        for (int j = 0; j < 4; ++j)
            bfv[j] = *(const bf16x8*)&Bs[cur][(wc * 64 + j * 16 + fr) * 32 + ko];
#pragma unroll
        for (int i = 0; i < 4; ++i)
#pragma unroll
            for (int j = 0; j < 4; ++j)
                acc[i][j] = __builtin_amdgcn_mfma_f32_16x16x32_bf16(af[i], bfv[j], acc[i][j], 0, 0, 0);
        __syncthreads();
        cur ^= 1;
    }

    u16* C16 = (u16*)Cv;
    u8*  C8  = (u8*)Cv;
    const int qr = (lane >> 4) * 4;
    float bcol[4];
#pragma unroll
    for (int j = 0; j < 4; ++j) bcol[j] = bias[bn + wc * 64 + j * 16 + fr];
    float s4[4] = {}, q4[4] = {};
#pragma unroll
    for (int i = 0; i < 4; ++i) {
#pragma unroll
        for (int r = 0; r < 4; ++r) {
            int row = bm + wr * 64 + i * 16 + qr + r;
            float bm_ = 1.f;
            if (DEGB) bm_ = (float)(rp[row + 1] - rp[row]) + 1.f;
#pragma unroll
            for (int j = 0; j < 4; ++j) {
                int col = bn + wc * 64 + j * 16 + fr;
                float o = acc[i][j][r] + bm_ * bcol[j];
                if (RELU) o = fmaxf(o, 0.f);
                if (STATS) { s4[j] += o; q4[j] = fmaf(o, o, q4[j]); }
                if (F8OUT) C8[(size_t)row * OD + col] = f2fp8(o);
                else       C16[(size_t)row * OD + col] = f2bf(o);
            }
        }
    }

    if (STATS) {
        // reduce across the 4 quads that share (w, fr): lanes l, l^16, l^32, l^48
#pragma unroll
        for (int j = 0; j < 4; ++j) {
            s4[j] += __shfl_xor(s4[j], 16); s4[j] += __shfl_xor(s4[j], 32);
            q4[j] += __shfl_xor(q4[j], 16); q4[j] += __shfl_xor(q4[j], 32);
        }
        __syncthreads();                       // LDS (As) free for reuse
        float* sred = (float*)&As[0][0];       // [4 waves][4 j][16 fr][2]
        if ((lane >> 4) == 0) {
#pragma unroll
            for (int j = 0; j < 4; ++j) {
                sred[((w * 4 + j) * 16 + fr) * 2 + 0] = s4[j];
                sred[((w * 4 + j) * 16 + fr) * 2 + 1] = q4[j];
            }
        }
        __syncthreads();
        if (wr == 0 && (lane >> 4) == 0) {     // waves 0,1; 16 lanes; 4 j => 128 cols
#pragma unroll
            for (int j = 0; j < 4; ++j) {
                int i0 = ((w * 4 + j) * 16 + fr) * 2;
                int i1 = (((w + 2) * 4 + j) * 16 + fr) * 2;
                float ss = sred[i0] + sred[i1];
                float qq = sred[i0 + 1] + sred[i1 + 1];
                int col = bn + wc * 64 + j * 16 + fr;
                partial[(size_t)blockIdx.x * 1024 + col]       = ss;
                partial[(size_t)blockIdx.x * 1024 + 512 + col] = qq;
            }
        }
    }
}

// ---------------- fp8 gather+self(+relu), D=256 ----------------
template <bool RELU>
__global__ __launch_bounds__(256) void k_agg256_f8(const u8* __restrict__ h8, const int* __restrict__ rp,
                                                   const int* __restrict__ cs, u16* __restrict__ out)
{
    const int lane = threadIdx.x & 63;
    const int n = blockIdx.x * 4 + (threadIdx.x >> 6);
    const int g = lane >> 4;
    const int c = lane & 15;
    const uint4* hb = (const uint4*)h8 + c;

    float acc[16];
#pragma unroll
    for (int i = 0; i < 16; ++i) acc[i] = 0.f;
    if (g == 0) dec16(acc, hb[(size_t)n * 16]);

    const int beg = rp[n], end = rp[n + 1];
    int e = beg;
    for (; e + 16 <= end; e += 16) {
        uint4 v0 = hb[(size_t)cs[e + g] * 16];
        uint4 v1 = hb[(size_t)cs[e + 4 + g] * 16];
        uint4 v2 = hb[(size_t)cs[e + 8 + g] * 16];
        uint4 v3 = hb[(size_t)cs[e + 12 + g] * 16];
        dec16(acc, v0); dec16(acc, v1); dec16(acc, v2); dec16(acc, v3);
    }
    for (; e + 4 <= end; e += 4) {
        uint4 v = hb[(size_t)cs[e + g] * 16];
        dec16(acc, v);
    }
    if (e + g < end) {
        uint4 v = hb[(size_t)cs[e + g] * 16];
        dec16(acc, v);
    }
#pragma unroll
    for (int i = 0; i < 16; ++i) acc[i] += __shfl_xor(acc[i], 16);
#pragma unroll
    for (int i = 0; i < 16; ++i) acc[i] += __shfl_xor(acc[i], 32);
    if (g == 0) {
        if (RELU) {
#pragma unroll
            for (int i = 0; i < 16; ++i) acc[i] = fmaxf(acc[i], 0.f);
        }
        uint4 o0, o1;
        o0.x = pack2(acc[0], acc[1]);  o0.y = pack2(acc[2], acc[3]);
        o0.z = pack2(acc[4], acc[5]);  o0.w = pack2(acc[6], acc[7]);
        o1.x = pack2(acc[8], acc[9]);  o1.y = pack2(acc[10], acc[11]);
        o1.z = pack2(acc[12], acc[13]); o1.w = pack2(acc[14], acc[15]);
        uint4* op = (uint4*)((u32*)out + (size_t)n * 128 + c * 8);
        op[0] = o0; op[1] = o1;
    }
}

// ---------------- fp8 gather+self(+relu), D=512 ----------------
template <bool RELU>
__global__ __launch_bounds__(256) void k_agg512_f8(const u8* __restrict__ h8, const int* __restrict__ rp,
                                                   const int* __restrict__ cs, u16* __restrict__ out)
{
    const int lane = threadIdx.x & 63;
    const int n = blockIdx.x * 4 + (threadIdx.x >> 6);
    const int g = lane >> 5;
    const int c = lane & 31;
    const uint4* hb = (const uint4*)h8 + c;

    float acc[16];
#pragma unroll
    for (int i = 0; i < 16; ++i) acc[i] = 0.f;
    if (g == 0) dec16(acc, hb[(size_t)n * 32]);

    const int beg = rp[n], end = rp[n + 1];
    int e = beg;
    for (; e + 8 <= end; e += 8) {
        uint4 v0 = hb[(size_t)cs[e + g] * 32];
        uint4 v1 = hb[(size_t)cs[e + 2 + g] * 32];
        uint4 v2 = hb[(size_t)cs[e + 4 + g] * 32];
        uint4 v3 = hb[(size_t)cs[e + 6 + g] * 32];
        dec16(acc, v0); dec16(acc, v1); dec16(acc, v2); dec16(acc, v3);
    }
    for (; e + 2 <= end; e += 2) {
        uint4 v = hb[(size_t)cs[e + g] * 32];
        dec16(acc, v);
    }
    if (e + g < end) {
        uint4 v = hb[(size_t)cs[e + g] * 32];
        dec16(acc, v);
    }
#pragma unroll
    for (int i = 0; i < 16; ++i) acc[i] += __shfl_xor(acc[i], 32);
    if (g == 0) {
        if (RELU) {
#pragma unroll
            for (int i = 0; i < 16; ++i) acc[i] = fmaxf(acc[i], 0.f);
        }
        uint4 o0, o1;
        o0.x = pack2(acc[0], acc[1]);  o0.y = pack2(acc[2], acc[3]);
        o0.z = pack2(acc[4], acc[5]);  o0.w = pack2(acc[6], acc[7]);
        o1.x = pack2(acc[8], acc[9]);  o1.y = pack2(acc[10], acc[11]);
        o1.z = pack2(acc[12], acc[13]); o1.w = pack2(acc[14], acc[15]);
        uint4* op = (uint4*)((u32*)out + (size_t)n * 256 + c * 8);
        op[0] = o0; op[1] = o1;
    }
}

// ---------------- BN stats, stage A (layers 2,3) ----------------
template <int D>
__global__ __launch_bounds__(256) void k_bn_part(const u16* __restrict__ h, float* __restrict__ partial)
{
    constexpr int SLOT = D / 8;
    constexpr int NS = 256 / SLOT;
    constexpr int ROWS = 16;
    const int t = threadIdx.x;
    const int s = t % SLOT, j = t / SLOT;
    const int r0 = blockIdx.x * ROWS;
    float a[8] = {}, q[8] = {};
#pragma unroll
    for (int rr = 0; rr < ROWS / NS; ++rr) {
        int r = j + rr * NS;
        uint4 v = *((const uint4*)(h + (size_t)(r0 + r) * D) + s);
        u32 wv[4] = {v.x, v.y, v.z, v.w};
#pragma unroll
        for (int k = 0; k < 4; ++k) {
            float lo = bf_lo(wv[k]), hi = bf_hi(wv[k]);
            a[2 * k]     += lo; q[2 * k]     = fmaf(lo, lo, q[2 * k]);
            a[2 * k + 1] += hi; q[2 * k + 1] = fmaf(hi, hi, q[2 * k + 1]);
        }
    }
    __shared__ float red[16][256];
#pragma unroll
    for (int i = 0; i < 8; ++i) { red[i][t] = a[i]; red[8 + i][t] = q[i]; }
    __syncthreads();
    if (j == 0) {
        for (int k = 1; k < NS; ++k) {
            int o = k * SLOT + s;
#pragma unroll
            for (int i = 0; i < 8; ++i) { a[i] += red[i][o]; q[i] += red[8 + i][o]; }
        }
        float* pb = partial + (size_t)blockIdx.x * (2 * D);
        float4* p0 = (float4*)(pb + 8 * s);
        p0[0] = make_float4(a[0], a[1], a[2], a[3]);
        p0[1] = make_float4(a[4], a[5], a[6], a[7]);
        float4* p1 = (float4*)(pb + D + 8 * s);
        p1[0] = make_float4(q[0], q[1], q[2], q[3]);
        p1[1] = make_float4(q[4], q[5], q[6], q[7]);
    }
}

// ---------------- BN stats, stage B ----------------
template <int D, int P, int SEG>
__global__ __launch_bounds__(256) void k_bn_red(const float* __restrict__ partial, float* __restrict__ sums)
{
    const int g = blockIdx.x * 256 + threadIdx.x;
    const int col = g & (2 * D - 1);
    const int seg = g / (2 * D);
    constexpr int CHUNK = P / SEG;
    const float* p = partial + (size_t)seg * CHUNK * (2 * D) + col;
    float acc = 0.f;
#pragma unroll 4
    for (int i = 0; i < CHUNK; ++i) acc += p[(size_t)i * (2 * D)];
    atomicAdd(&sums[col], acc);
}

// ---------------- BN apply with inline finalize ----------------
template <int D>
__global__ __launch_bounds__(256) void k_bn_apply(u16* __restrict__ h, const float* __restrict__ sums,
                                                  const float* __restrict__ gam, const float* __restrict__ bet)
{
    int i = blockIdx.x * 256 + threadIdx.x;
    int c = (i * 8) & (D - 1);
    const float invN = 1.f / (float)N_NODES;
    float sc[8], sh[8];
#pragma unroll
    for (int k = 0; k < 8; ++k) {
        float mu  = sums[c + k] * invN;
        float var = sums[D + c + k] * invN - mu * mu;
        float rs  = rsqrtf(var + 1e-5f);
        sc[k] = gam[c + k] * rs;
        sh[k] = bet[c + k] - mu * sc[k];
    }
    uint4 v = ((uint4*)h)[i];
    u32 vv[4] = {v.x, v.y, v.z, v.w};
    u32 r[4];
#pragma unroll
    for (int k = 0; k < 4; ++k) {
        float a = leakyf(fmaf(bf_lo(vv[k]), sc[2 * k], sh[2 * k]));
        float b = leakyf(fmaf(bf_hi(vv[k]), sc[2 * k + 1], sh[2 * k + 1]));
        r[k] = pack2(a, b);
    }
    ((uint4*)h)[i] = make_uint4(r[0], r[1], r[2], r[3]);
}

// ---------------- pool (fused BN3+leaky) + head via last-block ----------------
__global__ __launch_bounds__(256) void k_pool_bn_final(const u16* __restrict__ h, const float* __restrict__ sums,
                                                       const float* __restrict__ gam, const float* __restrict__ bet,
                                                       float* __restrict__ gp, const float* __restrict__ Wp,
                                                       const float* __restrict__ bp, float* __restrict__ out,
                                                       int* __restrict__ done)
{
    __shared__ float lg[32];
    __shared__ int isLast;
    int b = blockIdx.x, ch = blockIdx.y, t = threadIdx.x;
    int s = t & 63, j = t >> 6;
    const float invN = 1.f / (float)N_NODES;
    float sc[4], sh[4];
#pragma unroll
    for (int k = 0; k < 4; ++k) {
        int c = 4 * s + k;
        float mu  = sums[c] * invN;
        float var = sums[256 + c] * invN - mu * mu;
        float rs  = rsqrtf(var + 1e-5f);
        sc[k] = gam[c] * rs;
        sh[k] = bet[c] - mu * sc[k];
    }
    int r0 = b * 2000 + ch * 80;
    float a0 = 0.f, a1 = 0.f, a2 = 0.f, a3 = 0.f;
    for (int r = j; r < 80; r += 4) {
        uint2 v = *((const uint2*)(h + (size_t)(r0 + r) * 256) + s);
        a0 += leakyf(fmaf(bf_lo(v.x), sc[0], sh[0]));
        a1 += leakyf(fmaf(bf_hi(v.x), sc[1], sh[1]));
        a2 += leakyf(fmaf(bf_lo(v.y), sc[2], sh[2]));
        a3 += leakyf(fmaf(bf_hi(v.y), sc[3], sh[3]));
    }
    atomicAdd(&gp[b * 256 + s * 4 + 0], a0);
    atomicAdd(&gp[b * 256 + s * 4 + 1], a1);
    atomicAdd(&gp[b * 256 + s * 4 + 2], a2);
    atomicAdd(&gp[b * 256 + s * 4 + 3], a3);

    __threadfence();
    if (t == 0) isLast = (atomicAdd(done, 1) == 16 * 25 - 1);
    __syncthreads();
    if (!isLast) return;
    __threadfence();
    if (t < 32) {
        int bb = t >> 1, c = t & 1;
        float sacc = 0.f;
        for (int k = 0; k < 256; ++k) sacc = fmaf(gp[bb * 256 + k], Wp[c * 256 + k], sacc);
        float o = sacc * (1.f / 2000.f) + bp[c];
        out[bb * 2 + c] = o;
        lg[t] = o;
    }
    __syncthreads();
    if (t < 16) out[32 + t] = (lg[t * 2 + 1] > lg[t * 2]) ? 1.f : 0.f;
}

extern "C" void kernel_launch(void* const* d_in, const int* in_sizes, int n_in,
                              void* d_out, int out_size, void* d_ws, size_t ws_size,
                              hipStream_t stream)
{
    const float* x   = (const float*)d_in[0];
    const int*   ei  = (const int*)d_in[1];
    const float* W1  = (const float*)d_in[2];
    const float* b1  = (const float*)d_in[3];
    const float* W2  = (const float*)d_in[4];
    const float* b2  = (const float*)d_in[5];
    const float* W3  = (const float*)d_in[6];
    const float* b3  = (const float*)d_in[7];
    const float* g1  = (const float*)d_in[8];
    const float* be1 = (const float*)d_in[9];
    const float* g2  = (const float*)d_in[10];
    const float* be2 = (const float*)d_in[11];
    const float* g3  = (const float*)d_in[12];
    const float* be3 = (const float*)d_in[13];
    const float* Wp  = (const float*)d_in[14];
    const float* bp  = (const float*)d_in[15];
    float* out = (float*)d_out;

    const int E = in_sizes[1] / 2;
    const int* src = ei;
    const int* dst = ei + E;

    char* ws = (char*)d_ws;
    size_t off = 0;
    auto alloc = [&](size_t bytes) -> void* {
        void* p = ws + off;
        off = (off + bytes + 255) & ~(size_t)255;
        return p;
    };
    u16*   bufA = (u16*)alloc((size_t)N_NODES * 512 * 2);
    u16*   bufB = (u16*)alloc((size_t)N_NODES * 512 * 2);
    u8*    buf8 = (u8*)alloc((size_t)N_NODES * 512);
    u8*    x8   = (u8*)alloc((size_t)N_NODES * 256);
    u16*   w1b  = (u16*)alloc(512 * 256 * 2);
    u16*   w2b  = (u16*)alloc(512 * 512 * 2);
    u16*   w3b  = (u16*)alloc(256 * 512 * 2);
    int*   cs   = (int*)alloc((size_t)E * 4);
    int*   rp   = (int*)alloc((size_t)(N_NODES + 1) * 4);
    // contiguous zero region: cnt | cur | sums1..3 | gp | done
    int*   cnt  = (int*)alloc((size_t)N_NODES * 4 * 2 + 7424 * 4);
    int*   cur  = cnt + N_NODES;
    float* zz   = (float*)(cnt + 2 * N_NODES);
    float* sums1 = zz, *sums2 = zz + 1024, *sums3 = zz + 2048;
    float* gp   = zz + 3072;                 // 4096 floats
    int*   done = (int*)(zz + 7168);
    const size_t zbytes = (size_t)N_NODES * 8 + 7424 * 4;
    int*   bsum = (int*)alloc(256 * 4);
    float* part = (float*)alloc((size_t)2000 * 1024 * 4);

    hipMemsetAsync(cnt, 0, zbytes, stream);

    const int eb = (E + 255) / 256;          // 2000
    const int nb = N_NODES / 256;            // 125

    // fused prep: count | x->fp8 | weights->bf16
    k_prep<<<eb + 8000 + 512, 256, 0, stream>>>(dst, cnt, E, x, (u32*)x8, W1, W2, W3, w1b, w2b, w3b);
    k_scan_blk<<<nb, 256, 0, stream>>>(cnt, rp, bsum);
    k_scan_add<<<nb, 256, 0, stream>>>(rp, bsum, nb, N_NODES, E);
    k_place<<<eb, 256, 0, stream>>>(src, dst, rp, cur, cs, E);

    const int PB = N_NODES / 16;             // 2000 stage-A blocks

    // ---- layer 1: s = x + sum_src x (fp8 gather); h1 = relu(s@W1' + (deg+1)*b1), stats fused ----
    k_agg256_f8<false><<<N_NODES / 4, 256, 0, stream>>>(x8, rp, cs, bufA);
    k_gemm_mfma<true, true, false, true><<<dim3(250, 4), 256, 0, stream>>>(bufA, w1b, b1, rp, bufB, part, 256, 512);
    k_bn_red<512, 250, 2><<<8, 256, 0, stream>>>(part, sums1);
    k_bn_apply<512><<<N_NODES * 512 / 8 / 256, 256, 0, stream>>>(bufB, sums1, g1, be1);

    // ---- layer 2: GEMM (fp8 out) -> 512-wide fp8 gather+relu -> stats -> apply ----
    k_gemm_mfma<false, false, true, false><<<dim3(250, 4), 256, 0, stream>>>(bufB, w2b, b2, rp, buf8, nullptr, 512, 512);
    k_agg512_f8<true><<<N_NODES / 4, 256, 0, stream>>>(buf8, rp, cs, bufA);
    k_bn_part<512><<<PB, 256, 0, stream>>>(bufA, part);
    k_bn_red<512, 2000, 8><<<32, 256, 0, stream>>>(part, sums2);
    k_bn_apply<512><<<N_NODES * 512 / 8 / 256, 256, 0, stream>>>(bufA, sums2, g2, be2);

    // ---- layer 3: GEMM (512->256, fp8 out) -> 256-wide fp8 gather+relu -> stats ----
    k_gemm_mfma<false, false, true, false><<<dim3(250, 2), 256, 0, stream>>>(bufA, w3b, b3, rp, buf8, nullptr, 512, 256);
    k_agg256_f8<true><<<N_NODES / 4, 256, 0, stream>>>(buf8, rp, cs, bufB);
    k_bn_part<256><<<PB, 256, 0, stream>>>(bufB, part);
    k_bn_red<256, 2000, 8><<<16, 256, 0, stream>>>(part, sums3);

    // ---- pool (fused BN3+leaky) + head (last-block) ----
    k_pool_bn_final<<<dim3(16, 25), 256, 0, stream>>>(bufB, sums3, g3, be3, gp, Wp, bp, out, done);
}

// Round 13
// 384.102 us; speedup vs baseline: 2.3749x; 1.0738x over previous
//
#include <hip/hip_runtime.h>

#define N_NODES 32000
typedef unsigned short u16;
typedef unsigned int u32;
typedef unsigned char u8;
typedef __attribute__((ext_vector_type(8))) short bf16x8;
typedef __attribute__((ext_vector_type(4))) float f32x4;
typedef __attribute__((ext_vector_type(2))) float f32x2;

__device__ __forceinline__ float leakyf(float v) { return v >= 0.f ? v : 0.1f * v; }
__device__ __forceinline__ u16 f2bf(float f) {
    u32 u = __float_as_uint(f);
    return (u16)((u + 0x7FFFu + ((u >> 16) & 1u)) >> 16);
}
__device__ __forceinline__ float bf_lo(u32 u) { return __uint_as_float(u << 16); }
__device__ __forceinline__ float bf_hi(u32 u) { return __uint_as_float(u & 0xFFFF0000u); }
__device__ __forceinline__ u32 pack2(float a, float b) { return (u32)f2bf(a) | ((u32)f2bf(b) << 16); }

__device__ __forceinline__ void dec4(float* acc, u32 w) {
    f32x2 lo = __builtin_amdgcn_cvt_pk_f32_fp8(w, false);
    f32x2 hi = __builtin_amdgcn_cvt_pk_f32_fp8(w, true);
    acc[0] += lo[0]; acc[1] += lo[1]; acc[2] += hi[0]; acc[3] += hi[1];
}
__device__ __forceinline__ void dec16(float* acc, uint4 v) {
    dec4(acc + 0, v.x); dec4(acc + 4, v.y); dec4(acc + 8, v.z); dec4(acc + 12, v.w);
}
__device__ __forceinline__ u8 f2fp8(float v) {
    return (u8)__builtin_amdgcn_cvt_pk_fp8_f32(v, v, 0, false);
}

__device__ __forceinline__ void gload16(const u16* g, u16* l) {
    __builtin_amdgcn_global_load_lds((const __attribute__((address_space(1))) void*)g,
                                     (__attribute__((address_space(3))) void*)l, 16, 0, 0);
}

// ---------------- fused prep: edge-count | x->fp8 | weights->bf16 ----------------
__global__ __launch_bounds__(256) void k_prep(const int* __restrict__ dst, int* __restrict__ cnt, int E,
                                              const float* __restrict__ x, u32* __restrict__ x8,
                                              const float* __restrict__ W1, const float* __restrict__ W2,
                                              const float* __restrict__ W3, u16* __restrict__ o1,
                                              u16* __restrict__ o2, u16* __restrict__ o3)
{
    const int b = blockIdx.x, t = threadIdx.x;
    if (b < 2000) {
        int e = b * 256 + t;
        if (e < E) atomicAdd(&cnt[dst[e]], 1);
    } else if (b < 10000) {
        int i = (b - 2000) * 256 + t;
        float4 v = ((const float4*)x)[i];
        int p = __builtin_amdgcn_cvt_pk_fp8_f32(v.x, v.y, 0, false);
        p = __builtin_amdgcn_cvt_pk_fp8_f32(v.z, v.w, p, true);
        x8[i] = (u32)p;
    } else {
        int bb = b - 10000;
        const float* in; u16* out; int i;
        if (bb < 128)      { in = W1; out = o1; i = bb * 256 + t; }
        else if (bb < 384) { in = W2; out = o2; i = (bb - 128) * 256 + t; }
        else               { in = W3; out = o3; i = (bb - 384) * 256 + t; }
        float4 v = ((const float4*)in)[i];
        ushort4 o;
        o.x = f2bf(v.x); o.y = f2bf(v.y); o.z = f2bf(v.z); o.w = f2bf(v.w);
        ((ushort4*)out)[i] = o;
    }
}

// ---------------- CSR scan ----------------
__global__ __launch_bounds__(256) void k_scan_blk(const int* __restrict__ cnt, int* __restrict__ rp,
                                                  int* __restrict__ bsum)
{
    __shared__ int sh[256];
    const int b = blockIdx.x, t = threadIdx.x;
    int v = cnt[b * 256 + t];
    sh[t] = v;
    __syncthreads();
    for (int off = 1; off < 256; off <<= 1) {
        int u = (t >= off) ? sh[t - off] : 0;
        __syncthreads();
        sh[t] += u;
        __syncthreads();
    }
    rp[b * 256 + t] = sh[t] - v;
    if (t == 255) bsum[b] = sh[255];
}

__global__ __launch_bounds__(256) void k_scan_add(int* __restrict__ rp, const int* __restrict__ bsum,
                                                  int nb, int n, int E)
{
    __shared__ int sh[256];
    const int b = blockIdx.x, t = threadIdx.x;
    int v = (t < b && t < nb) ? bsum[t] : 0;
    sh[t] = v;
    __syncthreads();
    for (int off = 128; off > 0; off >>= 1) {
        if (t < off) sh[t] += sh[t + off];
        __syncthreads();
    }
    int i = b * 256 + t;
    rp[i] += sh[0];
    if (i == 0) rp[n] = E;
}

__global__ __launch_bounds__(256) void k_place(const int* __restrict__ src, const int* __restrict__ dst,
                                               const int* __restrict__ rp, int* __restrict__ cur,
                                               int* __restrict__ cs, int E)
{
    int e = blockIdx.x * 256 + threadIdx.x;
    if (e < E) {
        int d = dst[e];
        int p = rp[d] + atomicAdd(&cur[d], 1);
        cs[p] = src[e];
    }
}

// ---------------- bf16 MFMA GEMM, dbuf + counted vmcnt; optional fused column stats ----------------
template <bool RELU, bool DEGB, bool F8OUT, bool STATS>
__global__ __launch_bounds__(256) void k_gemm_mfma(const u16* __restrict__ A, const u16* __restrict__ W,
                                                   const float* __restrict__ bias, const int* __restrict__ rp,
                                                   void* __restrict__ Cv, float* __restrict__ partial,
                                                   int K, int OD)
{
    __shared__ u16 As[2][128 * 32];
    __shared__ u16 Bs[2][128 * 32];
    const int t = threadIdx.x;
    const int lane = t & 63;
    const int w = t >> 6;
    const int wr = w >> 1, wc = w & 1;
    const int bm = blockIdx.x * 128;
    const int bn = blockIdx.y * 128;

    const int c0 = w * 64 + lane;
    const int r0 = c0 >> 2, kc0 = (c0 & 3) * 8;
    const int c1 = c0 + 256;
    const int r1 = c1 >> 2, kc1 = (c1 & 3) * 8;
    const u16* gA0 = A + (size_t)(bm + r0) * K + kc0;
    const u16* gA1 = A + (size_t)(bm + r1) * K + kc1;
    const u16* gB0 = W + (size_t)(bn + r0) * K + kc0;
    const u16* gB1 = W + (size_t)(bn + r1) * K + kc1;

    f32x4 acc[4][4];
#pragma unroll
    for (int i = 0; i < 4; ++i)
#pragma unroll
        for (int j = 0; j < 4; ++j)
            acc[i][j] = (f32x4){0.f, 0.f, 0.f, 0.f};

    const int fr = lane & 15;
    const int ko = (lane >> 4) * 8;

    auto STAGE = [&](int b, int k0) {
        gload16(gA0 + k0, &As[b][0] + w * 512);
        gload16(gA1 + k0, &As[b][0] + 2048 + w * 512);
        gload16(gB0 + k0, &Bs[b][0] + w * 512);
        gload16(gB1 + k0, &Bs[b][0] + 2048 + w * 512);
    };

    STAGE(0, 0);

    int cur = 0;
    for (int k0 = 0; k0 < K; k0 += 32) {
        if (k0 + 32 < K) {
            STAGE(cur ^ 1, k0 + 32);
            asm volatile("s_waitcnt vmcnt(4)" ::: "memory");
        } else {
            asm volatile("s_waitcnt vmcnt(0)" ::: "memory");
        }
        __syncthreads();
        bf16x8 af[4], bfv[4];
#pragma unroll
        for (int i = 0; i < 4; ++i)
            af[i] = *(const bf16x8*)&As[cur][(wr * 64 + i * 16 + fr) * 32 + ko];
#pragma unroll
        for (int j = 0; j < 4; ++j)
            bfv[j] = *(const bf16x8*)&Bs[cur][(wc * 64 + j * 16 + fr) * 32 + ko];
#pragma unroll
        for (int i = 0; i < 4; ++i)
#pragma unroll
            for (int j = 0; j < 4; ++j)
                acc[i][j] = __builtin_amdgcn_mfma_f32_16x16x32_bf16(af[i], bfv[j], acc[i][j], 0, 0, 0);
        __syncthreads();
        cur ^= 1;
    }

    u16* C16 = (u16*)Cv;
    u8*  C8  = (u8*)Cv;
    const int qr = (lane >> 4) * 4;
    float bcol[4];
#pragma unroll
    for (int j = 0; j < 4; ++j) bcol[j] = bias[bn + wc * 64 + j * 16 + fr];
    float s4[4] = {}, q4[4] = {};
#pragma unroll
    for (int i = 0; i < 4; ++i) {
#pragma unroll
        for (int r = 0; r < 4; ++r) {
            int row = bm + wr * 64 + i * 16 + qr + r;
            float bm_ = 1.f;
            if (DEGB) bm_ = (float)(rp[row + 1] - rp[row]) + 1.f;
#pragma unroll
            for (int j = 0; j < 4; ++j) {
                int col = bn + wc * 64 + j * 16 + fr;
                float o = acc[i][j][r] + bm_ * bcol[j];
                if (RELU) o = fmaxf(o, 0.f);
                if (STATS) { s4[j] += o; q4[j] = fmaf(o, o, q4[j]); }
                if (F8OUT) C8[(size_t)row * OD + col] = f2fp8(o);
                else       C16[(size_t)row * OD + col] = f2bf(o);
            }
        }
    }

    if (STATS) {
#pragma unroll
        for (int j = 0; j < 4; ++j) {
            s4[j] += __shfl_xor(s4[j], 16); s4[j] += __shfl_xor(s4[j], 32);
            q4[j] += __shfl_xor(q4[j], 16); q4[j] += __shfl_xor(q4[j], 32);
        }
        __syncthreads();
        float* sred = (float*)&As[0][0];
        if ((lane >> 4) == 0) {
#pragma unroll
            for (int j = 0; j < 4; ++j) {
                sred[((w * 4 + j) * 16 + fr) * 2 + 0] = s4[j];
                sred[((w * 4 + j) * 16 + fr) * 2 + 1] = q4[j];
            }
        }
        __syncthreads();
        if (wr == 0 && (lane >> 4) == 0) {
#pragma unroll
            for (int j = 0; j < 4; ++j) {
                int i0 = ((w * 4 + j) * 16 + fr) * 2;
                int i1 = (((w + 2) * 4 + j) * 16 + fr) * 2;
                float ss = sred[i0] + sred[i1];
                float qq = sred[i0 + 1] + sred[i1 + 1];
                int col = bn + wc * 64 + j * 16 + fr;
                partial[(size_t)blockIdx.x * 1024 + col]       = ss;
                partial[(size_t)blockIdx.x * 1024 + 512 + col] = qq;
            }
        }
    }
}

// ---------------- fp8 gather+self(+relu), D=256 ----------------
template <bool RELU>
__global__ __launch_bounds__(256) void k_agg256_f8(const u8* __restrict__ h8, const int* __restrict__ rp,
                                                   const int* __restrict__ cs, u16* __restrict__ out)
{
    const int lane = threadIdx.x & 63;
    const int n = blockIdx.x * 4 + (threadIdx.x >> 6);
    const int g = lane >> 4;
    const int c = lane & 15;
    const uint4* hb = (const uint4*)h8 + c;

    float acc[16];
#pragma unroll
    for (int i = 0; i < 16; ++i) acc[i] = 0.f;
    if (g == 0) dec16(acc, hb[(size_t)n * 16]);

    const int beg = rp[n], end = rp[n + 1];
    int e = beg;
    for (; e + 16 <= end; e += 16) {
        uint4 v0 = hb[(size_t)cs[e + g] * 16];
        uint4 v1 = hb[(size_t)cs[e + 4 + g] * 16];
        uint4 v2 = hb[(size_t)cs[e + 8 + g] * 16];
        uint4 v3 = hb[(size_t)cs[e + 12 + g] * 16];
        dec16(acc, v0); dec16(acc, v1); dec16(acc, v2); dec16(acc, v3);
    }
    for (; e + 4 <= end; e += 4) {
        uint4 v = hb[(size_t)cs[e + g] * 16];
        dec16(acc, v);
    }
    if (e + g < end) {
        uint4 v = hb[(size_t)cs[e + g] * 16];
        dec16(acc, v);
    }
#pragma unroll
    for (int i = 0; i < 16; ++i) acc[i] += __shfl_xor(acc[i], 16);
#pragma unroll
    for (int i = 0; i < 16; ++i) acc[i] += __shfl_xor(acc[i], 32);
    if (g == 0) {
        if (RELU) {
#pragma unroll
            for (int i = 0; i < 16; ++i) acc[i] = fmaxf(acc[i], 0.f);
        }
        uint4 o0, o1;
        o0.x = pack2(acc[0], acc[1]);  o0.y = pack2(acc[2], acc[3]);
        o0.z = pack2(acc[4], acc[5]);  o0.w = pack2(acc[6], acc[7]);
        o1.x = pack2(acc[8], acc[9]);  o1.y = pack2(acc[10], acc[11]);
        o1.z = pack2(acc[12], acc[13]); o1.w = pack2(acc[14], acc[15]);
        uint4* op = (uint4*)((u32*)out + (size_t)n * 128 + c * 8);
        op[0] = o0; op[1] = o1;
    }
}

// ---------------- fp8 gather+self(+relu), D=512 ----------------
template <bool RELU>
__global__ __launch_bounds__(256) void k_agg512_f8(const u8* __restrict__ h8, const int* __restrict__ rp,
                                                   const int* __restrict__ cs, u16* __restrict__ out)
{
    const int lane = threadIdx.x & 63;
    const int n = blockIdx.x * 4 + (threadIdx.x >> 6);
    const int g = lane >> 5;
    const int c = lane & 31;
    const uint4* hb = (const uint4*)h8 + c;

    float acc[16];
#pragma unroll
    for (int i = 0; i < 16; ++i) acc[i] = 0.f;
    if (g == 0) dec16(acc, hb[(size_t)n * 32]);

    const int beg = rp[n], end = rp[n + 1];
    int e = beg;
    for (; e + 8 <= end; e += 8) {
        uint4 v0 = hb[(size_t)cs[e + g] * 32];
        uint4 v1 = hb[(size_t)cs[e + 2 + g] * 32];
        uint4 v2 = hb[(size_t)cs[e + 4 + g] * 32];
        uint4 v3 = hb[(size_t)cs[e + 6 + g] * 32];
        dec16(acc, v0); dec16(acc, v1); dec16(acc, v2); dec16(acc, v3);
    }
    for (; e + 2 <= end; e += 2) {
        uint4 v = hb[(size_t)cs[e + g] * 32];
        dec16(acc, v);
    }
    if (e + g < end) {
        uint4 v = hb[(size_t)cs[e + g] * 32];
        dec16(acc, v);
    }
#pragma unroll
    for (int i = 0; i < 16; ++i) acc[i] += __shfl_xor(acc[i], 32);
    if (g == 0) {
        if (RELU) {
#pragma unroll
            for (int i = 0; i < 16; ++i) acc[i] = fmaxf(acc[i], 0.f);
        }
        uint4 o0, o1;
        o0.x = pack2(acc[0], acc[1]);  o0.y = pack2(acc[2], acc[3]);
        o0.z = pack2(acc[4], acc[5]);  o0.w = pack2(acc[6], acc[7]);
        o1.x = pack2(acc[8], acc[9]);  o1.y = pack2(acc[10], acc[11]);
        o1.z = pack2(acc[12], acc[13]); o1.w = pack2(acc[14], acc[15]);
        uint4* op = (uint4*)((u32*)out + (size_t)n * 256 + c * 8);
        op[0] = o0; op[1] = o1;
    }
}

// ---------------- BN stats, stage A (layers 2,3) ----------------
template <int D>
__global__ __launch_bounds__(256) void k_bn_part(const u16* __restrict__ h, float* __restrict__ partial)
{
    constexpr int SLOT = D / 8;
    constexpr int NS = 256 / SLOT;
    constexpr int ROWS = 16;
    const int t = threadIdx.x;
    const int s = t % SLOT, j = t / SLOT;
    const int r0 = blockIdx.x * ROWS;
    float a[8] = {}, q[8] = {};
#pragma unroll
    for (int rr = 0; rr < ROWS / NS; ++rr) {
        int r = j + rr * NS;
        uint4 v = *((const uint4*)(h + (size_t)(r0 + r) * D) + s);
        u32 wv[4] = {v.x, v.y, v.z, v.w};
#pragma unroll
        for (int k = 0; k < 4; ++k) {
            float lo = bf_lo(wv[k]), hi = bf_hi(wv[k]);
            a[2 * k]     += lo; q[2 * k]     = fmaf(lo, lo, q[2 * k]);
            a[2 * k + 1] += hi; q[2 * k + 1] = fmaf(hi, hi, q[2 * k + 1]);
        }
    }
    __shared__ float red[16][256];
#pragma unroll
    for (int i = 0; i < 8; ++i) { red[i][t] = a[i]; red[8 + i][t] = q[i]; }
    __syncthreads();
    if (j == 0) {
        for (int k = 1; k < NS; ++k) {
            int o = k * SLOT + s;
#pragma unroll
            for (int i = 0; i < 8; ++i) { a[i] += red[i][o]; q[i] += red[8 + i][o]; }
        }
        float* pb = partial + (size_t)blockIdx.x * (2 * D);
        float4* p0 = (float4*)(pb + 8 * s);
        p0[0] = make_float4(a[0], a[1], a[2], a[3]);
        p0[1] = make_float4(a[4], a[5], a[6], a[7]);
        float4* p1 = (float4*)(pb + D + 8 * s);
        p1[0] = make_float4(q[0], q[1], q[2], q[3]);
        p1[1] = make_float4(q[4], q[5], q[6], q[7]);
    }
}

// ---------------- BN stats, stage B ----------------
template <int D, int P, int SEG>
__global__ __launch_bounds__(256) void k_bn_red(const float* __restrict__ partial, float* __restrict__ sums)
{
    const int g = blockIdx.x * 256 + threadIdx.x;
    const int col = g & (2 * D - 1);
    const int seg = g / (2 * D);
    constexpr int CHUNK = P / SEG;
    const float* p = partial + (size_t)seg * CHUNK * (2 * D) + col;
    float acc = 0.f;
#pragma unroll 4
    for (int i = 0; i < CHUNK; ++i) acc += p[(size_t)i * (2 * D)];
    atomicAdd(&sums[col], acc);
}

// ---------------- BN apply with inline finalize ----------------
template <int D>
__global__ __launch_bounds__(256) void k_bn_apply(u16* __restrict__ h, const float* __restrict__ sums,
                                                  const float* __restrict__ gam, const float* __restrict__ bet)
{
    int i = blockIdx.x * 256 + threadIdx.x;
    int c = (i * 8) & (D - 1);
    const float invN = 1.f / (float)N_NODES;
    float sc[8], sh[8];
#pragma unroll
    for (int k = 0; k < 8; ++k) {
        float mu  = sums[c + k] * invN;
        float var = sums[D + c + k] * invN - mu * mu;
        float rs  = rsqrtf(var + 1e-5f);
        sc[k] = gam[c + k] * rs;
        sh[k] = bet[c + k] - mu * sc[k];
    }
    uint4 v = ((uint4*)h)[i];
    u32 vv[4] = {v.x, v.y, v.z, v.w};
    u32 r[4];
#pragma unroll
    for (int k = 0; k < 4; ++k) {
        float a = leakyf(fmaf(bf_lo(vv[k]), sc[2 * k], sh[2 * k]));
        float b = leakyf(fmaf(bf_hi(vv[k]), sc[2 * k + 1], sh[2 * k + 1]));
        r[k] = pack2(a, b);
    }
    ((uint4*)h)[i] = make_uint4(r[0], r[1], r[2], r[3]);
}

// ---------------- pool: BN3+leaky fused, bn_part geometry, NO atomics ----------------
// 2000 blocks x 16 rows (125 blocks per graph); per-block 256-col partial sums -> ppool
__global__ __launch_bounds__(256) void k_pool_bn(const u16* __restrict__ h, const float* __restrict__ sums,
                                                 const float* __restrict__ gam, const float* __restrict__ bet,
                                                 float* __restrict__ ppool)
{
    const int t = threadIdx.x;
    const int s = t & 31;          // uint4 slot: cols 8s..8s+7
    const int j = t >> 5;          // row substream 0..7
    const int r0 = blockIdx.x * 16;
    const float invN = 1.f / (float)N_NODES;
    float sc[8], sh[8];
#pragma unroll
    for (int k = 0; k < 8; ++k) {
        int c = 8 * s + k;
        float mu  = sums[c] * invN;
        float var = sums[256 + c] * invN - mu * mu;
        float rs  = rsqrtf(var + 1e-5f);
        sc[k] = gam[c] * rs;
        sh[k] = bet[c] - mu * sc[k];
    }
    float a[8] = {};
#pragma unroll
    for (int rr = 0; rr < 2; ++rr) {
        int r = r0 + j + rr * 8;
        uint4 v = *((const uint4*)(h + (size_t)r * 256) + s);
        u32 wv[4] = {v.x, v.y, v.z, v.w};
#pragma unroll
        for (int k = 0; k < 4; ++k) {
            a[2 * k]     += leakyf(fmaf(bf_lo(wv[k]), sc[2 * k], sh[2 * k]));
            a[2 * k + 1] += leakyf(fmaf(bf_hi(wv[k]), sc[2 * k + 1], sh[2 * k + 1]));
        }
    }
    __shared__ float red[8][256];
#pragma unroll
    for (int i = 0; i < 8; ++i) red[i][t] = a[i];
    __syncthreads();
    if (j == 0) {
#pragma unroll
        for (int k = 1; k < 8; ++k) {
            int o = k * 32 + s;
#pragma unroll
            for (int i = 0; i < 8; ++i) a[i] += red[i][o];
        }
        float4* pb = (float4*)(ppool + (size_t)blockIdx.x * 256 + 8 * s);
        pb[0] = make_float4(a[0], a[1], a[2], a[3]);
        pb[1] = make_float4(a[4], a[5], a[6], a[7]);
    }
}

// ---------------- head: one block per graph; reduce 125 partials, dot Wp, argmax ----------------
__global__ __launch_bounds__(256) void k_head(const float* __restrict__ ppool, const float* __restrict__ Wp,
                                              const float* __restrict__ bp, float* __restrict__ out)
{
    __shared__ float r0s[256], r1s[256];
    const int b = blockIdx.x, t = threadIdx.x;
    const float* p = ppool + (size_t)b * 125 * 256 + t;
    float g = 0.f;
#pragma unroll 5
    for (int i = 0; i < 125; ++i) g += p[(size_t)i * 256];
    g *= (1.f / 2000.f);
    r0s[t] = g * Wp[t];
    r1s[t] = g * Wp[256 + t];
    __syncthreads();
    for (int off = 128; off > 0; off >>= 1) {
        if (t < off) { r0s[t] += r0s[t + off]; r1s[t] += r1s[t + off]; }
        __syncthreads();
    }
    if (t == 0) {
        float o0 = r0s[0] + bp[0];
        float o1 = r1s[0] + bp[1];
        out[b * 2]     = o0;
        out[b * 2 + 1] = o1;
        out[32 + b]    = (o1 > o0) ? 1.f : 0.f;
    }
}

extern "C" void kernel_launch(void* const* d_in, const int* in_sizes, int n_in,
                              void* d_out, int out_size, void* d_ws, size_t ws_size,
                              hipStream_t stream)
{
    const float* x   = (const float*)d_in[0];
    const int*   ei  = (const int*)d_in[1];
    const float* W1  = (const float*)d_in[2];
    const float* b1  = (const float*)d_in[3];
    const float* W2  = (const float*)d_in[4];
    const float* b2  = (const float*)d_in[5];
    const float* W3  = (const float*)d_in[6];
    const float* b3  = (const float*)d_in[7];
    const float* g1  = (const float*)d_in[8];
    const float* be1 = (const float*)d_in[9];
    const float* g2  = (const float*)d_in[10];
    const float* be2 = (const float*)d_in[11];
    const float* g3  = (const float*)d_in[12];
    const float* be3 = (const float*)d_in[13];
    const float* Wp  = (const float*)d_in[14];
    const float* bp  = (const float*)d_in[15];
    float* out = (float*)d_out;

    const int E = in_sizes[1] / 2;
    const int* src = ei;
    const int* dst = ei + E;

    char* ws = (char*)d_ws;
    size_t off = 0;
    auto alloc = [&](size_t bytes) -> void* {
        void* p = ws + off;
        off = (off + bytes + 255) & ~(size_t)255;
        return p;
    };
    u16*   bufA = (u16*)alloc((size_t)N_NODES * 512 * 2);
    u16*   bufB = (u16*)alloc((size_t)N_NODES * 512 * 2);
    u8*    buf8 = (u8*)alloc((size_t)N_NODES * 512);
    u8*    x8   = (u8*)alloc((size_t)N_NODES * 256);
    u16*   w1b  = (u16*)alloc(512 * 256 * 2);
    u16*   w2b  = (u16*)alloc(512 * 512 * 2);
    u16*   w3b  = (u16*)alloc(256 * 512 * 2);
    int*   cs   = (int*)alloc((size_t)E * 4);
    int*   rp   = (int*)alloc((size_t)(N_NODES + 1) * 4);
    // contiguous zero region: cnt | cur | sums1..3
    int*   cnt  = (int*)alloc((size_t)N_NODES * 4 * 2 + 3072 * 4);
    int*   cur  = cnt + N_NODES;
    float* zz   = (float*)(cnt + 2 * N_NODES);
    float* sums1 = zz, *sums2 = zz + 1024, *sums3 = zz + 2048;
    const size_t zbytes = (size_t)N_NODES * 8 + 3072 * 4;
    int*   bsum = (int*)alloc(256 * 4);
    float* part = (float*)alloc((size_t)2000 * 1024 * 4);
    float* ppool = (float*)alloc((size_t)2000 * 256 * 4);

    hipMemsetAsync(cnt, 0, zbytes, stream);

    const int eb = (E + 255) / 256;          // 2000
    const int nb = N_NODES / 256;            // 125

    k_prep<<<eb + 8000 + 512, 256, 0, stream>>>(dst, cnt, E, x, (u32*)x8, W1, W2, W3, w1b, w2b, w3b);
    k_scan_blk<<<nb, 256, 0, stream>>>(cnt, rp, bsum);
    k_scan_add<<<nb, 256, 0, stream>>>(rp, bsum, nb, N_NODES, E);
    k_place<<<eb, 256, 0, stream>>>(src, dst, rp, cur, cs, E);

    const int PB = N_NODES / 16;             // 2000 stage-A blocks

    // ---- layer 1 ----
    k_agg256_f8<false><<<N_NODES / 4, 256, 0, stream>>>(x8, rp, cs, bufA);
    k_gemm_mfma<true, true, false, true><<<dim3(250, 4), 256, 0, stream>>>(bufA, w1b, b1, rp, bufB, part, 256, 512);
    k_bn_red<512, 250, 2><<<8, 256, 0, stream>>>(part, sums1);
    k_bn_apply<512><<<N_NODES * 512 / 8 / 256, 256, 0, stream>>>(bufB, sums1, g1, be1);

    // ---- layer 2 ----
    k_gemm_mfma<false, false, true, false><<<dim3(250, 4), 256, 0, stream>>>(bufB, w2b, b2, rp, buf8, nullptr, 512, 512);
    k_agg512_f8<true><<<N_NODES / 4, 256, 0, stream>>>(buf8, rp, cs, bufA);
    k_bn_part<512><<<PB, 256, 0, stream>>>(bufA, part);
    k_bn_red<512, 2000, 8><<<32, 256, 0, stream>>>(part, sums2);
    k_bn_apply<512><<<N_NODES * 512 / 8 / 256, 256, 0, stream>>>(bufA, sums2, g2, be2);

    // ---- layer 3 ----
    k_gemm_mfma<false, false, true, false><<<dim3(250, 2), 256, 0, stream>>>(bufA, w3b, b3, rp, buf8, nullptr, 512, 256);
    k_agg256_f8<true><<<N_NODES / 4, 256, 0, stream>>>(buf8, rp, cs, bufB);
    k_bn_part<256><<<PB, 256, 0, stream>>>(bufB, part);
    k_bn_red<256, 2000, 8><<<16, 256, 0, stream>>>(part, sums3);

    // ---- pool (fused BN3+leaky, no atomics) + head ----
    k_pool_bn<<<PB, 256, 0, stream>>>(bufB, sums3, g3, be3, ppool);
    k_head<<<16, 256, 0, stream>>>(ppool, Wp, bp, out);
}

// Round 15
// 324.029 us; speedup vs baseline: 2.8152x; 1.1854x over previous
//
#include <hip/hip_runtime.h>

#define N_NODES 32000
typedef unsigned short u16;
typedef unsigned int u32;
typedef unsigned char u8;
typedef __attribute__((ext_vector_type(8))) short bf16x8;
typedef __attribute__((ext_vector_type(4))) float f32x4;
typedef __attribute__((ext_vector_type(2))) float f32x2;

__device__ __forceinline__ float leakyf(float v) { return v >= 0.f ? v : 0.1f * v; }
__device__ __forceinline__ u16 f2bf(float f) {
    u32 u = __float_as_uint(f);
    return (u16)((u + 0x7FFFu + ((u >> 16) & 1u)) >> 16);
}
__device__ __forceinline__ float bf_lo(u32 u) { return __uint_as_float(u << 16); }
__device__ __forceinline__ float bf_hi(u32 u) { return __uint_as_float(u & 0xFFFF0000u); }
__device__ __forceinline__ u32 pack2(float a, float b) { return (u32)f2bf(a) | ((u32)f2bf(b) << 16); }

__device__ __forceinline__ void dec4(float* acc, u32 w) {
    f32x2 lo = __builtin_amdgcn_cvt_pk_f32_fp8(w, false);
    f32x2 hi = __builtin_amdgcn_cvt_pk_f32_fp8(w, true);
    acc[0] += lo[0]; acc[1] += lo[1]; acc[2] += hi[0]; acc[3] += hi[1];
}
__device__ __forceinline__ void dec16(float* acc, uint4 v) {
    dec4(acc + 0, v.x); dec4(acc + 4, v.y); dec4(acc + 8, v.z); dec4(acc + 12, v.w);
}
__device__ __forceinline__ u8 f2fp8(float v) {
    return (u8)__builtin_amdgcn_cvt_pk_fp8_f32(v, v, 0, false);
}

__device__ __forceinline__ void gload16(const u16* g, u16* l) {
    __builtin_amdgcn_global_load_lds((const __attribute__((address_space(1))) void*)g,
                                     (__attribute__((address_space(3))) void*)l, 16, 0, 0);
}

// ---------------- fused prep: edge-count | x->fp8 | weights->bf16 ----------------
__global__ __launch_bounds__(256) void k_prep(const int* __restrict__ dst, int* __restrict__ cnt, int E,
                                              const float* __restrict__ x, u32* __restrict__ x8,
                                              const float* __restrict__ W1, const float* __restrict__ W2,
                                              const float* __restrict__ W3, u16* __restrict__ o1,
                                              u16* __restrict__ o2, u16* __restrict__ o3)
{
    const int b = blockIdx.x, t = threadIdx.x;
    if (b < 2000) {
        int e = b * 256 + t;
        if (e < E) atomicAdd(&cnt[dst[e]], 1);
    } else if (b < 10000) {
        int i = (b - 2000) * 256 + t;
        float4 v = ((const float4*)x)[i];
        int p = __builtin_amdgcn_cvt_pk_fp8_f32(v.x, v.y, 0, false);
        p = __builtin_amdgcn_cvt_pk_fp8_f32(v.z, v.w, p, true);
        x8[i] = (u32)p;
    } else {
        int bb = b - 10000;
        const float* in; u16* out; int i;
        if (bb < 128)      { in = W1; out = o1; i = bb * 256 + t; }
        else if (bb < 384) { in = W2; out = o2; i = (bb - 128) * 256 + t; }
        else               { in = W3; out = o3; i = (bb - 384) * 256 + t; }
        float4 v = ((const float4*)in)[i];
        ushort4 o;
        o.x = f2bf(v.x); o.y = f2bf(v.y); o.z = f2bf(v.z); o.w = f2bf(v.w);
        ((ushort4*)out)[i] = o;
    }
}

// ---------------- CSR scan ----------------
__global__ __launch_bounds__(256) void k_scan_blk(const int* __restrict__ cnt, int* __restrict__ rp,
                                                  int* __restrict__ bsum)
{
    __shared__ int sh[256];
    const int b = blockIdx.x, t = threadIdx.x;
    int v = cnt[b * 256 + t];
    sh[t] = v;
    __syncthreads();
    for (int off = 1; off < 256; off <<= 1) {
        int u = (t >= off) ? sh[t - off] : 0;
        __syncthreads();
        sh[t] += u;
        __syncthreads();
    }
    rp[b * 256 + t] = sh[t] - v;
    if (t == 255) bsum[b] = sh[255];
}

__global__ __launch_bounds__(256) void k_scan_add(int* __restrict__ rp, const int* __restrict__ bsum,
                                                  int nb, int n, int E)
{
    __shared__ int sh[256];
    const int b = blockIdx.x, t = threadIdx.x;
    int v = (t < b && t < nb) ? bsum[t] : 0;
    sh[t] = v;
    __syncthreads();
    for (int off = 128; off > 0; off >>= 1) {
        if (t < off) sh[t] += sh[t + off];
        __syncthreads();
    }
    int i = b * 256 + t;
    rp[i] += sh[0];
    if (i == 0) rp[n] = E;
}

__global__ __launch_bounds__(256) void k_place(const int* __restrict__ src, const int* __restrict__ dst,
                                               const int* __restrict__ rp, int* __restrict__ cur,
                                               int* __restrict__ cs, int E)
{
    int e = blockIdx.x * 256 + threadIdx.x;
    if (e < E) {
        int d = dst[e];
        int p = rp[d] + atomicAdd(&cur[d], 1);
        cs[p] = src[e];
    }
}

// ---------------- bf16 MFMA GEMM, dbuf + counted vmcnt; optional fused column stats ----------------
template <bool RELU, bool DEGB, bool F8OUT, bool STATS>
__global__ __launch_bounds__(256) void k_gemm_mfma(const u16* __restrict__ A, const u16* __restrict__ W,
                                                   const float* __restrict__ bias, const int* __restrict__ rp,
                                                   void* __restrict__ Cv, float* __restrict__ partial,
                                                   int K, int OD)
{
    __shared__ u16 As[2][128 * 32];
    __shared__ u16 Bs[2][128 * 32];
    const int t = threadIdx.x;
    const int lane = t & 63;
    const int w = t >> 6;
    const int wr = w >> 1, wc = w & 1;
    const int bm = blockIdx.x * 128;
    const int bn = blockIdx.y * 128;

    const int c0 = w * 64 + lane;
    const int r0 = c0 >> 2, kc0 = (c0 & 3) * 8;
    const int c1 = c0 + 256;
    const int r1 = c1 >> 2, kc1 = (c1 & 3) * 8;
    const u16* gA0 = A + (size_t)(bm + r0) * K + kc0;
    const u16* gA1 = A + (size_t)(bm + r1) * K + kc1;
    const u16* gB0 = W + (size_t)(bn + r0) * K + kc0;
    const u16* gB1 = W + (size_t)(bn + r1) * K + kc1;

    f32x4 acc[4][4];
#pragma unroll
    for (int i = 0; i < 4; ++i)
#pragma unroll
        for (int j = 0; j < 4; ++j)
            acc[i][j] = (f32x4){0.f, 0.f, 0.f, 0.f};

    const int fr = lane & 15;
    const int ko = (lane >> 4) * 8;

    auto STAGE = [&](int b, int k0) {
        gload16(gA0 + k0, &As[b][0] + w * 512);
        gload16(gA1 + k0, &As[b][0] + 2048 + w * 512);
        gload16(gB0 + k0, &Bs[b][0] + w * 512);
        gload16(gB1 + k0, &Bs[b][0] + 2048 + w * 512);
    };

    STAGE(0, 0);

    int cur = 0;
    for (int k0 = 0; k0 < K; k0 += 32) {
        if (k0 + 32 < K) {
            STAGE(cur ^ 1, k0 + 32);
            asm volatile("s_waitcnt vmcnt(4)" ::: "memory");
        } else {
            asm volatile("s_waitcnt vmcnt(0)" ::: "memory");
        }
        __syncthreads();
        bf16x8 af[4], bfv[4];
#pragma unroll
        for (int i = 0; i < 4; ++i)
            af[i] = *(const bf16x8*)&As[cur][(wr * 64 + i * 16 + fr) * 32 + ko];
#pragma unroll
        for (int j = 0; j < 4; ++j)
            bfv[j] = *(const bf16x8*)&Bs[cur][(wc * 64 + j * 16 + fr) * 32 + ko];
#pragma unroll
        for (int i = 0; i < 4; ++i)
#pragma unroll
            for (int j = 0; j < 4; ++j)
                acc[i][j] = __builtin_amdgcn_mfma_f32_16x16x32_bf16(af[i], bfv[j], acc[i][j], 0, 0, 0);
        __syncthreads();
        cur ^= 1;
    }

    u16* C16 = (u16*)Cv;
    u8*  C8  = (u8*)Cv;
    const int qr = (lane >> 4) * 4;
    float bcol[4];
#pragma unroll
    for (int j = 0; j < 4; ++j) bcol[j] = bias[bn + wc * 64 + j * 16 + fr];
    float s4[4] = {}, q4[4] = {};
#pragma unroll
    for (int i = 0; i < 4; ++i) {
#pragma unroll
        for (int r = 0; r < 4; ++r) {
            int row = bm + wr * 64 + i * 16 + qr + r;
            float bm_ = 1.f;
            if (DEGB) bm_ = (float)(rp[row + 1] - rp[row]) + 1.f;
#pragma unroll
            for (int j = 0; j < 4; ++j) {
                int col = bn + wc * 64 + j * 16 + fr;
                float o = acc[i][j][r] + bm_ * bcol[j];
                if (RELU) o = fmaxf(o, 0.f);
                if (STATS) { s4[j] += o; q4[j] = fmaf(o, o, q4[j]); }
                if (F8OUT) C8[(size_t)row * OD + col] = f2fp8(o);
                else       C16[(size_t)row * OD + col] = f2bf(o);
            }
        }
    }

    if (STATS) {
#pragma unroll
        for (int j = 0; j < 4; ++j) {
            s4[j] += __shfl_xor(s4[j], 16); s4[j] += __shfl_xor(s4[j], 32);
            q4[j] += __shfl_xor(q4[j], 16); q4[j] += __shfl_xor(q4[j], 32);
        }
        __syncthreads();
        float* sred = (float*)&As[0][0];
        if ((lane >> 4) == 0) {
#pragma unroll
            for (int j = 0; j < 4; ++j) {
                sred[((w * 4 + j) * 16 + fr) * 2 + 0] = s4[j];
                sred[((w * 4 + j) * 16 + fr) * 2 + 1] = q4[j];
            }
        }
        __syncthreads();
        if (wr == 0 && (lane >> 4) == 0) {
#pragma unroll
            for (int j = 0; j < 4; ++j) {
                int i0 = ((w * 4 + j) * 16 + fr) * 2;
                int i1 = (((w + 2) * 4 + j) * 16 + fr) * 2;
                float ss = sred[i0] + sred[i1];
                float qq = sred[i0 + 1] + sred[i1 + 1];
                int col = bn + wc * 64 + j * 16 + fr;
                partial[(size_t)blockIdx.x * 1024 + col]       = ss;
                partial[(size_t)blockIdx.x * 1024 + 512 + col] = qq;
            }
        }
    }
}

// ---------------- fp8 gather+self(+relu), D=256 ----------------
template <bool RELU>
__global__ __launch_bounds__(256) void k_agg256_f8(const u8* __restrict__ h8, const int* __restrict__ rp,
                                                   const int* __restrict__ cs, u16* __restrict__ out)
{
    const int lane = threadIdx.x & 63;
    const int n = blockIdx.x * 4 + (threadIdx.x >> 6);
    const int g = lane >> 4;
    const int c = lane & 15;
    const uint4* hb = (const uint4*)h8 + c;

    float acc[16];
#pragma unroll
    for (int i = 0; i < 16; ++i) acc[i] = 0.f;
    if (g == 0) dec16(acc, hb[(size_t)n * 16]);

    const int beg = rp[n], end = rp[n + 1];
    int e = beg;
    for (; e + 16 <= end; e += 16) {
        uint4 v0 = hb[(size_t)cs[e + g] * 16];
        uint4 v1 = hb[(size_t)cs[e + 4 + g] * 16];
        uint4 v2 = hb[(size_t)cs[e + 8 + g] * 16];
        uint4 v3 = hb[(size_t)cs[e + 12 + g] * 16];
        dec16(acc, v0); dec16(acc, v1); dec16(acc, v2); dec16(acc, v3);
    }
    for (; e + 4 <= end; e += 4) {
        uint4 v = hb[(size_t)cs[e + g] * 16];
        dec16(acc, v);
    }
    if (e + g < end) {
        uint4 v = hb[(size_t)cs[e + g] * 16];
        dec16(acc, v);
    }
#pragma unroll
    for (int i = 0; i < 16; ++i) acc[i] += __shfl_xor(acc[i], 16);
#pragma unroll
    for (int i = 0; i < 16; ++i) acc[i] += __shfl_xor(acc[i], 32);
    if (g == 0) {
        if (RELU) {
#pragma unroll
            for (int i = 0; i < 16; ++i) acc[i] = fmaxf(acc[i], 0.f);
        }
        uint4 o0, o1;
        o0.x = pack2(acc[0], acc[1]);  o0.y = pack2(acc[2], acc[3]);
        o0.z = pack2(acc[4], acc[5]);  o0.w = pack2(acc[6], acc[7]);
        o1.x = pack2(acc[8], acc[9]);  o1.y = pack2(acc[10], acc[11]);
        o1.z = pack2(acc[12], acc[13]); o1.w = pack2(acc[14], acc[15]);
        uint4* op = (uint4*)((u32*)out + (size_t)n * 128 + c * 8);
        op[0] = o0; op[1] = o1;
    }
}

// ---------------- fp8 gather+self(+relu), D=512 ----------------
template <bool RELU>
__global__ __launch_bounds__(256) void k_agg512_f8(const u8* __restrict__ h8, const int* __restrict__ rp,
                                                   const int* __restrict__ cs, u16* __restrict__ out)
{
    const int lane = threadIdx.x & 63;
    const int n = blockIdx.x * 4 + (threadIdx.x >> 6);
    const int g = lane >> 5;
    const int c = lane & 31;
    const uint4* hb = (const uint4*)h8 + c;

    float acc[16];
#pragma unroll
    for (int i = 0; i < 16; ++i) acc[i] = 0.f;
    if (g == 0) dec16(acc, hb[(size_t)n * 32]);

    const int beg = rp[n], end = rp[n + 1];
    int e = beg;
    for (; e + 8 <= end; e += 8) {
        uint4 v0 = hb[(size_t)cs[e + g] * 32];
        uint4 v1 = hb[(size_t)cs[e + 2 + g] * 32];
        uint4 v2 = hb[(size_t)cs[e + 4 + g] * 32];
        uint4 v3 = hb[(size_t)cs[e + 6 + g] * 32];
        dec16(acc, v0); dec16(acc, v1); dec16(acc, v2); dec16(acc, v3);
    }
    for (; e + 2 <= end; e += 2) {
        uint4 v = hb[(size_t)cs[e + g] * 32];
        dec16(acc, v);
    }
    if (e + g < end) {
        uint4 v = hb[(size_t)cs[e + g] * 32];
        dec16(acc, v);
    }
#pragma unroll
    for (int i = 0; i < 16; ++i) acc[i] += __shfl_xor(acc[i], 32);
    if (g == 0) {
        if (RELU) {
#pragma unroll
            for (int i = 0; i < 16; ++i) acc[i] = fmaxf(acc[i], 0.f);
        }
        uint4 o0, o1;
        o0.x = pack2(acc[0], acc[1]);  o0.y = pack2(acc[2], acc[3]);
        o0.z = pack2(acc[4], acc[5]);  o0.w = pack2(acc[6], acc[7]);
        o1.x = pack2(acc[8], acc[9]);  o1.y = pack2(acc[10], acc[11]);
        o1.z = pack2(acc[12], acc[13]); o1.w = pack2(acc[14], acc[15]);
        uint4* op = (uint4*)((u32*)out + (size_t)n * 256 + c * 8);
        op[0] = o0; op[1] = o1;
    }
}

// ---------------- BN stats, stage A (layers 2,3) ----------------
template <int D>
__global__ __launch_bounds__(256) void k_bn_part(const u16* __restrict__ h, float* __restrict__ partial)
{
    constexpr int SLOT = D / 8;
    constexpr int NS = 256 / SLOT;
    constexpr int ROWS = 16;
    const int t = threadIdx.x;
    const int s = t % SLOT, j = t / SLOT;
    const int r0 = blockIdx.x * ROWS;
    float a[8] = {}, q[8] = {};
#pragma unroll
    for (int rr = 0; rr < ROWS / NS; ++rr) {
        int r = j + rr * NS;
        uint4 v = *((const uint4*)(h + (size_t)(r0 + r) * D) + s);
        u32 wv[4] = {v.x, v.y, v.z, v.w};
#pragma unroll
        for (int k = 0; k < 4; ++k) {
            float lo = bf_lo(wv[k]), hi = bf_hi(wv[k]);
            a[2 * k]     += lo; q[2 * k]     = fmaf(lo, lo, q[2 * k]);
            a[2 * k + 1] += hi; q[2 * k + 1] = fmaf(hi, hi, q[2 * k + 1]);
        }
    }
    __shared__ float red[16][256];
#pragma unroll
    for (int i = 0; i < 8; ++i) { red[i][t] = a[i]; red[8 + i][t] = q[i]; }
    __syncthreads();
    if (j == 0) {
        for (int k = 1; k < NS; ++k) {
            int o = k * SLOT + s;
#pragma unroll
            for (int i = 0; i < 8; ++i) { a[i] += red[i][o]; q[i] += red[8 + i][o]; }
        }
        float* pb = partial + (size_t)blockIdx.x * (2 * D);
        float4* p0 = (float4*)(pb + 8 * s);
        p0[0] = make_float4(a[0], a[1], a[2], a[3]);
        p0[1] = make_float4(a[4], a[5], a[6], a[7]);
        float4* p1 = (float4*)(pb + D + 8 * s);
        p1[0] = make_float4(q[0], q[1], q[2], q[3]);
        p1[1] = make_float4(q[4], q[5], q[6], q[7]);
    }
}

// ---------------- BN stats reduce, level 1: P rows -> SEG rows (no atomics) ----------------
template <int D, int P, int SEG>
__global__ __launch_bounds__(256) void k_bn_red1(const float* __restrict__ partial, float* __restrict__ part2)
{
    const int g = blockIdx.x * 256 + threadIdx.x;
    const int col = g & (2 * D - 1);
    const int seg = g / (2 * D);
    constexpr int CHUNK = P / SEG;
    const float* p = partial + (size_t)seg * CHUNK * (2 * D) + col;
    float acc = 0.f;
#pragma unroll
    for (int i = 0; i < CHUNK; ++i) acc += p[(size_t)i * (2 * D)];
    part2[(size_t)seg * (2 * D) + col] = acc;
}

// ---------------- BN stats reduce, level 2: SEG rows -> sums (direct store) ----------------
template <int D, int SEG>
__global__ __launch_bounds__(256) void k_bn_red2(const float* __restrict__ part2, float* __restrict__ sums)
{
    const int col = blockIdx.x * 256 + threadIdx.x;
    float acc = 0.f;
#pragma unroll
    for (int i = 0; i < SEG; ++i) acc += part2[(size_t)i * (2 * D) + col];
    sums[col] = acc;
}

// ---------------- BN apply with inline finalize ----------------
template <int D>
__global__ __launch_bounds__(256) void k_bn_apply(u16* __restrict__ h, const float* __restrict__ sums,
                                                  const float* __restrict__ gam, const float* __restrict__ bet)
{
    int i = blockIdx.x * 256 + threadIdx.x;
    int c = (i * 8) & (D - 1);
    const float invN = 1.f / (float)N_NODES;
    float sc[8], sh[8];
#pragma unroll
    for (int k = 0; k < 8; ++k) {
        float mu  = sums[c + k] * invN;
        float var = sums[D + c + k] * invN - mu * mu;
        float rs  = rsqrtf(var + 1e-5f);
        sc[k] = gam[c + k] * rs;
        sh[k] = bet[c + k] - mu * sc[k];
    }
    uint4 v = ((uint4*)h)[i];
    u32 vv[4] = {v.x, v.y, v.z, v.w};
    u32 r[4];
#pragma unroll
    for (int k = 0; k < 4; ++k) {
        float a = leakyf(fmaf(bf_lo(vv[k]), sc[2 * k], sh[2 * k]));
        float b = leakyf(fmaf(bf_hi(vv[k]), sc[2 * k + 1], sh[2 * k + 1]));
        r[k] = pack2(a, b);
    }
    ((uint4*)h)[i] = make_uint4(r[0], r[1], r[2], r[3]);
}

// ---------------- pool: BN3+leaky fused, bn_part geometry, NO atomics ----------------
__global__ __launch_bounds__(256) void k_pool_bn(const u16* __restrict__ h, const float* __restrict__ sums,
                                                 const float* __restrict__ gam, const float* __restrict__ bet,
                                                 float* __restrict__ ppool)
{
    const int t = threadIdx.x;
    const int s = t & 31;
    const int j = t >> 5;
    const int r0 = blockIdx.x * 16;
    const float invN = 1.f / (float)N_NODES;
    float sc[8], sh[8];
#pragma unroll
    for (int k = 0; k < 8; ++k) {
        int c = 8 * s + k;
        float mu  = sums[c] * invN;
        float var = sums[256 + c] * invN - mu * mu;
        float rs  = rsqrtf(var + 1e-5f);
        sc[k] = gam[c] * rs;
        sh[k] = bet[c] - mu * sc[k];
    }
    float a[8] = {};
#pragma unroll
    for (int rr = 0; rr < 2; ++rr) {
        int r = r0 + j + rr * 8;
        uint4 v = *((const uint4*)(h + (size_t)r * 256) + s);
        u32 wv[4] = {v.x, v.y, v.z, v.w};
#pragma unroll
        for (int k = 0; k < 4; ++k) {
            a[2 * k]     += leakyf(fmaf(bf_lo(wv[k]), sc[2 * k], sh[2 * k]));
            a[2 * k + 1] += leakyf(fmaf(bf_hi(wv[k]), sc[2 * k + 1], sh[2 * k + 1]));
        }
    }
    __shared__ float red[8][256];
#pragma unroll
    for (int i = 0; i < 8; ++i) red[i][t] = a[i];
    __syncthreads();
    if (j == 0) {
#pragma unroll
        for (int k = 1; k < 8; ++k) {
            int o = k * 32 + s;
#pragma unroll
            for (int i = 0; i < 8; ++i) a[i] += red[i][o];
        }
        float4* pb = (float4*)(ppool + (size_t)blockIdx.x * 256 + 8 * s);
        pb[0] = make_float4(a[0], a[1], a[2], a[3]);
        pb[1] = make_float4(a[4], a[5], a[6], a[7]);
    }
}

// ---------------- head: one block per graph ----------------
__global__ __launch_bounds__(256) void k_head(const float* __restrict__ ppool, const float* __restrict__ Wp,
                                              const float* __restrict__ bp, float* __restrict__ out)
{
    __shared__ float r0s[256], r1s[256];
    const int b = blockIdx.x, t = threadIdx.x;
    const float* p = ppool + (size_t)b * 125 * 256 + t;
    float g = 0.f;
#pragma unroll 5
    for (int i = 0; i < 125; ++i) g += p[(size_t)i * 256];
    g *= (1.f / 2000.f);
    r0s[t] = g * Wp[t];
    r1s[t] = g * Wp[256 + t];
    __syncthreads();
    for (int off = 128; off > 0; off >>= 1) {
        if (t < off) { r0s[t] += r0s[t + off]; r1s[t] += r1s[t + off]; }
        __syncthreads();
    }
    if (t == 0) {
        float o0 = r0s[0] + bp[0];
        float o1 = r1s[0] + bp[1];
        out[b * 2]     = o0;
        out[b * 2 + 1] = o1;
        out[32 + b]    = (o1 > o0) ? 1.f : 0.f;
    }
}

extern "C" void kernel_launch(void* const* d_in, const int* in_sizes, int n_in,
                              void* d_out, int out_size, void* d_ws, size_t ws_size,
                              hipStream_t stream)
{
    const float* x   = (const float*)d_in[0];
    const int*   ei  = (const int*)d_in[1];
    const float* W1  = (const float*)d_in[2];
    const float* b1  = (const float*)d_in[3];
    const float* W2  = (const float*)d_in[4];
    const float* b2  = (const float*)d_in[5];
    const float* W3  = (const float*)d_in[6];
    const float* b3  = (const float*)d_in[7];
    const float* g1  = (const float*)d_in[8];
    const float* be1 = (const float*)d_in[9];
    const float* g2  = (const float*)d_in[10];
    const float* be2 = (const float*)d_in[11];
    const float* g3  = (const float*)d_in[12];
    const float* be3 = (const float*)d_in[13];
    const float* Wp  = (const float*)d_in[14];
    const float* bp  = (const float*)d_in[15];
    float* out = (float*)d_out;

    const int E = in_sizes[1] / 2;
    const int* src = ei;
    const int* dst = ei + E;

    char* ws = (char*)d_ws;
    size_t off = 0;
    auto alloc = [&](size_t bytes) -> void* {
        void* p = ws + off;
        off = (off + bytes + 255) & ~(size_t)255;
        return p;
    };
    u16*   bufA = (u16*)alloc((size_t)N_NODES * 512 * 2);
    u16*   bufB = (u16*)alloc((size_t)N_NODES * 512 * 2);
    u8*    buf8 = (u8*)alloc((size_t)N_NODES * 512);
    u8*    x8   = (u8*)alloc((size_t)N_NODES * 256);
    u16*   w1b  = (u16*)alloc(512 * 256 * 2);
    u16*   w2b  = (u16*)alloc(512 * 512 * 2);
    u16*   w3b  = (u16*)alloc(256 * 512 * 2);
    int*   cs   = (int*)alloc((size_t)E * 4);
    int*   rp   = (int*)alloc((size_t)(N_NODES + 1) * 4);
    int*   cnt  = (int*)alloc((size_t)N_NODES * 4 * 2);
    int*   cur  = cnt + N_NODES;
    const size_t zbytes = (size_t)N_NODES * 8;
    int*   bsum = (int*)alloc(256 * 4);
    float* part = (float*)alloc((size_t)2000 * 1024 * 4);
    float* part2 = (float*)alloc((size_t)100 * 1024 * 4);
    float* sums1 = (float*)alloc(1024 * 4);
    float* sums2 = (float*)alloc(1024 * 4);
    float* sums3 = (float*)alloc(1024 * 4);
    float* ppool = (float*)alloc((size_t)2000 * 256 * 4);

    hipMemsetAsync(cnt, 0, zbytes, stream);

    const int eb = (E + 255) / 256;          // 2000
    const int nb = N_NODES / 256;            // 125

    k_prep<<<eb + 8000 + 512, 256, 0, stream>>>(dst, cnt, E, x, (u32*)x8, W1, W2, W3, w1b, w2b, w3b);
    k_scan_blk<<<nb, 256, 0, stream>>>(cnt, rp, bsum);
    k_scan_add<<<nb, 256, 0, stream>>>(rp, bsum, nb, N_NODES, E);
    k_place<<<eb, 256, 0, stream>>>(src, dst, rp, cur, cs, E);

    const int PB = N_NODES / 16;             // 2000 stage-A blocks

    // ---- layer 1: stats fused in GEMM epilogue (250 partial rows) ----
    k_agg256_f8<false><<<N_NODES / 4, 256, 0, stream>>>(x8, rp, cs, bufA);
    k_gemm_mfma<true, true, false, true><<<dim3(250, 4), 256, 0, stream>>>(bufA, w1b, b1, rp, bufB, part, 256, 512);
    k_bn_red1<512, 250, 25><<<100, 256, 0, stream>>>(part, part2);
    k_bn_red2<512, 25><<<4, 256, 0, stream>>>(part2, sums1);
    k_bn_apply<512><<<N_NODES * 512 / 8 / 256, 256, 0, stream>>>(bufB, sums1, g1, be1);

    // ---- layer 2 ----
    k_gemm_mfma<false, false, true, false><<<dim3(250, 4), 256, 0, stream>>>(bufB, w2b, b2, rp, buf8, nullptr, 512, 512);
    k_agg512_f8<true><<<N_NODES / 4, 256, 0, stream>>>(buf8, rp, cs, bufA);
    k_bn_part<512><<<PB, 256, 0, stream>>>(bufA, part);
    k_bn_red1<512, 2000, 100><<<400, 256, 0, stream>>>(part, part2);
    k_bn_red2<512, 100><<<4, 256, 0, stream>>>(part2, sums2);
    k_bn_apply<512><<<N_NODES * 512 / 8 / 256, 256, 0, stream>>>(bufA, sums2, g2, be2);

    // ---- layer 3: GEMM -> agg -> stats (BN3 applied inside pool) ----
    k_gemm_mfma<false, false, true, false><<<dim3(250, 2), 256, 0, stream>>>(bufA, w3b, b3, rp, buf8, nullptr, 512, 256);
    k_agg256_f8<true><<<N_NODES / 4, 256, 0, stream>>>(buf8, rp, cs, bufB);
    k_bn_part<256><<<PB, 256, 0, stream>>>(bufB, part);
    k_bn_red1<256, 2000, 100><<<200, 256, 0, stream>>>(part, part2);
    k_bn_red2<256, 100><<<2, 256, 0, stream>>>(part2, sums3);

    // ---- pool (fused BN3+leaky, no atomics) + head ----
    k_pool_bn<<<PB, 256, 0, stream>>>(bufB, sums3, g3, be3, ppool);
    k_head<<<16, 256, 0, stream>>>(ppool, Wp, bp, out);
}